// Round 3
// baseline (2683.347 us; speedup 1.0000x reference)
//
#include <hip/hip_runtime.h>
#include <hip/hip_bf16.h>

#define BB 32
#define TT 512
#define IND 16
#define FD 128
#define NAGG 32
#define NHEADS 4
#define DHEAD 32

// block = 128 threads (2 waves). Sum across block.
__device__ __forceinline__ float bsum128(float v, float* red) {
#pragma unroll
  for (int o = 32; o > 0; o >>= 1) v += __shfl_xor(v, o);
  if ((threadIdx.x & 63) == 0) red[threadIdx.x >> 6] = v;
  __syncthreads();
  float r = red[0] + red[1];
  __syncthreads();
  return r;
}

// ---- QKV projection from 16-dim input ----
__global__ void proj16_k(const float* __restrict__ X,
                         const float* __restrict__ wq, const float* __restrict__ bq,
                         const float* __restrict__ wk, const float* __restrict__ bk,
                         const float* __restrict__ wv, const float* __restrict__ bv,
                         float* __restrict__ Q, float* __restrict__ K, float* __restrict__ V) {
  int bt = blockIdx.x;
  int f = threadIdx.x;
  __shared__ float xs[IND];
  if (f < IND) xs[f] = X[(size_t)bt * IND + f];
  __syncthreads();
  float q = bq[f], k = bk[f], v = bv[f];
#pragma unroll
  for (int i = 0; i < IND; i++) {
    float x = xs[i];
    q += x * wq[i * FD + f];
    k += x * wk[i * FD + f];
    v += x * wv[i * FD + f];
  }
  size_t o = (size_t)bt * FD + f;
  Q[o] = q; K[o] = k; V[o] = v;
}

// ---- QKV projection from 128-dim fp32 input ----
__global__ void proj128_k(const float* __restrict__ Xin,
                          const float* __restrict__ wq, const float* __restrict__ bq,
                          const float* __restrict__ wk, const float* __restrict__ bk,
                          const float* __restrict__ wv, const float* __restrict__ bv,
                          float* __restrict__ Q, float* __restrict__ K, float* __restrict__ V) {
  int bt = blockIdx.x;
  int f = threadIdx.x;
  __shared__ float xs[FD];
  xs[f] = Xin[(size_t)bt * FD + f];
  __syncthreads();
  float q = bq[f], k = bk[f], v = bv[f];
  for (int i = 0; i < FD; i++) {
    float x = xs[i];
    q += x * wq[i * FD + f];
    k += x * wk[i * FD + f];
    v += x * wv[i * FD + f];
  }
  size_t o = (size_t)bt * FD + f;
  Q[o] = q; K[o] = k; V[o] = v;
}

// ---- fused SAB core: attention + residual + LN + FFN + LN, one block per (b,t) ----
__global__ void sab_core(const float* __restrict__ Q, const float* __restrict__ K,
                         const float* __restrict__ V, const float* __restrict__ mask,
                         const float* __restrict__ wo, const float* __restrict__ bo,
                         const float* __restrict__ g0, const float* __restrict__ be0,
                         const float* __restrict__ g1, const float* __restrict__ be1,
                         float* __restrict__ Xp) {
  int bt = blockIdx.x;
  int b = bt >> 9;  // T = 512
  int f = threadIdx.x;
  __shared__ float qs[FD];
  __shared__ float pr[NHEADS][TT];
  __shared__ float h0[FD];
  __shared__ float red[2];
  qs[f] = Q[(size_t)bt * FD + f];
  __syncthreads();
  const float* Kb = K + (size_t)b * TT * FD;
  const float sc = 0.17677669529663688f;  // 1/sqrt(32)
  for (int k = f; k < TT; k += FD) {
    float m = mask[b * TT + k];
    const float* kr = Kb + (size_t)k * FD;
    float s0 = 0.f, s1 = 0.f, s2 = 0.f, s3 = 0.f;
#pragma unroll
    for (int d = 0; d < DHEAD; d++) {
      s0 += qs[d] * kr[d];
      s1 += qs[DHEAD + d] * kr[DHEAD + d];
      s2 += qs[2 * DHEAD + d] * kr[2 * DHEAD + d];
      s3 += qs[3 * DHEAD + d] * kr[3 * DHEAD + d];
    }
    bool keep = m > 0.f;
    pr[0][k] = keep ? s0 * sc : -1e9f;
    pr[1][k] = keep ? s1 * sc : -1e9f;
    pr[2][k] = keep ? s2 * sc : -1e9f;
    pr[3][k] = keep ? s3 * sc : -1e9f;
  }
  __syncthreads();
  // masked softmax per head; head h = f>>5 handled by a 32-thread aligned group
  int h = f >> 5;
  int lane = f & 31;
  float mx = -1e30f;
  for (int k = lane; k < TT; k += 32) mx = fmaxf(mx, pr[h][k]);
#pragma unroll
  for (int o = 16; o > 0; o >>= 1) mx = fmaxf(mx, __shfl_xor(mx, o));
  float sm = 0.f;
  for (int k = lane; k < TT; k += 32) {
    float e = expf(pr[h][k] - mx);
    pr[h][k] = e;
    sm += e;
  }
#pragma unroll
  for (int o = 16; o > 0; o >>= 1) sm += __shfl_xor(sm, o);
  float inv = 1.f / sm;
  for (int k = lane; k < TT; k += 32) pr[h][k] *= inv;
  __syncthreads();
  // O = Q + A @ V
  const float* Vb = V + (size_t)b * TT * FD;
  float o = qs[f];
  for (int k = 0; k < TT; k++) o += pr[h][k] * Vb[(size_t)k * FD + f];
  // LN0
  float s1r = bsum128(o, red);
  float s2r = bsum128(o * o, red);
  float mean = s1r * (1.f / 128.f);
  float var = s2r * (1.f / 128.f) - mean * mean;
  float y = (o - mean) * rsqrtf(var + 1e-5f) * g0[f] + be0[f];
  h0[f] = y;
  __syncthreads();
  // FFN: y + relu(y @ wo + bo)
  float acc = bo[f];
  for (int i = 0; i < FD; i++) acc += h0[i] * wo[(size_t)i * FD + f];
  float z = y + fmaxf(acc, 0.f);
  // LN1
  s1r = bsum128(z, red);
  s2r = bsum128(z * z, red);
  mean = s1r * (1.f / 128.f);
  var = s2r * (1.f / 128.f) - mean * mean;
  float r = (z - mean) * rsqrtf(var + 1e-5f) * g1[f] + be1[f];
  Xp[(size_t)bt * FD + f] = r * mask[bt];
}

// ---- Xp2 = (Xp @ wti + bti) * m ; s = Xp2 @ was + bas ----
__global__ void ti_k(const float* __restrict__ Xp,
                     const float* __restrict__ wti, const float* __restrict__ bti,
                     const float* __restrict__ was, const float* __restrict__ bas,
                     const float* __restrict__ mask,
                     float* __restrict__ Xp2, float* __restrict__ S) {
  int bt = blockIdx.x;
  int f = threadIdx.x;
  __shared__ float xs[FD];
  __shared__ float x2[FD];
  xs[f] = Xp[(size_t)bt * FD + f];
  __syncthreads();
  float acc = bti[f];
  for (int i = 0; i < FD; i++) acc += xs[i] * wti[i * FD + f];
  acc *= mask[bt];
  Xp2[(size_t)bt * FD + f] = acc;
  x2[f] = acc;
  __syncthreads();
  if (f < NAGG) {
    float s = bas[f];
    for (int i = 0; i < FD; i++) s += x2[i] * was[i * NAGG + f];
    S[(size_t)bt * NAGG + f] = s;
  }
}

// ---- softmax over T per (b,a); att stored [b][a][t] ----
__global__ void soft_t(const float* __restrict__ S, const float* __restrict__ mask,
                       float* __restrict__ att) {
  int b = blockIdx.x >> 5, a = blockIdx.x & 31;
  int tid = threadIdx.x;  // 256
  __shared__ float e_s[TT];
  __shared__ float red[4];
  float mx = -1e30f;
  for (int t = tid; t < TT; t += 256) mx = fmaxf(mx, S[((size_t)b * TT + t) * NAGG + a]);
#pragma unroll
  for (int o = 32; o > 0; o >>= 1) mx = fmaxf(mx, __shfl_xor(mx, o));
  if ((tid & 63) == 0) red[tid >> 6] = mx;
  __syncthreads();
  mx = fmaxf(fmaxf(red[0], red[1]), fmaxf(red[2], red[3]));
  __syncthreads();
  float sm = 0.f;
  for (int t = tid; t < TT; t += 256) {
    float m = mask[b * TT + t];
    float e = expf(S[((size_t)b * TT + t) * NAGG + a] - mx) * m;
    e_s[t] = e;
    sm += e;
  }
#pragma unroll
  for (int o = 32; o > 0; o >>= 1) sm += __shfl_xor(sm, o);
  if ((tid & 63) == 0) red[tid >> 6] = sm;
  __syncthreads();
  sm = red[0] + red[1] + red[2] + red[3];
  float inv = 1.f / (sm + 1e-16f);
  for (int t = tid; t < TT; t += 256) att[((size_t)b * NAGG + a) * TT + t] = e_s[t] * inv;
}

// ---- masked max/mean pooling over T of edges[a,f,t] = Xp2[t,f]*att[a,t] ----
__global__ void pool_k(const float* __restrict__ Xp2, const float* __restrict__ att,
                       const float* __restrict__ mask,
                       float* __restrict__ aggF, float* __restrict__ agg_out) {
  int b = blockIdx.x >> 5, a = blockIdx.x & 31;
  int f = threadIdx.x;  // 128
  __shared__ float att_s[TT];
  __shared__ float ms[TT];
  for (int t = f; t < TT; t += FD) {
    att_s[t] = att[((size_t)b * NAGG + a) * TT + t];
    ms[t] = mask[b * TT + t];
  }
  __syncthreads();
  float mn = 1e30f, mxm = -1e30f, sm = 0.f, nt = 0.f;
  int anyUn = 0;
  for (int t = 0; t < TT; t++) {
    float e = Xp2[((size_t)b * TT + t) * FD + f] * att_s[t];
    mn = fminf(mn, e);
    float m = ms[t];
    if (m > 0.f) { mxm = fmaxf(mxm, e); sm += e; nt += 1.f; }
    else anyUn = 1;
  }
  float mp = anyUn ? fmaxf(mxm, mn - 1.f) : mxm;
  float mean = sm / (nt == 0.f ? 1.f : nt);
  size_t base = (size_t)b * 8192 + (size_t)a * 256;
  aggF[base + f] = mp;
  aggF[base + 128 + f] = mean;
  agg_out[base + f] = mp;
  agg_out[base + 128 + f] = mean;
}

// ---- per-batch agg @ wto[144:,:] ----
__global__ void aggmm_k(const float* __restrict__ aggF, const float* __restrict__ wto,
                        float* __restrict__ aggterm) {
  int b = blockIdx.x;
  int f = threadIdx.x;
  __shared__ float ag[8192];
  for (int j = f; j < 8192; j += FD) ag[j] = aggF[(size_t)b * 8192 + j];
  __syncthreads();
  const float* w = wto + (size_t)(IND + FD) * FD;
  float acc = 0.f;
  for (int j = 0; j < 8192; j++) acc += ag[j] * w[(size_t)j * FD + f];
  aggterm[b * FD + f] = acc;
}

// ---- final: relu(LN(X@wto_x + Xp2@wto_p + aggterm + bto)) * m ----
__global__ void final_k(const float* __restrict__ X, const float* __restrict__ Xp2,
                        const float* __restrict__ aggterm,
                        const float* __restrict__ wto, const float* __restrict__ bto,
                        const float* __restrict__ gto, const float* __restrict__ btoln,
                        const float* __restrict__ mask, float* __restrict__ out) {
  int bt = blockIdx.x;
  int b = bt >> 9;
  int f = threadIdx.x;
  __shared__ float xs[IND];
  __shared__ float xp[FD];
  __shared__ float red[2];
  if (f < IND) xs[f] = X[(size_t)bt * IND + f];
  xp[f] = Xp2[(size_t)bt * FD + f];
  __syncthreads();
  float acc = bto[f] + aggterm[b * FD + f];
#pragma unroll
  for (int i = 0; i < IND; i++) acc += xs[i] * wto[i * FD + f];
  for (int i = 0; i < FD; i++) acc += xp[i] * wto[(IND + i) * FD + f];
  float s1r = bsum128(acc, red);
  float s2r = bsum128(acc * acc, red);
  float mean = s1r * (1.f / 128.f);
  float var = s2r * (1.f / 128.f) - mean * mean;
  float y = (acc - mean) * rsqrtf(var + 1e-5f) * gto[f] + btoln[f];
  y = fmaxf(y, 0.f) * mask[bt];
  out[(size_t)bt * FD + f] = y;
}

extern "C" void kernel_launch(void* const* d_in, const int* in_sizes, int n_in,
                              void* d_out, int out_size, void* d_ws, size_t ws_size,
                              hipStream_t stream) {
  const float* X    = (const float*)d_in[0];
  const float* mask = (const float*)d_in[1];
  const float* wq0 = (const float*)d_in[2];  const float* bq0 = (const float*)d_in[3];
  const float* wk0 = (const float*)d_in[4];  const float* bk0 = (const float*)d_in[5];
  const float* wv0 = (const float*)d_in[6];  const float* bv0 = (const float*)d_in[7];
  const float* wo0 = (const float*)d_in[8];  const float* bo0 = (const float*)d_in[9];
  const float* g00 = (const float*)d_in[10]; const float* be00 = (const float*)d_in[11];
  const float* g10 = (const float*)d_in[12]; const float* be10 = (const float*)d_in[13];
  const float* wq1 = (const float*)d_in[14]; const float* bq1 = (const float*)d_in[15];
  const float* wk1 = (const float*)d_in[16]; const float* bk1 = (const float*)d_in[17];
  const float* wv1 = (const float*)d_in[18]; const float* bv1 = (const float*)d_in[19];
  const float* wo1 = (const float*)d_in[20]; const float* bo1 = (const float*)d_in[21];
  const float* g01 = (const float*)d_in[22]; const float* be01 = (const float*)d_in[23];
  const float* g11 = (const float*)d_in[24]; const float* be11 = (const float*)d_in[25];
  const float* wti = (const float*)d_in[26]; const float* bti = (const float*)d_in[27];
  const float* was = (const float*)d_in[28]; const float* bas = (const float*)d_in[29];
  const float* wto = (const float*)d_in[30]; const float* bto = (const float*)d_in[31];
  const float* gto = (const float*)d_in[32]; const float* btoln = (const float*)d_in[33];

  const size_t BIG = (size_t)BB * TT * FD;  // 2,097,152 floats
  float* ws = (float*)d_ws;
  float* Q  = ws;
  float* K  = ws + BIG;
  float* V  = ws + 2 * BIG;
  float* Xp = ws + 3 * BIG;
  // reuse after SABs:
  float* Xp2 = Q;
  float* S   = K;
  float* att = V;
  float* aggF    = Xp;
  float* aggterm = Xp + 262144 + 1024;

  float* out_main = (float*)d_out;
  float* out_agg  = (float*)d_out + BIG;  // B*T*F elements then B*8192

  int nbt = BB * TT;
  proj16_k<<<nbt, 128, 0, stream>>>(X, wq0, bq0, wk0, bk0, wv0, bv0, Q, K, V);
  sab_core<<<nbt, 128, 0, stream>>>(Q, K, V, mask, wo0, bo0, g00, be00, g10, be10, Xp);
  proj128_k<<<nbt, 128, 0, stream>>>(Xp, wq1, bq1, wk1, bk1, wv1, bv1, Q, K, V);
  sab_core<<<nbt, 128, 0, stream>>>(Q, K, V, mask, wo1, bo1, g01, be01, g11, be11, Xp);
  ti_k<<<nbt, 128, 0, stream>>>(Xp, wti, bti, was, bas, mask, Xp2, S);
  soft_t<<<BB * NAGG, 256, 0, stream>>>(S, mask, att);
  pool_k<<<BB * NAGG, 128, 0, stream>>>(Xp2, att, mask, aggF, out_agg);
  aggmm_k<<<BB, 128, 0, stream>>>(aggF, wto, aggterm);
  final_k<<<nbt, 128, 0, stream>>>(X, Xp2, aggterm, wto, bto, gto, btoln, mask, out_main);
}

// Round 4
// 793.548 us; speedup vs baseline: 3.3815x; 3.3815x over previous
//
#include <hip/hip_runtime.h>
#include <hip/hip_bf16.h>

#define BB 32
#define TT 512
#define IND 16
#define FD 128
#define NAGG 32
#define NHEADS 4
#define DHEAD 32
#define QB 32
#define KB 32

// block = 128 threads (2 waves). Sum across block.
__device__ __forceinline__ float bsum128(float v, float* red) {
#pragma unroll
  for (int o = 32; o > 0; o >>= 1) v += __shfl_xor(v, o);
  if ((threadIdx.x & 63) == 0) red[threadIdx.x >> 6] = v;
  __syncthreads();
  float r = red[0] + red[1];
  __syncthreads();
  return r;
}

// ---- QKV projection from 16-dim input ----
__global__ void proj16_k(const float* __restrict__ X,
                         const float* __restrict__ wq, const float* __restrict__ bq,
                         const float* __restrict__ wk, const float* __restrict__ bk,
                         const float* __restrict__ wv, const float* __restrict__ bv,
                         float* __restrict__ Q, float* __restrict__ K, float* __restrict__ V) {
  int bt = blockIdx.x;
  int f = threadIdx.x;
  __shared__ float xs[IND];
  if (f < IND) xs[f] = X[(size_t)bt * IND + f];
  __syncthreads();
  float q = bq[f], k = bk[f], v = bv[f];
#pragma unroll
  for (int i = 0; i < IND; i++) {
    float x = xs[i];
    q += x * wq[i * FD + f];
    k += x * wk[i * FD + f];
    v += x * wv[i * FD + f];
  }
  size_t o = (size_t)bt * FD + f;
  Q[o] = q; K[o] = k; V[o] = v;
}

// ---- QKV projection from 128-dim fp32 input ----
__global__ void proj128_k(const float* __restrict__ Xin,
                          const float* __restrict__ wq, const float* __restrict__ bq,
                          const float* __restrict__ wk, const float* __restrict__ bk,
                          const float* __restrict__ wv, const float* __restrict__ bv,
                          float* __restrict__ Q, float* __restrict__ K, float* __restrict__ V) {
  int bt = blockIdx.x;
  int f = threadIdx.x;
  __shared__ float xs[FD];
  xs[f] = Xin[(size_t)bt * FD + f];
  __syncthreads();
  float q = bq[f], k = bk[f], v = bv[f];
#pragma unroll 16
  for (int i = 0; i < FD; i++) {
    float x = xs[i];
    q += x * wq[i * FD + f];
    k += x * wk[i * FD + f];
    v += x * wv[i * FD + f];
  }
  size_t o = (size_t)bt * FD + f;
  Q[o] = q; K[o] = k; V[o] = v;
}

// ---- Q-tiled flash attention: Ores = Q + softmax(QK^T/sqrt(dh), mask)@V ----
// grid: BB * (TT/QB) = 512 blocks, 256 threads.
// LDS layout: q_s/k_s/v_s idx = row*133 + h*33 + d (h<4, d<32); s_s = [(q*4+h)*33 + k]
__global__ __launch_bounds__(256, 2) void attn_k(const float* __restrict__ Q,
                                                 const float* __restrict__ K,
                                                 const float* __restrict__ V,
                                                 const float* __restrict__ mask,
                                                 float* __restrict__ Ores) {
  int b = blockIdx.x >> 4;
  int qt = blockIdx.x & 15;
  int tid = threadIdx.x;
  __shared__ float q_s[QB * 133];
  __shared__ float k_s[KB * 133];
  __shared__ float v_s[KB * 133];
  __shared__ float s_s[128 * 33];  // scores; reused as output staging [32*132]
  __shared__ float m_s[QB * 4], l_s[QB * 4], sc_s[QB * 4];
  __shared__ float msk_s[KB];
  const float scale = 0.17677669529663688f;  // 1/sqrt(32)

  int r = tid >> 3, c = tid & 7;  // staging map: row r, 16-float chunk c
  size_t qrow = ((size_t)(b * TT + qt * QB + r)) * FD + c * 16;
  {
    const float4* src = (const float4*)(Q + qrow);
#pragma unroll
    for (int jj = 0; jj < 4; jj++) {
      float4 v4 = src[jj];
      int col = c * 16 + jj * 4;
      float* dst = &q_s[r * 133 + (col >> 5) * 33 + (col & 31)];
      dst[0] = v4.x; dst[1] = v4.y; dst[2] = v4.z; dst[3] = v4.w;
    }
  }
  if (tid < 128) { m_s[tid] = -1e30f; l_s[tid] = 0.f; }
  float o_acc[16];
#pragma unroll
  for (int i = 0; i < 16; i++) o_acc[i] = 0.f;

  // score mapping: 2 q * 1 head * 8 k per thread
  int qg = tid >> 4;          // 0..15 -> q pair {2qg, 2qg+1}
  int g = tid & 15;
  int sh = g >> 2;            // head
  int sk = (g & 3) * 8;       // k base
  // AV mapping: q = aq, d = ag + 8i
  int aq = tid >> 3;
  int ag = tid & 7;

  for (int kt = 0; kt < 16; kt++) {
    __syncthreads();
    {  // stage K,V tile
      size_t krow = ((size_t)(b * TT + kt * KB + r)) * FD + c * 16;
      const float4* ksrc = (const float4*)(K + krow);
      const float4* vsrc = (const float4*)(V + krow);
#pragma unroll
      for (int jj = 0; jj < 4; jj++) {
        float4 kv = ksrc[jj];
        float4 vv = vsrc[jj];
        int col = c * 16 + jj * 4;
        int off = r * 133 + (col >> 5) * 33 + (col & 31);
        float* kd = &k_s[off];
        float* vd = &v_s[off];
        kd[0] = kv.x; kd[1] = kv.y; kd[2] = kv.z; kd[3] = kv.w;
        vd[0] = vv.x; vd[1] = vv.y; vd[2] = vv.z; vd[3] = vv.w;
      }
      if (tid < KB) msk_s[tid] = mask[b * TT + kt * KB + tid];
    }
    __syncthreads();
    {  // scores
      float acc0[8], acc1[8];
#pragma unroll
      for (int j = 0; j < 8; j++) { acc0[j] = 0.f; acc1[j] = 0.f; }
      const float* q0 = &q_s[(2 * qg) * 133 + sh * 33];
      const float* q1 = q0 + 133;
      const float* kb = &k_s[sk * 133 + sh * 33];
#pragma unroll 8
      for (int d = 0; d < 32; d++) {
        float a0 = q0[d], a1 = q1[d];
#pragma unroll
        for (int j = 0; j < 8; j++) {
          float kv = kb[j * 133 + d];
          acc0[j] += a0 * kv;
          acc1[j] += a1 * kv;
        }
      }
#pragma unroll
      for (int j = 0; j < 8; j++) {
        bool keep = msk_s[sk + j] > 0.f;
        s_s[(2 * qg * 4 + sh) * 33 + sk + j] = keep ? acc0[j] * scale : -1e9f;
        s_s[((2 * qg + 1) * 4 + sh) * 33 + sk + j] = keep ? acc1[j] * scale : -1e9f;
      }
    }
    __syncthreads();
    if (tid < 128) {  // online softmax update per (q,h)
      float* row = &s_s[tid * 33];
      float mo = m_s[tid];
      float tm = mo;
#pragma unroll 8
      for (int k = 0; k < KB; k++) tm = fmaxf(tm, row[k]);
      float sc = __expf(mo - tm);
      float l = l_s[tid] * sc;
#pragma unroll 8
      for (int k = 0; k < KB; k++) {
        float p = __expf(row[k] - tm);
        row[k] = p;
        l += p;
      }
      m_s[tid] = tm; l_s[tid] = l; sc_s[tid] = sc;
    }
    __syncthreads();
    {  // O update
#pragma unroll
      for (int hh = 0; hh < 4; hh++) {
        float scv = sc_s[aq * 4 + hh];
        const float* pr = &s_s[(aq * 4 + hh) * 33];
        const float* vb = &v_s[hh * 33];
        float a0 = o_acc[hh * 4 + 0] * scv;
        float a1 = o_acc[hh * 4 + 1] * scv;
        float a2 = o_acc[hh * 4 + 2] * scv;
        float a3 = o_acc[hh * 4 + 3] * scv;
#pragma unroll 8
        for (int k = 0; k < KB; k++) {
          float pk = pr[k];
          const float* vr = vb + k * 133 + ag;
          a0 += pk * vr[0];
          a1 += pk * vr[8];
          a2 += pk * vr[16];
          a3 += pk * vr[24];
        }
        o_acc[hh * 4 + 0] = a0; o_acc[hh * 4 + 1] = a1;
        o_acc[hh * 4 + 2] = a2; o_acc[hh * 4 + 3] = a3;
      }
    }
  }
  __syncthreads();
  {  // finalize: o = q + o/l, stage to s_s flat [q*132 + d]
#pragma unroll
    for (int i = 0; i < 16; i++) {
      int d = ag + 8 * i;
      int h = d >> 5;
      float l = l_s[aq * 4 + h];
      float qv = q_s[aq * 133 + h * 33 + (d & 31)];
      s_s[aq * 132 + d] = qv + o_acc[i] / l;
    }
  }
  __syncthreads();
  {  // coalesced store
    float* dst = Ores + qrow;
    const float* srcp = &s_s[r * 132 + c * 16];
#pragma unroll
    for (int jj = 0; jj < 4; jj++) {
      *(float4*)(dst + jj * 4) = *(const float4*)(srcp + jj * 4);
    }
  }
}

// ---- post: LN0 -> FFN -> LN1 -> *mask, one block per (b,t) ----
__global__ void post_k(const float* __restrict__ Ores, const float* __restrict__ mask,
                       const float* __restrict__ wo, const float* __restrict__ bo,
                       const float* __restrict__ g0, const float* __restrict__ be0,
                       const float* __restrict__ g1, const float* __restrict__ be1,
                       float* __restrict__ Xp) {
  int bt = blockIdx.x;
  int f = threadIdx.x;
  __shared__ float h0[FD];
  __shared__ float red[2];
  float o = Ores[(size_t)bt * FD + f];
  float s1r = bsum128(o, red);
  float s2r = bsum128(o * o, red);
  float mean = s1r * (1.f / 128.f);
  float var = s2r * (1.f / 128.f) - mean * mean;
  float y = (o - mean) * rsqrtf(var + 1e-5f) * g0[f] + be0[f];
  h0[f] = y;
  __syncthreads();
  float acc = bo[f];
#pragma unroll 16
  for (int i = 0; i < FD; i++) acc += h0[i] * wo[(size_t)i * FD + f];
  float z = y + fmaxf(acc, 0.f);
  s1r = bsum128(z, red);
  s2r = bsum128(z * z, red);
  mean = s1r * (1.f / 128.f);
  var = s2r * (1.f / 128.f) - mean * mean;
  float rr = (z - mean) * rsqrtf(var + 1e-5f) * g1[f] + be1[f];
  Xp[(size_t)bt * FD + f] = rr * mask[bt];
}

// ---- Xp2 = (Xp @ wti + bti) * m ; s = Xp2 @ was + bas ----
__global__ void ti_k(const float* __restrict__ Xp,
                     const float* __restrict__ wti, const float* __restrict__ bti,
                     const float* __restrict__ was, const float* __restrict__ bas,
                     const float* __restrict__ mask,
                     float* __restrict__ Xp2, float* __restrict__ S) {
  int bt = blockIdx.x;
  int f = threadIdx.x;
  __shared__ float xs[FD];
  __shared__ float x2[FD];
  xs[f] = Xp[(size_t)bt * FD + f];
  __syncthreads();
  float acc = bti[f];
#pragma unroll 16
  for (int i = 0; i < FD; i++) acc += xs[i] * wti[i * FD + f];
  acc *= mask[bt];
  Xp2[(size_t)bt * FD + f] = acc;
  x2[f] = acc;
  __syncthreads();
  if (f < NAGG) {
    float s = bas[f];
#pragma unroll 16
    for (int i = 0; i < FD; i++) s += x2[i] * was[i * NAGG + f];
    S[(size_t)bt * NAGG + f] = s;
  }
}

// ---- softmax over T per (b,a); att stored [b][a][t] ----
__global__ void soft_t(const float* __restrict__ S, const float* __restrict__ mask,
                       float* __restrict__ att) {
  int b = blockIdx.x >> 5, a = blockIdx.x & 31;
  int tid = threadIdx.x;  // 256
  __shared__ float e_s[TT];
  __shared__ float red[4];
  float mx = -1e30f;
  for (int t = tid; t < TT; t += 256) mx = fmaxf(mx, S[((size_t)b * TT + t) * NAGG + a]);
#pragma unroll
  for (int o = 32; o > 0; o >>= 1) mx = fmaxf(mx, __shfl_xor(mx, o));
  if ((tid & 63) == 0) red[tid >> 6] = mx;
  __syncthreads();
  mx = fmaxf(fmaxf(red[0], red[1]), fmaxf(red[2], red[3]));
  __syncthreads();
  float sm = 0.f;
  for (int t = tid; t < TT; t += 256) {
    float m = mask[b * TT + t];
    float e = __expf(S[((size_t)b * TT + t) * NAGG + a] - mx) * m;
    e_s[t] = e;
    sm += e;
  }
#pragma unroll
  for (int o = 32; o > 0; o >>= 1) sm += __shfl_xor(sm, o);
  if ((tid & 63) == 0) red[tid >> 6] = sm;
  __syncthreads();
  sm = red[0] + red[1] + red[2] + red[3];
  float inv = 1.f / (sm + 1e-16f);
  for (int t = tid; t < TT; t += 256) att[((size_t)b * NAGG + a) * TT + t] = e_s[t] * inv;
}

// ---- masked max/mean pooling over T of edges[a,f,t] = Xp2[t,f]*att[a,t] ----
__global__ void pool_k(const float* __restrict__ Xp2, const float* __restrict__ att,
                       const float* __restrict__ mask,
                       float* __restrict__ aggF, float* __restrict__ agg_out) {
  int b = blockIdx.x >> 5, a = blockIdx.x & 31;
  int f = threadIdx.x;  // 128
  __shared__ float att_s[TT];
  __shared__ float ms[TT];
  for (int t = f; t < TT; t += FD) {
    att_s[t] = att[((size_t)b * NAGG + a) * TT + t];
    ms[t] = mask[b * TT + t];
  }
  __syncthreads();
  float mn = 1e30f, mxm = -1e30f, sm = 0.f, nt = 0.f;
  int anyUn = 0;
#pragma unroll 4
  for (int t = 0; t < TT; t++) {
    float e = Xp2[((size_t)b * TT + t) * FD + f] * att_s[t];
    mn = fminf(mn, e);
    float m = ms[t];
    if (m > 0.f) { mxm = fmaxf(mxm, e); sm += e; nt += 1.f; }
    else anyUn = 1;
  }
  float mp = anyUn ? fmaxf(mxm, mn - 1.f) : mxm;
  float mean = sm / (nt == 0.f ? 1.f : nt);
  size_t base = (size_t)b * 8192 + (size_t)a * 256;
  aggF[base + f] = mp;
  aggF[base + 128 + f] = mean;
  agg_out[base + f] = mp;
  agg_out[base + 128 + f] = mean;
}

// ---- per-batch agg @ wto[144:,:], split into 8 j-chunks of 1024 ----
__global__ void aggmm_k(const float* __restrict__ aggF, const float* __restrict__ wto,
                        float* __restrict__ part) {
  int b = blockIdx.x >> 3, cc = blockIdx.x & 7;
  int f = threadIdx.x;
  __shared__ float ag[1024];
  for (int j = f; j < 1024; j += FD) ag[j] = aggF[(size_t)b * 8192 + cc * 1024 + j];
  __syncthreads();
  const float* w = wto + ((size_t)(IND + FD) + cc * 1024) * FD;
  float acc = 0.f;
#pragma unroll 8
  for (int j = 0; j < 1024; j++) acc += ag[j] * w[(size_t)j * FD + f];
  part[(size_t)(b * 8 + cc) * FD + f] = acc;
}

// ---- final: relu(LN(X@wto_x + Xp2@wto_p + sum(part) + bto)) * m ----
__global__ void final_k(const float* __restrict__ X, const float* __restrict__ Xp2,
                        const float* __restrict__ part,
                        const float* __restrict__ wto, const float* __restrict__ bto,
                        const float* __restrict__ gto, const float* __restrict__ btoln,
                        const float* __restrict__ mask, float* __restrict__ out) {
  int bt = blockIdx.x;
  int b = bt >> 9;
  int f = threadIdx.x;
  __shared__ float xs[IND];
  __shared__ float xp[FD];
  __shared__ float red[2];
  if (f < IND) xs[f] = X[(size_t)bt * IND + f];
  xp[f] = Xp2[(size_t)bt * FD + f];
  __syncthreads();
  float acc = bto[f];
#pragma unroll
  for (int cc = 0; cc < 8; cc++) acc += part[(size_t)(b * 8 + cc) * FD + f];
#pragma unroll
  for (int i = 0; i < IND; i++) acc += xs[i] * wto[i * FD + f];
#pragma unroll 16
  for (int i = 0; i < FD; i++) acc += xp[i] * wto[(IND + i) * FD + f];
  float s1r = bsum128(acc, red);
  float s2r = bsum128(acc * acc, red);
  float mean = s1r * (1.f / 128.f);
  float var = s2r * (1.f / 128.f) - mean * mean;
  float y = (acc - mean) * rsqrtf(var + 1e-5f) * gto[f] + btoln[f];
  y = fmaxf(y, 0.f) * mask[bt];
  out[(size_t)bt * FD + f] = y;
}

extern "C" void kernel_launch(void* const* d_in, const int* in_sizes, int n_in,
                              void* d_out, int out_size, void* d_ws, size_t ws_size,
                              hipStream_t stream) {
  const float* X    = (const float*)d_in[0];
  const float* mask = (const float*)d_in[1];
  const float* wq0 = (const float*)d_in[2];  const float* bq0 = (const float*)d_in[3];
  const float* wk0 = (const float*)d_in[4];  const float* bk0 = (const float*)d_in[5];
  const float* wv0 = (const float*)d_in[6];  const float* bv0 = (const float*)d_in[7];
  const float* wo0 = (const float*)d_in[8];  const float* bo0 = (const float*)d_in[9];
  const float* g00 = (const float*)d_in[10]; const float* be00 = (const float*)d_in[11];
  const float* g10 = (const float*)d_in[12]; const float* be10 = (const float*)d_in[13];
  const float* wq1 = (const float*)d_in[14]; const float* bq1 = (const float*)d_in[15];
  const float* wk1 = (const float*)d_in[16]; const float* bk1 = (const float*)d_in[17];
  const float* wv1 = (const float*)d_in[18]; const float* bv1 = (const float*)d_in[19];
  const float* wo1 = (const float*)d_in[20]; const float* bo1 = (const float*)d_in[21];
  const float* g01 = (const float*)d_in[22]; const float* be01 = (const float*)d_in[23];
  const float* g11 = (const float*)d_in[24]; const float* be11 = (const float*)d_in[25];
  const float* wti = (const float*)d_in[26]; const float* bti = (const float*)d_in[27];
  const float* was = (const float*)d_in[28]; const float* bas = (const float*)d_in[29];
  const float* wto = (const float*)d_in[30]; const float* bto = (const float*)d_in[31];
  const float* gto = (const float*)d_in[32]; const float* btoln = (const float*)d_in[33];

  const size_t BIG = (size_t)BB * TT * FD;  // 2,097,152 floats
  float* ws = (float*)d_ws;
  float* Q  = ws;
  float* K  = ws + BIG;
  float* V  = ws + 2 * BIG;
  float* Xp = ws + 3 * BIG;
  float* Ores = Q;               // in-place: attn reads its Q rows first
  // reuse after SABs:
  float* Xp2 = K;
  float* S   = V;
  float* att = V + 524288;
  float* aggF = Xp;
  float* part = Xp + 262144;

  float* out_main = (float*)d_out;
  float* out_agg  = (float*)d_out + BIG;

  int nbt = BB * TT;
  proj16_k<<<nbt, 128, 0, stream>>>(X, wq0, bq0, wk0, bk0, wv0, bv0, Q, K, V);
  attn_k<<<BB * (TT / QB), 256, 0, stream>>>(Q, K, V, mask, Ores);
  post_k<<<nbt, 128, 0, stream>>>(Ores, mask, wo0, bo0, g00, be00, g10, be10, Xp);
  proj128_k<<<nbt, 128, 0, stream>>>(Xp, wq1, bq1, wk1, bk1, wv1, bv1, Q, K, V);
  attn_k<<<BB * (TT / QB), 256, 0, stream>>>(Q, K, V, mask, Ores);
  post_k<<<nbt, 128, 0, stream>>>(Ores, mask, wo1, bo1, g01, be01, g11, be11, Xp);
  ti_k<<<nbt, 128, 0, stream>>>(Xp, wti, bti, was, bas, mask, Xp2, S);
  soft_t<<<BB * NAGG, 256, 0, stream>>>(S, mask, att);
  pool_k<<<BB * NAGG, 128, 0, stream>>>(Xp2, att, mask, aggF, out_agg);
  aggmm_k<<<BB * 8, 128, 0, stream>>>(aggF, wto, part);
  final_k<<<nbt, 128, 0, stream>>>(X, Xp2, part, wto, bto, gto, btoln, mask, out_main);
}

// Round 5
// 434.576 us; speedup vs baseline: 6.1746x; 1.8260x over previous
//
#include <hip/hip_runtime.h>
#include <hip/hip_bf16.h>

#define BB 32
#define TT 512
#define IND 16
#define FD 128
#define NAGG 32

// ---- proj16, row-tiled: 8 rows/block ----
__global__ void proj16_k(const float* __restrict__ X,
                         const float* __restrict__ wq, const float* __restrict__ bq,
                         const float* __restrict__ wk, const float* __restrict__ bk,
                         const float* __restrict__ wv, const float* __restrict__ bv,
                         float* __restrict__ Q, float* __restrict__ K, float* __restrict__ V) {
  int base = blockIdx.x * 8;
  int f = threadIdx.x;
  __shared__ float xs[8][IND];
  {
    int rr = f >> 4, ii = f & 15;
    xs[rr][ii] = X[(size_t)(base + rr) * IND + ii];
  }
  __syncthreads();
  float qa[8], ka[8], va[8];
  float bqf = bq[f], bkf = bk[f], bvf = bv[f];
#pragma unroll
  for (int rr = 0; rr < 8; rr++) { qa[rr] = bqf; ka[rr] = bkf; va[rr] = bvf; }
#pragma unroll
  for (int i = 0; i < IND; i++) {
    float wqv = wq[i * FD + f], wkv = wk[i * FD + f], wvv = wv[i * FD + f];
#pragma unroll
    for (int rr = 0; rr < 8; rr++) {
      float x = xs[rr][i];
      qa[rr] += x * wqv; ka[rr] += x * wkv; va[rr] += x * wvv;
    }
  }
#pragma unroll
  for (int rr = 0; rr < 8; rr++) {
    size_t o = (size_t)(base + rr) * FD + f;
    Q[o] = qa[rr]; K[o] = ka[rr]; V[o] = va[rr];
  }
}

// ---- flash attention v2: 4q*4k score tiles w/ fused in-register softmax, 4q*4d AV ----
// grid BB*16, block 256. LDS rows stride 133 (+1 pad per 32-col head chunk).
__global__ __launch_bounds__(256, 2) void attn_k(const float* __restrict__ Q,
                                                 const float* __restrict__ K,
                                                 const float* __restrict__ V,
                                                 const float* __restrict__ mask,
                                                 float* __restrict__ Ores) {
  int b = blockIdx.x >> 4;
  int qt = blockIdx.x & 15;
  int tid = threadIdx.x;
  __shared__ float q_s[32 * 133];
  __shared__ float k_s[32 * 133];
  __shared__ float v_s[32 * 133];
  __shared__ float p_s[128 * 33];  // P rows [(q*4+h)*33 + k]; reused as out staging [q*132+d]
  __shared__ float m_s[128], l_s[128], sc_s[128];
  __shared__ float msk[32];
  const float scale = 0.17677669529663688f;  // 1/sqrt(32)

  int r = tid >> 3, c = tid & 7;
  size_t qrow = ((size_t)(b * TT + qt * 32 + r)) * FD + c * 16;
  {  // stage Q
    const float4* src = (const float4*)(Q + qrow);
#pragma unroll
    for (int jj = 0; jj < 4; jj++) {
      float4 v4 = src[jj];
      int col = c * 16 + jj * 4;
      float* dst = &q_s[r * 133 + (col >> 5) * 33 + (col & 31)];
      dst[0] = v4.x; dst[1] = v4.y; dst[2] = v4.z; dst[3] = v4.w;
    }
  }
  if (tid < 128) { m_s[tid] = -1e30f; l_s[tid] = 0.f; }
  float o_acc[4][4];
#pragma unroll
  for (int i = 0; i < 4; i++)
#pragma unroll
    for (int j = 0; j < 4; j++) o_acc[i][j] = 0.f;

  // score map: qg rows 4qg+i, head sh, ks 4sk+j
  int qg = tid >> 5, sh = (tid >> 3) & 3, sk = tid & 7;
  // AV map: rows 4aq+i, head hh, d cols dd..dd+3 (within head)
  int aq = tid >> 5, dq = tid & 31;
  int hh = dq >> 3, dd = (dq & 7) * 4;

  for (int kt = 0; kt < 16; kt++) {
    {  // stage K,V tile
      size_t krow = ((size_t)(b * TT + kt * 32 + r)) * FD + c * 16;
      const float4* ksrc = (const float4*)(K + krow);
      const float4* vsrc = (const float4*)(V + krow);
#pragma unroll
      for (int jj = 0; jj < 4; jj++) {
        float4 kv = ksrc[jj];
        float4 vv = vsrc[jj];
        int col = c * 16 + jj * 4;
        int off = r * 133 + (col >> 5) * 33 + (col & 31);
        float* kd = &k_s[off];
        float* vd = &v_s[off];
        kd[0] = kv.x; kd[1] = kv.y; kd[2] = kv.z; kd[3] = kv.w;
        vd[0] = vv.x; vd[1] = vv.y; vd[2] = vv.z; vd[3] = vv.w;
      }
      if (tid < 32) msk[tid] = mask[b * TT + kt * 32 + tid];
    }
    __syncthreads();
    {  // scores + fused online softmax
      float acc[4][4];
#pragma unroll
      for (int i = 0; i < 4; i++)
#pragma unroll
        for (int j = 0; j < 4; j++) acc[i][j] = 0.f;
      const float* qb = &q_s[(4 * qg) * 133 + sh * 33];
      const float* kb = &k_s[(4 * sk) * 133 + sh * 33];
#pragma unroll 4
      for (int d = 0; d < 32; d++) {
        float q0 = qb[d], q1 = qb[133 + d], q2 = qb[266 + d], q3 = qb[399 + d];
        float k0 = kb[d], k1 = kb[133 + d], k2 = kb[266 + d], k3 = kb[399 + d];
        acc[0][0] += q0 * k0; acc[0][1] += q0 * k1; acc[0][2] += q0 * k2; acc[0][3] += q0 * k3;
        acc[1][0] += q1 * k0; acc[1][1] += q1 * k1; acc[1][2] += q1 * k2; acc[1][3] += q1 * k3;
        acc[2][0] += q2 * k0; acc[2][1] += q2 * k1; acc[2][2] += q2 * k2; acc[2][3] += q2 * k3;
        acc[3][0] += q3 * k0; acc[3][1] += q3 * k1; acc[3][2] += q3 * k2; acc[3][3] += q3 * k3;
      }
      float km[4];
#pragma unroll
      for (int j = 0; j < 4; j++) km[j] = msk[4 * sk + j];
#pragma unroll
      for (int i = 0; i < 4; i++) {
        float s0 = km[0] > 0.f ? acc[i][0] * scale : -1e9f;
        float s1 = km[1] > 0.f ? acc[i][1] * scale : -1e9f;
        float s2 = km[2] > 0.f ? acc[i][2] * scale : -1e9f;
        float s3 = km[3] > 0.f ? acc[i][3] * scale : -1e9f;
        float tm = fmaxf(fmaxf(s0, s1), fmaxf(s2, s3));
        tm = fmaxf(tm, __shfl_xor(tm, 1));
        tm = fmaxf(tm, __shfl_xor(tm, 2));
        tm = fmaxf(tm, __shfl_xor(tm, 4));
        int idx = (4 * qg + i) * 4 + sh;
        float mo = m_s[idx];
        float mn = fmaxf(mo, tm);
        float p0 = __expf(s0 - mn), p1 = __expf(s1 - mn);
        float p2 = __expf(s2 - mn), p3 = __expf(s3 - mn);
        float* pw = &p_s[idx * 33 + 4 * sk];
        pw[0] = p0; pw[1] = p1; pw[2] = p2; pw[3] = p3;
        float ls = p0 + p1 + p2 + p3;
        ls += __shfl_xor(ls, 1);
        ls += __shfl_xor(ls, 2);
        ls += __shfl_xor(ls, 4);
        if (sk == 0) {
          float scv = __expf(mo - mn);
          m_s[idx] = mn;
          l_s[idx] = l_s[idx] * scv + ls;
          sc_s[idx] = scv;
        }
      }
    }
    __syncthreads();
    {  // AV accumulate
#pragma unroll
      for (int i = 0; i < 4; i++) {
        float scv = sc_s[(4 * aq + i) * 4 + hh];
#pragma unroll
        for (int j = 0; j < 4; j++) o_acc[i][j] *= scv;
      }
      const float* pb = &p_s[((4 * aq) * 4 + hh) * 33];
      const float* vb = &v_s[hh * 33 + dd];
#pragma unroll 4
      for (int k = 0; k < 32; k++) {
        float pv0 = pb[k], pv1 = pb[132 + k], pv2 = pb[264 + k], pv3 = pb[396 + k];
        const float* vr = vb + k * 133;
        float v0 = vr[0], v1 = vr[1], v2 = vr[2], v3 = vr[3];
        o_acc[0][0] += pv0 * v0; o_acc[0][1] += pv0 * v1; o_acc[0][2] += pv0 * v2; o_acc[0][3] += pv0 * v3;
        o_acc[1][0] += pv1 * v0; o_acc[1][1] += pv1 * v1; o_acc[1][2] += pv1 * v2; o_acc[1][3] += pv1 * v3;
        o_acc[2][0] += pv2 * v0; o_acc[2][1] += pv2 * v1; o_acc[2][2] += pv2 * v2; o_acc[2][3] += pv2 * v3;
        o_acc[3][0] += pv3 * v0; o_acc[3][1] += pv3 * v1; o_acc[3][2] += pv3 * v2; o_acc[3][3] += pv3 * v3;
      }
    }
    __syncthreads();
  }
  {  // finalize: o = q + o/l into staging
#pragma unroll
    for (int i = 0; i < 4; i++) {
      int row = 4 * aq + i;
      float inv = 1.f / l_s[row * 4 + hh];
#pragma unroll
      for (int j = 0; j < 4; j++) {
        float qv = q_s[row * 133 + hh * 33 + dd + j];
        p_s[row * 132 + hh * 32 + dd + j] = qv + o_acc[i][j] * inv;
      }
    }
  }
  __syncthreads();
  {  // coalesced store
    float* dst = Ores + qrow;
    const float* srcp = &p_s[r * 132 + c * 16];
#pragma unroll
    for (int jj = 0; jj < 4; jj++)
      *(float4*)(dst + jj * 4) = *(const float4*)(srcp + jj * 4);
  }
}

// wave-per-row LN helper: rows w*4+j over A, write to Bf scaled
__device__ __forceinline__ void ln_rows(const float (*A)[128], float (*Bf)[128],
                                        int lane, int w,
                                        float ga, float gb, float ba, float bb,
                                        const float* mk) {
  for (int j = 0; j < 4; j++) {
    int rr = w * 4 + j;
    float a = A[rr][lane], b2 = A[rr][lane + 64];
    float s = a + b2, ss = a * a + b2 * b2;
#pragma unroll
    for (int o = 32; o > 0; o >>= 1) { s += __shfl_xor(s, o); ss += __shfl_xor(ss, o); }
    float mean = s * (1.f / 128.f);
    float var = ss * (1.f / 128.f) - mean * mean;
    float rs = rsqrtf(var + 1e-5f);
    float m = mk ? mk[rr] : 1.f;
    Bf[rr][lane] = ((a - mean) * rs * ga + ba) * m;
    Bf[rr][lane + 64] = ((b2 - mean) * rs * gb + bb) * m;
  }
}

// ---- post(layer1) + proj128(layer2): 8 rows/block ----
__global__ void post_proj_k(const float* __restrict__ Ores, const float* __restrict__ mask,
                            const float* __restrict__ wo, const float* __restrict__ bo,
                            const float* __restrict__ g0, const float* __restrict__ be0,
                            const float* __restrict__ g1, const float* __restrict__ be1,
                            const float* __restrict__ wq, const float* __restrict__ bq,
                            const float* __restrict__ wk, const float* __restrict__ bk,
                            const float* __restrict__ wv, const float* __restrict__ bv,
                            float* __restrict__ Q, float* __restrict__ K, float* __restrict__ V) {
  int base = blockIdx.x * 8;
  int tid = threadIdx.x;
  int lane = tid & 63, w = tid >> 6;
  __shared__ float A[8][128];
  __shared__ float Bf[8][128];
  __shared__ float mk[8];
#pragma unroll
  for (int rr = 0; rr < 8; rr++) A[rr][tid] = Ores[(size_t)(base + rr) * FD + tid];
  if (tid < 8) mk[tid] = mask[base + tid];
  __syncthreads();
  ln_rows(A, Bf, lane, w, g0[lane], g0[lane + 64], be0[lane], be0[lane + 64], nullptr);
  __syncthreads();
  // FFN
  float acc[8];
  float bof = bo[tid];
#pragma unroll
  for (int rr = 0; rr < 8; rr++) acc[rr] = bof;
  for (int i = 0; i < 128; i++) {
    float wv_ = wo[i * 128 + tid];
#pragma unroll
    for (int rr = 0; rr < 8; rr++) acc[rr] += Bf[rr][i] * wv_;
  }
  __syncthreads();
#pragma unroll
  for (int rr = 0; rr < 8; rr++) A[rr][tid] = Bf[rr][tid] + fmaxf(acc[rr], 0.f);
  __syncthreads();
  ln_rows(A, Bf, lane, w, g1[lane], g1[lane + 64], be1[lane], be1[lane + 64], mk);
  __syncthreads();
  // proj to Q,K,V
  float qa[8], ka[8], va[8];
  float bqf = bq[tid], bkf = bk[tid], bvf = bv[tid];
#pragma unroll
  for (int rr = 0; rr < 8; rr++) { qa[rr] = bqf; ka[rr] = bkf; va[rr] = bvf; }
  for (int i = 0; i < 128; i++) {
    float wqv = wq[i * 128 + tid], wkv = wk[i * 128 + tid], wvv = wv[i * 128 + tid];
#pragma unroll
    for (int rr = 0; rr < 8; rr++) {
      float xv = Bf[rr][i];
      qa[rr] += xv * wqv; ka[rr] += xv * wkv; va[rr] += xv * wvv;
    }
  }
#pragma unroll
  for (int rr = 0; rr < 8; rr++) {
    size_t o = (size_t)(base + rr) * FD + tid;
    Q[o] = qa[rr]; K[o] = ka[rr]; V[o] = va[rr];
  }
}

// ---- post(layer2) + ti + as-score: 8 rows/block ----
__global__ void post_ti_k(const float* __restrict__ Ores, const float* __restrict__ mask,
                          const float* __restrict__ wo, const float* __restrict__ bo,
                          const float* __restrict__ g0, const float* __restrict__ be0,
                          const float* __restrict__ g1, const float* __restrict__ be1,
                          const float* __restrict__ wti, const float* __restrict__ bti,
                          const float* __restrict__ was, const float* __restrict__ bas,
                          float* __restrict__ Xp2, float* __restrict__ S) {
  int base = blockIdx.x * 8;
  int tid = threadIdx.x;
  int lane = tid & 63, w = tid >> 6;
  __shared__ float A[8][128];
  __shared__ float Bf[8][128];
  __shared__ float mk[8];
#pragma unroll
  for (int rr = 0; rr < 8; rr++) A[rr][tid] = Ores[(size_t)(base + rr) * FD + tid];
  if (tid < 8) mk[tid] = mask[base + tid];
  __syncthreads();
  ln_rows(A, Bf, lane, w, g0[lane], g0[lane + 64], be0[lane], be0[lane + 64], nullptr);
  __syncthreads();
  float acc[8];
  float bof = bo[tid];
#pragma unroll
  for (int rr = 0; rr < 8; rr++) acc[rr] = bof;
  for (int i = 0; i < 128; i++) {
    float wv_ = wo[i * 128 + tid];
#pragma unroll
    for (int rr = 0; rr < 8; rr++) acc[rr] += Bf[rr][i] * wv_;
  }
  __syncthreads();
#pragma unroll
  for (int rr = 0; rr < 8; rr++) A[rr][tid] = Bf[rr][tid] + fmaxf(acc[rr], 0.f);
  __syncthreads();
  ln_rows(A, Bf, lane, w, g1[lane], g1[lane + 64], be1[lane], be1[lane + 64], mk);
  __syncthreads();
  // ti: Xp2 = (xp @ wti + bti) * m
  float btif = bti[tid];
#pragma unroll
  for (int rr = 0; rr < 8; rr++) acc[rr] = btif;
  for (int i = 0; i < 128; i++) {
    float wv_ = wti[i * 128 + tid];
#pragma unroll
    for (int rr = 0; rr < 8; rr++) acc[rr] += Bf[rr][i] * wv_;
  }
#pragma unroll
  for (int rr = 0; rr < 8; rr++) {
    float x2 = acc[rr] * mk[rr];
    A[rr][tid] = x2;
    Xp2[(size_t)(base + rr) * FD + tid] = x2;
  }
  __syncthreads();
  // S = Xp2 @ was + bas  (thread: a = tid&31, rows 2rg,2rg+1)
  int a = tid & 31, rg = tid >> 5;
  float s0 = bas[a], s1 = s0;
  for (int i = 0; i < 128; i++) {
    float wv_ = was[i * NAGG + a];
    s0 += A[2 * rg][i] * wv_;
    s1 += A[2 * rg + 1][i] * wv_;
  }
  S[(size_t)(base + 2 * rg) * NAGG + a] = s0;
  S[(size_t)(base + 2 * rg + 1) * NAGG + a] = s1;
}

// ---- fused softmax-over-T + masked max/mean pooling: block per (b,a), 128 thr ----
__global__ void soft_pool_k(const float* __restrict__ S, const float* __restrict__ Xp2,
                            const float* __restrict__ mask,
                            float* __restrict__ aggF, float* __restrict__ agg_out) {
  int b = blockIdx.x >> 5, a = blockIdx.x & 31;
  int f = threadIdx.x;  // 128
  __shared__ float att_s[TT];
  __shared__ float ms[TT];
  __shared__ float red[2];
  float sv[4], mv[4];
#pragma unroll
  for (int j = 0; j < 4; j++) {
    int t = f + j * 128;
    sv[j] = S[(size_t)(b * TT + t) * NAGG + a];
    mv[j] = mask[b * TT + t];
    ms[t] = mv[j];
  }
  float mx = fmaxf(fmaxf(sv[0], sv[1]), fmaxf(sv[2], sv[3]));
#pragma unroll
  for (int o = 32; o > 0; o >>= 1) mx = fmaxf(mx, __shfl_xor(mx, o));
  if ((f & 63) == 0) red[f >> 6] = mx;
  __syncthreads();
  mx = fmaxf(red[0], red[1]);
  __syncthreads();
  float sm = 0.f;
#pragma unroll
  for (int j = 0; j < 4; j++) {
    float e = __expf(sv[j] - mx) * mv[j];
    att_s[f + j * 128] = e;
    sm += e;
  }
#pragma unroll
  for (int o = 32; o > 0; o >>= 1) sm += __shfl_xor(sm, o);
  if ((f & 63) == 0) red[f >> 6] = sm;
  __syncthreads();
  float inv = 1.f / (red[0] + red[1] + 1e-16f);
#pragma unroll
  for (int j = 0; j < 4; j++) att_s[f + j * 128] *= inv;
  __syncthreads();
  float mn = 1e30f, mxm = -1e30f, smv = 0.f, nt = 0.f;
  int anyUn = 0;
#pragma unroll 4
  for (int t = 0; t < TT; t++) {
    float e = Xp2[(size_t)(b * TT + t) * FD + f] * att_s[t];
    mn = fminf(mn, e);
    float m = ms[t];
    if (m > 0.f) { mxm = fmaxf(mxm, e); smv += e; nt += 1.f; }
    else anyUn = 1;
  }
  float mp = anyUn ? fmaxf(mxm, mn - 1.f) : mxm;
  float mean = smv / (nt == 0.f ? 1.f : nt);
  size_t bs = (size_t)b * 8192 + (size_t)a * 256;
  aggF[bs + f] = mp;
  aggF[bs + 128 + f] = mean;
  agg_out[bs + f] = mp;
  agg_out[bs + 128 + f] = mean;
}

// ---- per-batch agg @ wto[144:,:], split into 8 j-chunks of 1024 ----
__global__ void aggmm_k(const float* __restrict__ aggF, const float* __restrict__ wto,
                        float* __restrict__ part) {
  int b = blockIdx.x >> 3, cc = blockIdx.x & 7;
  int f = threadIdx.x;
  __shared__ float ag[1024];
  for (int j = f; j < 1024; j += FD) ag[j] = aggF[(size_t)b * 8192 + cc * 1024 + j];
  __syncthreads();
  const float* w = wto + ((size_t)(IND + FD) + cc * 1024) * FD;
  float acc = 0.f;
#pragma unroll 8
  for (int j = 0; j < 1024; j++) acc += ag[j] * w[(size_t)j * FD + f];
  part[(size_t)(b * 8 + cc) * FD + f] = acc;
}

// ---- final: relu(LN(X@wto_x + Xp2@wto_p + sum(part) + bto)) * m, 8 rows/block ----
__global__ void final_k(const float* __restrict__ X, const float* __restrict__ Xp2,
                        const float* __restrict__ part,
                        const float* __restrict__ wto, const float* __restrict__ bto,
                        const float* __restrict__ gto, const float* __restrict__ btoln,
                        const float* __restrict__ mask, float* __restrict__ out) {
  int base = blockIdx.x * 8;
  int b = base >> 9;
  int tid = threadIdx.x;
  int lane = tid & 63, w = tid >> 6;
  __shared__ float A[8][128];
  __shared__ float Bf[8][128];
  __shared__ float xss[8][16];
  __shared__ float mk[8];
#pragma unroll
  for (int rr = 0; rr < 8; rr++) Bf[rr][tid] = Xp2[(size_t)(base + rr) * FD + tid];
  {
    int rr = tid >> 4, ii = tid & 15;
    xss[rr][ii] = X[(size_t)(base + rr) * IND + ii];
  }
  if (tid < 8) mk[tid] = mask[base + tid];
  __syncthreads();
  float acc[8];
  float btof = bto[tid];
#pragma unroll
  for (int rr = 0; rr < 8; rr++) acc[rr] = btof;
#pragma unroll
  for (int cc = 0; cc < 8; cc++) {
    float pv = part[(size_t)(b * 8 + cc) * FD + tid];
#pragma unroll
    for (int rr = 0; rr < 8; rr++) if (cc == 0) acc[rr] += pv;  // placeholder avoided below
  }
  // (re-do parts accumulation correctly: sum of 8 part vectors, same for all rows)
  float psum = 0.f;
#pragma unroll
  for (int cc = 0; cc < 8; cc++) psum += part[(size_t)(b * 8 + cc) * FD + tid];
#pragma unroll
  for (int rr = 0; rr < 8; rr++) acc[rr] = btof + psum;
#pragma unroll
  for (int i = 0; i < IND; i++) {
    float wv_ = wto[i * FD + tid];
#pragma unroll
    for (int rr = 0; rr < 8; rr++) acc[rr] += xss[rr][i] * wv_;
  }
  for (int i = 0; i < 128; i++) {
    float wv_ = wto[(IND + i) * FD + tid];
#pragma unroll
    for (int rr = 0; rr < 8; rr++) acc[rr] += Bf[rr][i] * wv_;
  }
  __syncthreads();
#pragma unroll
  for (int rr = 0; rr < 8; rr++) A[rr][tid] = acc[rr];
  __syncthreads();
  // LN + relu + mask + store, wave-per-row
  float ga = gto[lane], gb = gto[lane + 64], ba = btoln[lane], bb = btoln[lane + 64];
  for (int j = 0; j < 4; j++) {
    int rr = w * 4 + j;
    float av = A[rr][lane], bv2 = A[rr][lane + 64];
    float s = av + bv2, ss = av * av + bv2 * bv2;
#pragma unroll
    for (int o = 32; o > 0; o >>= 1) { s += __shfl_xor(s, o); ss += __shfl_xor(ss, o); }
    float mean = s * (1.f / 128.f);
    float var = ss * (1.f / 128.f) - mean * mean;
    float rs = rsqrtf(var + 1e-5f);
    float m = mk[rr];
    out[(size_t)(base + rr) * FD + lane] = fmaxf((av - mean) * rs * ga + ba, 0.f) * m;
    out[(size_t)(base + rr) * FD + lane + 64] = fmaxf((bv2 - mean) * rs * gb + bb, 0.f) * m;
  }
}

extern "C" void kernel_launch(void* const* d_in, const int* in_sizes, int n_in,
                              void* d_out, int out_size, void* d_ws, size_t ws_size,
                              hipStream_t stream) {
  const float* X    = (const float*)d_in[0];
  const float* mask = (const float*)d_in[1];
  const float* wq0 = (const float*)d_in[2];  const float* bq0 = (const float*)d_in[3];
  const float* wk0 = (const float*)d_in[4];  const float* bk0 = (const float*)d_in[5];
  const float* wv0 = (const float*)d_in[6];  const float* bv0 = (const float*)d_in[7];
  const float* wo0 = (const float*)d_in[8];  const float* bo0 = (const float*)d_in[9];
  const float* g00 = (const float*)d_in[10]; const float* be00 = (const float*)d_in[11];
  const float* g10 = (const float*)d_in[12]; const float* be10 = (const float*)d_in[13];
  const float* wq1 = (const float*)d_in[14]; const float* bq1 = (const float*)d_in[15];
  const float* wk1 = (const float*)d_in[16]; const float* bk1 = (const float*)d_in[17];
  const float* wv1 = (const float*)d_in[18]; const float* bv1 = (const float*)d_in[19];
  const float* wo1 = (const float*)d_in[20]; const float* bo1 = (const float*)d_in[21];
  const float* g01 = (const float*)d_in[22]; const float* be01 = (const float*)d_in[23];
  const float* g11 = (const float*)d_in[24]; const float* be11 = (const float*)d_in[25];
  const float* wti = (const float*)d_in[26]; const float* bti = (const float*)d_in[27];
  const float* was = (const float*)d_in[28]; const float* bas = (const float*)d_in[29];
  const float* wto = (const float*)d_in[30]; const float* bto = (const float*)d_in[31];
  const float* gto = (const float*)d_in[32]; const float* btoln = (const float*)d_in[33];

  const size_t BIG = (size_t)BB * TT * FD;  // 2,097,152 floats
  float* ws = (float*)d_ws;
  float* Q  = ws;
  float* K  = ws + BIG;
  float* V  = ws + 2 * BIG;
  float* Xtra = ws + 3 * BIG;
  float* Ores = Q;        // in-place (row-local)
  float* Xp2 = K;         // after layer-2 attention K is dead
  float* S   = V;
  float* aggF = Xtra;
  float* part = Xtra + 262144;

  float* out_main = (float*)d_out;
  float* out_agg  = (float*)d_out + BIG;

  int nrb = BB * TT / 8;  // 2048 row-tiled blocks
  proj16_k<<<nrb, 128, 0, stream>>>(X, wq0, bq0, wk0, bk0, wv0, bv0, Q, K, V);
  attn_k<<<BB * 16, 256, 0, stream>>>(Q, K, V, mask, Ores);
  post_proj_k<<<nrb, 128, 0, stream>>>(Ores, mask, wo0, bo0, g00, be00, g10, be10,
                                       wq1, bq1, wk1, bk1, wv1, bv1, Q, K, V);
  attn_k<<<BB * 16, 256, 0, stream>>>(Q, K, V, mask, Ores);
  post_ti_k<<<nrb, 128, 0, stream>>>(Ores, mask, wo1, bo1, g01, be01, g11, be11,
                                     wti, bti, was, bas, Xp2, S);
  soft_pool_k<<<BB * NAGG, 128, 0, stream>>>(S, Xp2, mask, aggF, out_agg);
  aggmm_k<<<BB * 8, 128, 0, stream>>>(aggF, wto, part);
  final_k<<<nrb, 128, 0, stream>>>(X, Xp2, part, wto, bto, gto, btoln, mask, out_main);
}

// Round 6
// 323.601 us; speedup vs baseline: 8.2921x; 1.3429x over previous
//
#include <hip/hip_runtime.h>
#include <hip/hip_bf16.h>

#define BB 32
#define TT 512
#define IND 16
#define FD 128
#define NAGG 32

typedef __attribute__((ext_vector_type(8))) short bf16x8;
typedef __attribute__((ext_vector_type(4))) short s16x4;
typedef __attribute__((ext_vector_type(4))) float f32x4;

__device__ __forceinline__ short f2b(float x) {
  union { __hip_bfloat16 h; short s; } u;
  u.h = __float2bfloat16(x);
  return u.s;
}

#define MFMA_16x16x32(A, B, C) __builtin_amdgcn_mfma_f32_16x16x32_bf16(A, B, C, 0, 0, 0)

// ---- proj16, row-tiled: 8 rows/block ----
__global__ void proj16_k(const float* __restrict__ X,
                         const float* __restrict__ wq, const float* __restrict__ bq,
                         const float* __restrict__ wk, const float* __restrict__ bk,
                         const float* __restrict__ wv, const float* __restrict__ bv,
                         float* __restrict__ Q, float* __restrict__ K, float* __restrict__ V) {
  int base = blockIdx.x * 8;
  int f = threadIdx.x;
  __shared__ float xs[8][IND];
  {
    int rr = f >> 4, ii = f & 15;
    xs[rr][ii] = X[(size_t)(base + rr) * IND + ii];
  }
  __syncthreads();
  float qa[8], ka[8], va[8];
  float bqf = bq[f], bkf = bk[f], bvf = bv[f];
#pragma unroll
  for (int rr = 0; rr < 8; rr++) { qa[rr] = bqf; ka[rr] = bkf; va[rr] = bvf; }
#pragma unroll
  for (int i = 0; i < IND; i++) {
    float wqv = wq[i * FD + f], wkv = wk[i * FD + f], wvv = wv[i * FD + f];
#pragma unroll
    for (int rr = 0; rr < 8; rr++) {
      float x = xs[rr][i];
      qa[rr] += x * wqv; ka[rr] += x * wkv; va[rr] += x * wvv;
    }
  }
#pragma unroll
  for (int rr = 0; rr < 8; rr++) {
    size_t o = (size_t)(base + rr) * FD + f;
    Q[o] = qa[rr]; K[o] = ka[rr]; V[o] = va[rr];
  }
}

// ---- MFMA bf16 flash attention ----
// grid BB*16 (b, 32-q-row tile), 256 threads = 4 waves, wave w == head h.
// q_s/k_s: [32 rows][128 d] bf16, stride 136 (conflict-free b128 frag reads).
// vt_s: V transposed [128 d][32 k] stride 40. p_s: per-wave P [32 q][32 k] stride 40.
__global__ __launch_bounds__(256, 2) void attn_k(const float* __restrict__ Q,
                                                 const float* __restrict__ K,
                                                 const float* __restrict__ V,
                                                 const float* __restrict__ mask,
                                                 float* __restrict__ Ores) {
  int b = blockIdx.x >> 4;
  int qt = blockIdx.x & 15;
  int tid = threadIdx.x;
  int w = tid >> 6;        // head
  int lane = tid & 63;
  int l15 = lane & 15, g = lane >> 4;

  __shared__ __align__(16) short q_s[32 * 136];
  __shared__ __align__(16) short k_s[32 * 136];
  __shared__ __align__(16) short vt_s[128 * 40];
  __shared__ __align__(16) short p_s[4][32 * 40];
  __shared__ float msk_s[32];

  const float scale = 0.17677669529663688f;  // 1/sqrt(32)

  int sr = tid >> 3, sc8 = tid & 7;
  size_t qbase = ((size_t)(b * TT + qt * 32 + sr)) * FD + sc8 * 16;
  {  // stage Q -> bf16 LDS
    const float4* src = (const float4*)(Q + qbase);
#pragma unroll
    for (int jj = 0; jj < 4; jj++) {
      float4 v4 = src[jj];
      *(s16x4*)&q_s[sr * 136 + sc8 * 16 + jj * 4] =
          (s16x4){f2b(v4.x), f2b(v4.y), f2b(v4.z), f2b(v4.w)};
    }
  }

  f32x4 o00 = {0.f, 0.f, 0.f, 0.f}, o01 = o00, o10 = o00, o11 = o00;
  float m_st[2][4], l_st[2][4], sc_st[2][4];
#pragma unroll
  for (int mt = 0; mt < 2; mt++)
#pragma unroll
    for (int r = 0; r < 4; r++) { m_st[mt][r] = -1e30f; l_st[mt][r] = 0.f; }

  bf16x8 aq0, aq1;

  for (int kt = 0; kt < 16; kt++) {
    if (kt) __syncthreads();  // k_s/vt_s consumers done
    {  // stage K, V^T tiles + mask
      size_t kb = ((size_t)(b * TT + kt * 32 + sr)) * FD + sc8 * 16;
      const float4* ks = (const float4*)(K + kb);
      const float4* vs = (const float4*)(V + kb);
#pragma unroll
      for (int jj = 0; jj < 4; jj++) {
        float4 kv = ks[jj];
        *(s16x4*)&k_s[sr * 136 + sc8 * 16 + jj * 4] =
            (s16x4){f2b(kv.x), f2b(kv.y), f2b(kv.z), f2b(kv.w)};
      }
#pragma unroll
      for (int jj = 0; jj < 4; jj++) {
        float4 vv = vs[jj];
        int d0 = sc8 * 16 + jj * 4;
        vt_s[(d0 + 0) * 40 + sr] = f2b(vv.x);
        vt_s[(d0 + 1) * 40 + sr] = f2b(vv.y);
        vt_s[(d0 + 2) * 40 + sr] = f2b(vv.z);
        vt_s[(d0 + 3) * 40 + sr] = f2b(vv.w);
      }
      if (tid < 32) msk_s[tid] = mask[b * TT + kt * 32 + tid];
    }
    __syncthreads();
    if (kt == 0) {  // Q fragments (hoisted; q_s ready after first barrier)
      aq0 = *(const bf16x8*)&q_s[l15 * 136 + w * 32 + g * 8];
      aq1 = *(const bf16x8*)&q_s[(16 + l15) * 136 + w * 32 + g * 8];
    }
    // QK^T: S[q][k] = sum_d Q[q][d] K[k][d]; B-frag of K^T == row-read of K
    bf16x8 bk0 = *(const bf16x8*)&k_s[l15 * 136 + w * 32 + g * 8];
    bf16x8 bk1 = *(const bf16x8*)&k_s[(16 + l15) * 136 + w * 32 + g * 8];
    f32x4 zero = {0.f, 0.f, 0.f, 0.f};
    f32x4 s00 = MFMA_16x16x32(aq0, bk0, zero);
    f32x4 s01 = MFMA_16x16x32(aq0, bk1, zero);
    f32x4 s10 = MFMA_16x16x32(aq1, bk0, zero);
    f32x4 s11 = MFMA_16x16x32(aq1, bk1, zero);
    float mk0 = msk_s[l15], mk1 = msk_s[16 + l15];
    // online softmax per (mt, r); row of 32 k lives in 16 lanes x 2 n-tiles
#pragma unroll
    for (int mt = 0; mt < 2; mt++) {
#pragma unroll
      for (int r = 0; r < 4; r++) {
        float v0 = mt ? s10[r] : s00[r];
        float v1 = mt ? s11[r] : s01[r];
        float x0 = mk0 > 0.f ? v0 * scale : -1e9f;
        float x1 = mk1 > 0.f ? v1 * scale : -1e9f;
        float rm = fmaxf(x0, x1);
        rm = fmaxf(rm, __shfl_xor(rm, 1));
        rm = fmaxf(rm, __shfl_xor(rm, 2));
        rm = fmaxf(rm, __shfl_xor(rm, 4));
        rm = fmaxf(rm, __shfl_xor(rm, 8));
        float mo = m_st[mt][r];
        float mn = fmaxf(mo, rm);
        float p0 = __expf(x0 - mn);
        float p1 = __expf(x1 - mn);
        float rs = p0 + p1;
        rs += __shfl_xor(rs, 1);
        rs += __shfl_xor(rs, 2);
        rs += __shfl_xor(rs, 4);
        rs += __shfl_xor(rs, 8);
        float scv = __expf(mo - mn);
        m_st[mt][r] = mn;
        l_st[mt][r] = l_st[mt][r] * scv + rs;
        sc_st[mt][r] = scv;
        int qrow = 16 * mt + 4 * g + r;
        p_s[w][qrow * 40 + l15] = f2b(p0);
        p_s[w][qrow * 40 + 16 + l15] = f2b(p1);
      }
    }
    __syncthreads();  // P visible (wave-local, but safe ordering)
    // AV: O[q][d] += P[q][k] V[k][d]
    bf16x8 ap0 = *(const bf16x8*)&p_s[w][l15 * 40 + g * 8];
    bf16x8 ap1 = *(const bf16x8*)&p_s[w][(16 + l15) * 40 + g * 8];
    bf16x8 bv0 = *(const bf16x8*)&vt_s[(w * 32 + l15) * 40 + g * 8];
    bf16x8 bv1 = *(const bf16x8*)&vt_s[(w * 32 + 16 + l15) * 40 + g * 8];
#pragma unroll
    for (int r = 0; r < 4; r++) {
      o00[r] *= sc_st[0][r]; o01[r] *= sc_st[0][r];
      o10[r] *= sc_st[1][r]; o11[r] *= sc_st[1][r];
    }
    o00 = MFMA_16x16x32(ap0, bv0, o00);
    o01 = MFMA_16x16x32(ap0, bv1, o01);
    o10 = MFMA_16x16x32(ap1, bv0, o10);
    o11 = MFMA_16x16x32(ap1, bv1, o11);
  }
  // epilogue: Ores = Q + O/l  (fp32 residual from global)
  size_t rowbase = (size_t)(b * TT + qt * 32);
#pragma unroll
  for (int mt = 0; mt < 2; mt++) {
#pragma unroll
    for (int r = 0; r < 4; r++) {
      float inv = 1.f / l_st[mt][r];
      int qrow = 16 * mt + 4 * g + r;
      size_t base = (rowbase + qrow) * FD + w * 32 + l15;
      float ov0 = mt ? o10[r] : o00[r];
      float ov1 = mt ? o11[r] : o01[r];
      Ores[base] = Q[base] + ov0 * inv;
      Ores[base + 16] = Q[base + 16] + ov1 * inv;
    }
  }
}

// wave-per-row LN helper: rows w*4+j over A, write to Bf scaled
__device__ __forceinline__ void ln_rows(const float (*A)[128], float (*Bf)[128],
                                        int lane, int w,
                                        float ga, float gb, float ba, float bb,
                                        const float* mk) {
  for (int j = 0; j < 4; j++) {
    int rr = w * 4 + j;
    float a = A[rr][lane], b2 = A[rr][lane + 64];
    float s = a + b2, ss = a * a + b2 * b2;
#pragma unroll
    for (int o = 32; o > 0; o >>= 1) { s += __shfl_xor(s, o); ss += __shfl_xor(ss, o); }
    float mean = s * (1.f / 128.f);
    float var = ss * (1.f / 128.f) - mean * mean;
    float rs = rsqrtf(var + 1e-5f);
    float m = mk ? mk[rr] : 1.f;
    Bf[rr][lane] = ((a - mean) * rs * ga + ba) * m;
    Bf[rr][lane + 64] = ((b2 - mean) * rs * gb + bb) * m;
  }
}

// ---- post(layer1) + proj128(layer2): 8 rows/block ----
__global__ void post_proj_k(const float* __restrict__ Ores, const float* __restrict__ mask,
                            const float* __restrict__ wo, const float* __restrict__ bo,
                            const float* __restrict__ g0, const float* __restrict__ be0,
                            const float* __restrict__ g1, const float* __restrict__ be1,
                            const float* __restrict__ wq, const float* __restrict__ bq,
                            const float* __restrict__ wk, const float* __restrict__ bk,
                            const float* __restrict__ wv, const float* __restrict__ bv,
                            float* __restrict__ Q, float* __restrict__ K, float* __restrict__ V) {
  int base = blockIdx.x * 8;
  int tid = threadIdx.x;
  int lane = tid & 63, w = tid >> 6;
  __shared__ float A[8][128];
  __shared__ float Bf[8][128];
  __shared__ float mk[8];
#pragma unroll
  for (int rr = 0; rr < 8; rr++) A[rr][tid] = Ores[(size_t)(base + rr) * FD + tid];
  if (tid < 8) mk[tid] = mask[base + tid];
  __syncthreads();
  ln_rows(A, Bf, lane, w, g0[lane], g0[lane + 64], be0[lane], be0[lane + 64], nullptr);
  __syncthreads();
  float acc[8];
  float bof = bo[tid];
#pragma unroll
  for (int rr = 0; rr < 8; rr++) acc[rr] = bof;
  for (int i = 0; i < 128; i++) {
    float wv_ = wo[i * 128 + tid];
#pragma unroll
    for (int rr = 0; rr < 8; rr++) acc[rr] += Bf[rr][i] * wv_;
  }
  __syncthreads();
#pragma unroll
  for (int rr = 0; rr < 8; rr++) A[rr][tid] = Bf[rr][tid] + fmaxf(acc[rr], 0.f);
  __syncthreads();
  ln_rows(A, Bf, lane, w, g1[lane], g1[lane + 64], be1[lane], be1[lane + 64], mk);
  __syncthreads();
  float qa[8], ka[8], va[8];
  float bqf = bq[tid], bkf = bk[tid], bvf = bv[tid];
#pragma unroll
  for (int rr = 0; rr < 8; rr++) { qa[rr] = bqf; ka[rr] = bkf; va[rr] = bvf; }
  for (int i = 0; i < 128; i++) {
    float wqv = wq[i * 128 + tid], wkv = wk[i * 128 + tid], wvv = wv[i * 128 + tid];
#pragma unroll
    for (int rr = 0; rr < 8; rr++) {
      float xv = Bf[rr][i];
      qa[rr] += xv * wqv; ka[rr] += xv * wkv; va[rr] += xv * wvv;
    }
  }
#pragma unroll
  for (int rr = 0; rr < 8; rr++) {
    size_t o = (size_t)(base + rr) * FD + tid;
    Q[o] = qa[rr]; K[o] = ka[rr]; V[o] = va[rr];
  }
}

// ---- post(layer2) + ti + as-score: 8 rows/block ----
__global__ void post_ti_k(const float* __restrict__ Ores, const float* __restrict__ mask,
                          const float* __restrict__ wo, const float* __restrict__ bo,
                          const float* __restrict__ g0, const float* __restrict__ be0,
                          const float* __restrict__ g1, const float* __restrict__ be1,
                          const float* __restrict__ wti, const float* __restrict__ bti,
                          const float* __restrict__ was, const float* __restrict__ bas,
                          float* __restrict__ Xp2, float* __restrict__ S) {
  int base = blockIdx.x * 8;
  int tid = threadIdx.x;
  int lane = tid & 63, w = tid >> 6;
  __shared__ float A[8][128];
  __shared__ float Bf[8][128];
  __shared__ float mk[8];
#pragma unroll
  for (int rr = 0; rr < 8; rr++) A[rr][tid] = Ores[(size_t)(base + rr) * FD + tid];
  if (tid < 8) mk[tid] = mask[base + tid];
  __syncthreads();
  ln_rows(A, Bf, lane, w, g0[lane], g0[lane + 64], be0[lane], be0[lane + 64], nullptr);
  __syncthreads();
  float acc[8];
  float bof = bo[tid];
#pragma unroll
  for (int rr = 0; rr < 8; rr++) acc[rr] = bof;
  for (int i = 0; i < 128; i++) {
    float wv_ = wo[i * 128 + tid];
#pragma unroll
    for (int rr = 0; rr < 8; rr++) acc[rr] += Bf[rr][i] * wv_;
  }
  __syncthreads();
#pragma unroll
  for (int rr = 0; rr < 8; rr++) A[rr][tid] = Bf[rr][tid] + fmaxf(acc[rr], 0.f);
  __syncthreads();
  ln_rows(A, Bf, lane, w, g1[lane], g1[lane + 64], be1[lane], be1[lane + 64], mk);
  __syncthreads();
  float btif = bti[tid];
#pragma unroll
  for (int rr = 0; rr < 8; rr++) acc[rr] = btif;
  for (int i = 0; i < 128; i++) {
    float wv_ = wti[i * 128 + tid];
#pragma unroll
    for (int rr = 0; rr < 8; rr++) acc[rr] += Bf[rr][i] * wv_;
  }
#pragma unroll
  for (int rr = 0; rr < 8; rr++) {
    float x2 = acc[rr] * mk[rr];
    A[rr][tid] = x2;
    Xp2[(size_t)(base + rr) * FD + tid] = x2;
  }
  __syncthreads();
  int a = tid & 31, rg = tid >> 5;
  float s0 = bas[a], s1 = s0;
  for (int i = 0; i < 128; i++) {
    float wv_ = was[i * NAGG + a];
    s0 += A[2 * rg][i] * wv_;
    s1 += A[2 * rg + 1][i] * wv_;
  }
  S[(size_t)(base + 2 * rg) * NAGG + a] = s0;
  S[(size_t)(base + 2 * rg + 1) * NAGG + a] = s1;
}

// ---- fused softmax-over-T + masked max/mean pooling: block per (b,a), 128 thr ----
__global__ void soft_pool_k(const float* __restrict__ S, const float* __restrict__ Xp2,
                            const float* __restrict__ mask,
                            float* __restrict__ aggF, float* __restrict__ agg_out) {
  int b = blockIdx.x >> 5, a = blockIdx.x & 31;
  int f = threadIdx.x;  // 128
  __shared__ float att_s[TT];
  __shared__ float ms[TT];
  __shared__ float red[2];
  float sv[4], mv[4];
#pragma unroll
  for (int j = 0; j < 4; j++) {
    int t = f + j * 128;
    sv[j] = S[(size_t)(b * TT + t) * NAGG + a];
    mv[j] = mask[b * TT + t];
    ms[t] = mv[j];
  }
  float mx = fmaxf(fmaxf(sv[0], sv[1]), fmaxf(sv[2], sv[3]));
#pragma unroll
  for (int o = 32; o > 0; o >>= 1) mx = fmaxf(mx, __shfl_xor(mx, o));
  if ((f & 63) == 0) red[f >> 6] = mx;
  __syncthreads();
  mx = fmaxf(red[0], red[1]);
  __syncthreads();
  float sm = 0.f;
#pragma unroll
  for (int j = 0; j < 4; j++) {
    float e = __expf(sv[j] - mx) * mv[j];
    att_s[f + j * 128] = e;
    sm += e;
  }
#pragma unroll
  for (int o = 32; o > 0; o >>= 1) sm += __shfl_xor(sm, o);
  if ((f & 63) == 0) red[f >> 6] = sm;
  __syncthreads();
  float inv = 1.f / (red[0] + red[1] + 1e-16f);
#pragma unroll
  for (int j = 0; j < 4; j++) att_s[f + j * 128] *= inv;
  __syncthreads();
  float mn = 1e30f, mxm = -1e30f, smv = 0.f, nt = 0.f;
  int anyUn = 0;
#pragma unroll 4
  for (int t = 0; t < TT; t++) {
    float e = Xp2[(size_t)(b * TT + t) * FD + f] * att_s[t];
    mn = fminf(mn, e);
    float m = ms[t];
    if (m > 0.f) { mxm = fmaxf(mxm, e); smv += e; nt += 1.f; }
    else anyUn = 1;
  }
  float mp = anyUn ? fmaxf(mxm, mn - 1.f) : mxm;
  float mean = smv / (nt == 0.f ? 1.f : nt);
  size_t bs = (size_t)b * 8192 + (size_t)a * 256;
  aggF[bs + f] = mp;
  aggF[bs + 128 + f] = mean;
  agg_out[bs + f] = mp;
  agg_out[bs + 128 + f] = mean;
}

// ---- per-batch agg @ wto[144:,:], split into 8 j-chunks of 1024 ----
__global__ void aggmm_k(const float* __restrict__ aggF, const float* __restrict__ wto,
                        float* __restrict__ part) {
  int b = blockIdx.x >> 3, cc = blockIdx.x & 7;
  int f = threadIdx.x;
  __shared__ float ag[1024];
  for (int j = f; j < 1024; j += FD) ag[j] = aggF[(size_t)b * 8192 + cc * 1024 + j];
  __syncthreads();
  const float* w = wto + ((size_t)(IND + FD) + cc * 1024) * FD;
  float acc = 0.f;
#pragma unroll 8
  for (int j = 0; j < 1024; j++) acc += ag[j] * w[(size_t)j * FD + f];
  part[(size_t)(b * 8 + cc) * FD + f] = acc;
}

// ---- final: relu(LN(X@wto_x + Xp2@wto_p + sum(part) + bto)) * m, 8 rows/block ----
__global__ void final_k(const float* __restrict__ X, const float* __restrict__ Xp2,
                        const float* __restrict__ part,
                        const float* __restrict__ wto, const float* __restrict__ bto,
                        const float* __restrict__ gto, const float* __restrict__ btoln,
                        const float* __restrict__ mask, float* __restrict__ out) {
  int base = blockIdx.x * 8;
  int b = base >> 9;
  int tid = threadIdx.x;
  int lane = tid & 63, w = tid >> 6;
  __shared__ float A[8][128];
  __shared__ float Bf[8][128];
  __shared__ float xss[8][16];
  __shared__ float mk[8];
#pragma unroll
  for (int rr = 0; rr < 8; rr++) Bf[rr][tid] = Xp2[(size_t)(base + rr) * FD + tid];
  {
    int rr = tid >> 4, ii = tid & 15;
    xss[rr][ii] = X[(size_t)(base + rr) * IND + ii];
  }
  if (tid < 8) mk[tid] = mask[base + tid];
  __syncthreads();
  float psum = 0.f;
#pragma unroll
  for (int cc = 0; cc < 8; cc++) psum += part[(size_t)(b * 8 + cc) * FD + tid];
  float acc[8];
  float btof = bto[tid];
#pragma unroll
  for (int rr = 0; rr < 8; rr++) acc[rr] = btof + psum;
#pragma unroll
  for (int i = 0; i < IND; i++) {
    float wv_ = wto[i * FD + tid];
#pragma unroll
    for (int rr = 0; rr < 8; rr++) acc[rr] += xss[rr][i] * wv_;
  }
  for (int i = 0; i < 128; i++) {
    float wv_ = wto[(IND + i) * FD + tid];
#pragma unroll
    for (int rr = 0; rr < 8; rr++) acc[rr] += Bf[rr][i] * wv_;
  }
  __syncthreads();
#pragma unroll
  for (int rr = 0; rr < 8; rr++) A[rr][tid] = acc[rr];
  __syncthreads();
  float ga = gto[lane], gb = gto[lane + 64], ba = btoln[lane], bb = btoln[lane + 64];
  for (int j = 0; j < 4; j++) {
    int rr = w * 4 + j;
    float av = A[rr][lane], bv2 = A[rr][lane + 64];
    float s = av + bv2, ss = av * av + bv2 * bv2;
#pragma unroll
    for (int o = 32; o > 0; o >>= 1) { s += __shfl_xor(s, o); ss += __shfl_xor(ss, o); }
    float mean = s * (1.f / 128.f);
    float var = ss * (1.f / 128.f) - mean * mean;
    float rs = rsqrtf(var + 1e-5f);
    float m = mk[rr];
    out[(size_t)(base + rr) * FD + lane] = fmaxf((av - mean) * rs * ga + ba, 0.f) * m;
    out[(size_t)(base + rr) * FD + lane + 64] = fmaxf((bv2 - mean) * rs * gb + bb, 0.f) * m;
  }
}

extern "C" void kernel_launch(void* const* d_in, const int* in_sizes, int n_in,
                              void* d_out, int out_size, void* d_ws, size_t ws_size,
                              hipStream_t stream) {
  const float* X    = (const float*)d_in[0];
  const float* mask = (const float*)d_in[1];
  const float* wq0 = (const float*)d_in[2];  const float* bq0 = (const float*)d_in[3];
  const float* wk0 = (const float*)d_in[4];  const float* bk0 = (const float*)d_in[5];
  const float* wv0 = (const float*)d_in[6];  const float* bv0 = (const float*)d_in[7];
  const float* wo0 = (const float*)d_in[8];  const float* bo0 = (const float*)d_in[9];
  const float* g00 = (const float*)d_in[10]; const float* be00 = (const float*)d_in[11];
  const float* g10 = (const float*)d_in[12]; const float* be10 = (const float*)d_in[13];
  const float* wq1 = (const float*)d_in[14]; const float* bq1 = (const float*)d_in[15];
  const float* wk1 = (const float*)d_in[16]; const float* bk1 = (const float*)d_in[17];
  const float* wv1 = (const float*)d_in[18]; const float* bv1 = (const float*)d_in[19];
  const float* wo1 = (const float*)d_in[20]; const float* bo1 = (const float*)d_in[21];
  const float* g01 = (const float*)d_in[22]; const float* be01 = (const float*)d_in[23];
  const float* g11 = (const float*)d_in[24]; const float* be11 = (const float*)d_in[25];
  const float* wti = (const float*)d_in[26]; const float* bti = (const float*)d_in[27];
  const float* was = (const float*)d_in[28]; const float* bas = (const float*)d_in[29];
  const float* wto = (const float*)d_in[30]; const float* bto = (const float*)d_in[31];
  const float* gto = (const float*)d_in[32]; const float* btoln = (const float*)d_in[33];

  const size_t BIG = (size_t)BB * TT * FD;  // 2,097,152 floats
  float* ws = (float*)d_ws;
  float* Q  = ws;
  float* K  = ws + BIG;
  float* V  = ws + 2 * BIG;
  float* Xtra = ws + 3 * BIG;
  float* Ores = Q;        // in-place (row-local)
  float* Xp2 = K;         // after layer-2 attention K is dead
  float* S   = V;
  float* aggF = Xtra;
  float* part = Xtra + 262144;

  float* out_main = (float*)d_out;
  float* out_agg  = (float*)d_out + BIG;

  int nrb = BB * TT / 8;  // 2048 row-tiled blocks
  proj16_k<<<nrb, 128, 0, stream>>>(X, wq0, bq0, wk0, bk0, wv0, bv0, Q, K, V);
  attn_k<<<BB * 16, 256, 0, stream>>>(Q, K, V, mask, Ores);
  post_proj_k<<<nrb, 128, 0, stream>>>(Ores, mask, wo0, bo0, g00, be00, g10, be10,
                                       wq1, bq1, wk1, bk1, wv1, bv1, Q, K, V);
  attn_k<<<BB * 16, 256, 0, stream>>>(Q, K, V, mask, Ores);
  post_ti_k<<<nrb, 128, 0, stream>>>(Ores, mask, wo1, bo1, g01, be01, g11, be11,
                                     wti, bti, was, bas, Xp2, S);
  soft_pool_k<<<BB * NAGG, 128, 0, stream>>>(S, Xp2, mask, aggF, out_agg);
  aggmm_k<<<BB * 8, 128, 0, stream>>>(aggF, wto, part);
  final_k<<<nrb, 128, 0, stream>>>(X, Xp2, part, wto, bto, gto, btoln, mask, out_main);
}

// Round 7
// 259.928 us; speedup vs baseline: 10.3234x; 1.2450x over previous
//
#include <hip/hip_runtime.h>
#include <hip/hip_bf16.h>

#define BB 32
#define TT 512
#define IND 16
#define FD 128
#define NAGG 32

typedef unsigned short ushortt;
typedef __attribute__((ext_vector_type(8))) short bf16x8;
typedef __attribute__((ext_vector_type(4))) short s16x4;
typedef __attribute__((ext_vector_type(4))) float f32x4;

__device__ __forceinline__ short f2b(float x) {
  union { __hip_bfloat16 h; short s; } u;
  u.h = __float2bfloat16(x);
  return u.s;
}

#define MFMA_16x16x32(A, B, C) __builtin_amdgcn_mfma_f32_16x16x32_bf16(A, B, C, 0, 0, 0)

// ---- proj16: 8 rows/block; writes Q fp32, K bf16 row-major, V^T bf16 ----
__global__ void proj16_k(const float* __restrict__ X,
                         const float* __restrict__ wq, const float* __restrict__ bq,
                         const float* __restrict__ wk, const float* __restrict__ bk,
                         const float* __restrict__ wv, const float* __restrict__ bv,
                         float* __restrict__ Q, ushortt* __restrict__ Kb,
                         ushortt* __restrict__ Vt) {
  int base = blockIdx.x * 8;
  int b = base >> 9;
  int tloc = base & 511;
  int f = threadIdx.x;
  __shared__ float xs[8][IND];
  {
    int rr = f >> 4, ii = f & 15;
    xs[rr][ii] = X[(size_t)(base + rr) * IND + ii];
  }
  __syncthreads();
  float qa[8], ka[8], va[8];
  float bqf = bq[f], bkf = bk[f], bvf = bv[f];
#pragma unroll
  for (int rr = 0; rr < 8; rr++) { qa[rr] = bqf; ka[rr] = bkf; va[rr] = bvf; }
#pragma unroll
  for (int i = 0; i < IND; i++) {
    float wqv = wq[i * FD + f], wkv = wk[i * FD + f], wvv = wv[i * FD + f];
#pragma unroll
    for (int rr = 0; rr < 8; rr++) {
      float x = xs[rr][i];
      qa[rr] += x * wqv; ka[rr] += x * wkv; va[rr] += x * wvv;
    }
  }
  short vp[8];
#pragma unroll
  for (int rr = 0; rr < 8; rr++) {
    size_t o = (size_t)(base + rr) * FD + f;
    Q[o] = qa[rr];
    Kb[o] = (ushortt)f2b(ka[rr]);
    vp[rr] = f2b(va[rr]);
  }
  *(bf16x8*)&Vt[((size_t)(b * FD) + f) * 512 + tloc] = *(bf16x8*)vp;
}

// ---- MFMA bf16 flash attention v3: double-buffered, 1 barrier/tile ----
// grid BB*16, 256 thr = 4 waves (wave w = head). Inputs: Q fp32, Kb bf16 [b][t][d],
// Vt bf16 [b][d][t]. LDS: q_s/k_s stride 136 (pad), vt_s/p_s stride 40.
__global__ __launch_bounds__(256, 2) void attn_k(const float* __restrict__ Q,
                                                 const ushortt* __restrict__ Kb,
                                                 const ushortt* __restrict__ Vt,
                                                 const float* __restrict__ mask,
                                                 float* __restrict__ Ores) {
  int b = blockIdx.x >> 4;
  int qt = blockIdx.x & 15;
  int tid = threadIdx.x;
  int w = tid >> 6;
  int lane = tid & 63;
  int l15 = lane & 15, g = lane >> 4;

  __shared__ __align__(16) short q_s[32 * 136];
  __shared__ __align__(16) short k_s[2][32 * 136];
  __shared__ __align__(16) short vt_s[2][128 * 40];
  __shared__ __align__(16) short p_s[4][32 * 40];
  __shared__ float msk_s[512];

  const float scale = 0.17677669529663688f;

  // hoisted mask stage
  msk_s[tid] = mask[b * TT + tid];
  msk_s[256 + tid] = mask[b * TT + 256 + tid];

  // stage Q (fp32 -> bf16, padded)
  int sr = tid >> 3, sc8 = tid & 7;
  size_t qbase = ((size_t)(b * TT + qt * 32 + sr)) * FD + sc8 * 16;
  {
    const float4* src = (const float4*)(Q + qbase);
#pragma unroll
    for (int jj = 0; jj < 4; jj++) {
      float4 v4 = src[jj];
      *(s16x4*)&q_s[sr * 136 + sc8 * 16 + jj * 4] =
          (s16x4){f2b(v4.x), f2b(v4.y), f2b(v4.z), f2b(v4.w)};
    }
  }

  bf16x8 kr[2], vr[2];
  const ushortt* KbB = Kb + (size_t)b * TT * FD;
  const ushortt* VtB = Vt + (size_t)b * FD * 512;

#define LOAD_TILE(kt)                                                              \
  {                                                                                \
    const ushortt* kbp = KbB + (size_t)(kt) * 32 * FD;                             \
    _Pragma("unroll") for (int is = 0; is < 2; is++) {                             \
      int idx = tid + is * 256;                                                    \
      kr[is] = *(const bf16x8*)(kbp + (idx >> 4) * FD + (idx & 15) * 8);           \
      vr[is] = *(const bf16x8*)(VtB + (size_t)(idx >> 2) * 512 + (kt) * 32 +       \
                                (idx & 3) * 8);                                    \
    }                                                                              \
  }
#define WRITE_TILE(buf)                                                            \
  {                                                                                \
    _Pragma("unroll") for (int is = 0; is < 2; is++) {                             \
      int idx = tid + is * 256;                                                    \
      *(bf16x8*)&k_s[buf][(idx >> 4) * 136 + (idx & 15) * 8] = kr[is];             \
      *(bf16x8*)&vt_s[buf][(idx >> 2) * 40 + (idx & 3) * 8] = vr[is];              \
    }                                                                              \
  }

  LOAD_TILE(0);
  WRITE_TILE(0);

  f32x4 o00 = {0.f, 0.f, 0.f, 0.f}, o01 = o00, o10 = o00, o11 = o00;
  float m_st[2][4], l_st[2][4], sc_st[2][4];
#pragma unroll
  for (int mt = 0; mt < 2; mt++)
#pragma unroll
    for (int r = 0; r < 4; r++) { m_st[mt][r] = -1e30f; l_st[mt][r] = 0.f; }

  bf16x8 aq0, aq1;
  int cur = 0;

  for (int kt = 0; kt < 16; kt++) {
    __syncthreads();  // staging for kt visible; all waves done with buf cur^1
    if (kt == 0) {
      aq0 = *(const bf16x8*)&q_s[l15 * 136 + w * 32 + g * 8];
      aq1 = *(const bf16x8*)&q_s[(16 + l15) * 136 + w * 32 + g * 8];
    }
    if (kt < 15) LOAD_TILE(kt + 1);  // prefetch into regs (latency hidden)

    // QK^T
    bf16x8 bk0 = *(const bf16x8*)&k_s[cur][l15 * 136 + w * 32 + g * 8];
    bf16x8 bk1 = *(const bf16x8*)&k_s[cur][(16 + l15) * 136 + w * 32 + g * 8];
    f32x4 zero = {0.f, 0.f, 0.f, 0.f};
    f32x4 s00 = MFMA_16x16x32(aq0, bk0, zero);
    f32x4 s01 = MFMA_16x16x32(aq0, bk1, zero);
    f32x4 s10 = MFMA_16x16x32(aq1, bk0, zero);
    f32x4 s11 = MFMA_16x16x32(aq1, bk1, zero);
    float mk0 = msk_s[kt * 32 + l15], mk1 = msk_s[kt * 32 + 16 + l15];
#pragma unroll
    for (int mt = 0; mt < 2; mt++) {
#pragma unroll
      for (int r = 0; r < 4; r++) {
        float v0 = mt ? s10[r] : s00[r];
        float v1 = mt ? s11[r] : s01[r];
        float x0 = mk0 > 0.f ? v0 * scale : -1e9f;
        float x1 = mk1 > 0.f ? v1 * scale : -1e9f;
        float rm = fmaxf(x0, x1);
        rm = fmaxf(rm, __shfl_xor(rm, 1));
        rm = fmaxf(rm, __shfl_xor(rm, 2));
        rm = fmaxf(rm, __shfl_xor(rm, 4));
        rm = fmaxf(rm, __shfl_xor(rm, 8));
        float mo = m_st[mt][r];
        float mn = fmaxf(mo, rm);
        float p0 = __expf(x0 - mn);
        float p1 = __expf(x1 - mn);
        float rs = p0 + p1;
        rs += __shfl_xor(rs, 1);
        rs += __shfl_xor(rs, 2);
        rs += __shfl_xor(rs, 4);
        rs += __shfl_xor(rs, 8);
        float scv = __expf(mo - mn);
        m_st[mt][r] = mn;
        l_st[mt][r] = l_st[mt][r] * scv + rs;
        sc_st[mt][r] = scv;
        int qrow = 16 * mt + 4 * g + r;
        p_s[w][qrow * 40 + l15] = f2b(p0);
        p_s[w][qrow * 40 + 16 + l15] = f2b(p1);
      }
    }
    // P is wave-local: lgkmcnt (compiler) orders write->read, no barrier needed
    bf16x8 ap0 = *(const bf16x8*)&p_s[w][l15 * 40 + g * 8];
    bf16x8 ap1 = *(const bf16x8*)&p_s[w][(16 + l15) * 40 + g * 8];
    bf16x8 bv0 = *(const bf16x8*)&vt_s[cur][(w * 32 + l15) * 40 + g * 8];
    bf16x8 bv1 = *(const bf16x8*)&vt_s[cur][(w * 32 + 16 + l15) * 40 + g * 8];
#pragma unroll
    for (int r = 0; r < 4; r++) {
      o00[r] *= sc_st[0][r]; o01[r] *= sc_st[0][r];
      o10[r] *= sc_st[1][r]; o11[r] *= sc_st[1][r];
    }
    o00 = MFMA_16x16x32(ap0, bv0, o00);
    o01 = MFMA_16x16x32(ap0, bv1, o01);
    o10 = MFMA_16x16x32(ap1, bv0, o10);
    o11 = MFMA_16x16x32(ap1, bv1, o11);

    if (kt < 15) WRITE_TILE(cur ^ 1);  // stage next tile (vmcnt wait by compiler)
    cur ^= 1;
  }
  // epilogue: Ores = Q + O/l
  size_t rowbase = (size_t)(b * TT + qt * 32);
#pragma unroll
  for (int mt = 0; mt < 2; mt++) {
#pragma unroll
    for (int r = 0; r < 4; r++) {
      float inv = 1.f / l_st[mt][r];
      int qrow = 16 * mt + 4 * g + r;
      size_t base = (rowbase + qrow) * FD + w * 32 + l15;
      float ov0 = mt ? o10[r] : o00[r];
      float ov1 = mt ? o11[r] : o01[r];
      Ores[base] = Q[base] + ov0 * inv;
      Ores[base + 16] = Q[base + 16] + ov1 * inv;
    }
  }
#undef LOAD_TILE
#undef WRITE_TILE
}

// wave-per-row LN helper
__device__ __forceinline__ void ln_rows(const float (*A)[128], float (*Bf)[128],
                                        int lane, int w,
                                        float ga, float gb, float ba, float bb,
                                        const float* mk) {
  for (int j = 0; j < 4; j++) {
    int rr = w * 4 + j;
    float a = A[rr][lane], b2 = A[rr][lane + 64];
    float s = a + b2, ss = a * a + b2 * b2;
#pragma unroll
    for (int o = 32; o > 0; o >>= 1) { s += __shfl_xor(s, o); ss += __shfl_xor(ss, o); }
    float mean = s * (1.f / 128.f);
    float var = ss * (1.f / 128.f) - mean * mean;
    float rs = rsqrtf(var + 1e-5f);
    float m = mk ? mk[rr] : 1.f;
    Bf[rr][lane] = ((a - mean) * rs * ga + ba) * m;
    Bf[rr][lane + 64] = ((b2 - mean) * rs * gb + bb) * m;
  }
}

// ---- post(layer1) + proj128(layer2): writes Q fp32, Kb bf16, Vt bf16 ----
__global__ void post_proj_k(const float* __restrict__ Ores, const float* __restrict__ mask,
                            const float* __restrict__ wo, const float* __restrict__ bo,
                            const float* __restrict__ g0, const float* __restrict__ be0,
                            const float* __restrict__ g1, const float* __restrict__ be1,
                            const float* __restrict__ wq, const float* __restrict__ bq,
                            const float* __restrict__ wk, const float* __restrict__ bk,
                            const float* __restrict__ wv, const float* __restrict__ bv,
                            float* __restrict__ Q, ushortt* __restrict__ Kb,
                            ushortt* __restrict__ Vt) {
  int base = blockIdx.x * 8;
  int b = base >> 9;
  int tloc = base & 511;
  int tid = threadIdx.x;
  int lane = tid & 63, w = tid >> 6;
  __shared__ float A[8][128];
  __shared__ float Bf[8][128];
  __shared__ float mk[8];
#pragma unroll
  for (int rr = 0; rr < 8; rr++) A[rr][tid] = Ores[(size_t)(base + rr) * FD + tid];
  if (tid < 8) mk[tid] = mask[base + tid];
  __syncthreads();
  ln_rows(A, Bf, lane, w, g0[lane], g0[lane + 64], be0[lane], be0[lane + 64], nullptr);
  __syncthreads();
  float acc[8];
  float bof = bo[tid];
#pragma unroll
  for (int rr = 0; rr < 8; rr++) acc[rr] = bof;
  for (int i = 0; i < 128; i++) {
    float wv_ = wo[i * 128 + tid];
#pragma unroll
    for (int rr = 0; rr < 8; rr++) acc[rr] += Bf[rr][i] * wv_;
  }
  __syncthreads();
#pragma unroll
  for (int rr = 0; rr < 8; rr++) A[rr][tid] = Bf[rr][tid] + fmaxf(acc[rr], 0.f);
  __syncthreads();
  ln_rows(A, Bf, lane, w, g1[lane], g1[lane + 64], be1[lane], be1[lane + 64], mk);
  __syncthreads();
  float qa[8], ka[8], va[8];
  float bqf = bq[tid], bkf = bk[tid], bvf = bv[tid];
#pragma unroll
  for (int rr = 0; rr < 8; rr++) { qa[rr] = bqf; ka[rr] = bkf; va[rr] = bvf; }
  for (int i = 0; i < 128; i++) {
    float wqv = wq[i * 128 + tid], wkv = wk[i * 128 + tid], wvv = wv[i * 128 + tid];
#pragma unroll
    for (int rr = 0; rr < 8; rr++) {
      float xv = Bf[rr][i];
      qa[rr] += xv * wqv; ka[rr] += xv * wkv; va[rr] += xv * wvv;
    }
  }
  short vp[8];
#pragma unroll
  for (int rr = 0; rr < 8; rr++) {
    size_t o = (size_t)(base + rr) * FD + tid;
    Q[o] = qa[rr];
    Kb[o] = (ushortt)f2b(ka[rr]);
    vp[rr] = f2b(va[rr]);
  }
  *(bf16x8*)&Vt[((size_t)(b * FD) + tid) * 512 + tloc] = *(bf16x8*)vp;
}

// ---- post(layer2) + ti + as-score ----
__global__ void post_ti_k(const float* __restrict__ Ores, const float* __restrict__ mask,
                          const float* __restrict__ wo, const float* __restrict__ bo,
                          const float* __restrict__ g0, const float* __restrict__ be0,
                          const float* __restrict__ g1, const float* __restrict__ be1,
                          const float* __restrict__ wti, const float* __restrict__ bti,
                          const float* __restrict__ was, const float* __restrict__ bas,
                          float* __restrict__ Xp2, float* __restrict__ S) {
  int base = blockIdx.x * 8;
  int tid = threadIdx.x;
  int lane = tid & 63, w = tid >> 6;
  __shared__ float A[8][128];
  __shared__ float Bf[8][128];
  __shared__ float mk[8];
#pragma unroll
  for (int rr = 0; rr < 8; rr++) A[rr][tid] = Ores[(size_t)(base + rr) * FD + tid];
  if (tid < 8) mk[tid] = mask[base + tid];
  __syncthreads();
  ln_rows(A, Bf, lane, w, g0[lane], g0[lane + 64], be0[lane], be0[lane + 64], nullptr);
  __syncthreads();
  float acc[8];
  float bof = bo[tid];
#pragma unroll
  for (int rr = 0; rr < 8; rr++) acc[rr] = bof;
  for (int i = 0; i < 128; i++) {
    float wv_ = wo[i * 128 + tid];
#pragma unroll
    for (int rr = 0; rr < 8; rr++) acc[rr] += Bf[rr][i] * wv_;
  }
  __syncthreads();
#pragma unroll
  for (int rr = 0; rr < 8; rr++) A[rr][tid] = Bf[rr][tid] + fmaxf(acc[rr], 0.f);
  __syncthreads();
  ln_rows(A, Bf, lane, w, g1[lane], g1[lane + 64], be1[lane], be1[lane + 64], mk);
  __syncthreads();
  float btif = bti[tid];
#pragma unroll
  for (int rr = 0; rr < 8; rr++) acc[rr] = btif;
  for (int i = 0; i < 128; i++) {
    float wv_ = wti[i * 128 + tid];
#pragma unroll
    for (int rr = 0; rr < 8; rr++) acc[rr] += Bf[rr][i] * wv_;
  }
#pragma unroll
  for (int rr = 0; rr < 8; rr++) {
    float x2 = acc[rr] * mk[rr];
    A[rr][tid] = x2;
    Xp2[(size_t)(base + rr) * FD + tid] = x2;
  }
  __syncthreads();
  int a = tid & 31, rg = tid >> 5;
  float s0 = bas[a], s1 = s0;
  for (int i = 0; i < 128; i++) {
    float wv_ = was[i * NAGG + a];
    s0 += A[2 * rg][i] * wv_;
    s1 += A[2 * rg + 1][i] * wv_;
  }
  S[(size_t)(base + 2 * rg) * NAGG + a] = s0;
  S[(size_t)(base + 2 * rg + 1) * NAGG + a] = s1;
}

// ---- fused softmax-over-T + masked max/mean pooling ----
__global__ void soft_pool_k(const float* __restrict__ S, const float* __restrict__ Xp2,
                            const float* __restrict__ mask,
                            float* __restrict__ aggF, float* __restrict__ agg_out) {
  int b = blockIdx.x >> 5, a = blockIdx.x & 31;
  int f = threadIdx.x;  // 128
  __shared__ float att_s[TT];
  __shared__ float ms[TT];
  __shared__ float red[2];
  float sv[4], mv[4];
#pragma unroll
  for (int j = 0; j < 4; j++) {
    int t = f + j * 128;
    sv[j] = S[(size_t)(b * TT + t) * NAGG + a];
    mv[j] = mask[b * TT + t];
    ms[t] = mv[j];
  }
  float mx = fmaxf(fmaxf(sv[0], sv[1]), fmaxf(sv[2], sv[3]));
#pragma unroll
  for (int o = 32; o > 0; o >>= 1) mx = fmaxf(mx, __shfl_xor(mx, o));
  if ((f & 63) == 0) red[f >> 6] = mx;
  __syncthreads();
  mx = fmaxf(red[0], red[1]);
  __syncthreads();
  float sm = 0.f;
#pragma unroll
  for (int j = 0; j < 4; j++) {
    float e = __expf(sv[j] - mx) * mv[j];
    att_s[f + j * 128] = e;
    sm += e;
  }
#pragma unroll
  for (int o = 32; o > 0; o >>= 1) sm += __shfl_xor(sm, o);
  if ((f & 63) == 0) red[f >> 6] = sm;
  __syncthreads();
  float inv = 1.f / (red[0] + red[1] + 1e-16f);
#pragma unroll
  for (int j = 0; j < 4; j++) att_s[f + j * 128] *= inv;
  __syncthreads();
  float mn = 1e30f, mxm = -1e30f, smv = 0.f, nt = 0.f;
  int anyUn = 0;
#pragma unroll 4
  for (int t = 0; t < TT; t++) {
    float e = Xp2[(size_t)(b * TT + t) * FD + f] * att_s[t];
    mn = fminf(mn, e);
    float m = ms[t];
    if (m > 0.f) { mxm = fmaxf(mxm, e); smv += e; nt += 1.f; }
    else anyUn = 1;
  }
  float mp = anyUn ? fmaxf(mxm, mn - 1.f) : mxm;
  float mean = smv / (nt == 0.f ? 1.f : nt);
  size_t bs = (size_t)b * 8192 + (size_t)a * 256;
  aggF[bs + f] = mp;
  aggF[bs + 128 + f] = mean;
  agg_out[bs + f] = mp;
  agg_out[bs + 128 + f] = mean;
}

// ---- agg @ wto[144:,:]: 32 K-chunks of 256, grid b*32 ----
__global__ void aggmm_k(const float* __restrict__ aggF, const float* __restrict__ wto,
                        float* __restrict__ part) {
  int b = blockIdx.x >> 5, cc = blockIdx.x & 31;
  int f = threadIdx.x;  // 128
  __shared__ float ag[256];
  ag[f] = aggF[(size_t)b * 8192 + cc * 256 + f];
  ag[128 + f] = aggF[(size_t)b * 8192 + cc * 256 + 128 + f];
  __syncthreads();
  const float* w = wto + ((size_t)(IND + FD) + cc * 256) * FD;
  float a0 = 0.f, a1 = 0.f, a2 = 0.f, a3 = 0.f;
#pragma unroll 4
  for (int j = 0; j < 256; j += 4) {
    a0 += ag[j] * w[(size_t)j * FD + f];
    a1 += ag[j + 1] * w[(size_t)(j + 1) * FD + f];
    a2 += ag[j + 2] * w[(size_t)(j + 2) * FD + f];
    a3 += ag[j + 3] * w[(size_t)(j + 3) * FD + f];
  }
  part[(size_t)(b * 32 + cc) * FD + f] = (a0 + a1) + (a2 + a3);
}

// ---- final: relu(LN(X@wto_x + Xp2@wto_p + sum(part) + bto)) * m ----
__global__ void final_k(const float* __restrict__ X, const float* __restrict__ Xp2,
                        const float* __restrict__ part,
                        const float* __restrict__ wto, const float* __restrict__ bto,
                        const float* __restrict__ gto, const float* __restrict__ btoln,
                        const float* __restrict__ mask, float* __restrict__ out) {
  int base = blockIdx.x * 8;
  int b = base >> 9;
  int tid = threadIdx.x;
  int lane = tid & 63, w = tid >> 6;
  __shared__ float A[8][128];
  __shared__ float Bf[8][128];
  __shared__ float xss[8][16];
  __shared__ float mk[8];
#pragma unroll
  for (int rr = 0; rr < 8; rr++) Bf[rr][tid] = Xp2[(size_t)(base + rr) * FD + tid];
  {
    int rr = tid >> 4, ii = tid & 15;
    xss[rr][ii] = X[(size_t)(base + rr) * IND + ii];
  }
  if (tid < 8) mk[tid] = mask[base + tid];
  __syncthreads();
  float psum = 0.f;
#pragma unroll 8
  for (int cc = 0; cc < 32; cc++) psum += part[(size_t)(b * 32 + cc) * FD + tid];
  float acc[8];
  float btof = bto[tid];
#pragma unroll
  for (int rr = 0; rr < 8; rr++) acc[rr] = btof + psum;
#pragma unroll
  for (int i = 0; i < IND; i++) {
    float wv_ = wto[i * FD + tid];
#pragma unroll
    for (int rr = 0; rr < 8; rr++) acc[rr] += xss[rr][i] * wv_;
  }
  for (int i = 0; i < 128; i++) {
    float wv_ = wto[(IND + i) * FD + tid];
#pragma unroll
    for (int rr = 0; rr < 8; rr++) acc[rr] += Bf[rr][i] * wv_;
  }
  __syncthreads();
#pragma unroll
  for (int rr = 0; rr < 8; rr++) A[rr][tid] = acc[rr];
  __syncthreads();
  float ga = gto[lane], gb = gto[lane + 64], ba = btoln[lane], bb = btoln[lane + 64];
  for (int j = 0; j < 4; j++) {
    int rr = w * 4 + j;
    float av = A[rr][lane], bv2 = A[rr][lane + 64];
    float s = av + bv2, ss = av * av + bv2 * bv2;
#pragma unroll
    for (int o = 32; o > 0; o >>= 1) { s += __shfl_xor(s, o); ss += __shfl_xor(ss, o); }
    float mean = s * (1.f / 128.f);
    float var = ss * (1.f / 128.f) - mean * mean;
    float rs = rsqrtf(var + 1e-5f);
    float m = mk[rr];
    out[(size_t)(base + rr) * FD + lane] = fmaxf((av - mean) * rs * ga + ba, 0.f) * m;
    out[(size_t)(base + rr) * FD + lane + 64] = fmaxf((bv2 - mean) * rs * gb + bb, 0.f) * m;
  }
}

extern "C" void kernel_launch(void* const* d_in, const int* in_sizes, int n_in,
                              void* d_out, int out_size, void* d_ws, size_t ws_size,
                              hipStream_t stream) {
  const float* X    = (const float*)d_in[0];
  const float* mask = (const float*)d_in[1];
  const float* wq0 = (const float*)d_in[2];  const float* bq0 = (const float*)d_in[3];
  const float* wk0 = (const float*)d_in[4];  const float* bk0 = (const float*)d_in[5];
  const float* wv0 = (const float*)d_in[6];  const float* bv0 = (const float*)d_in[7];
  const float* wo0 = (const float*)d_in[8];  const float* bo0 = (const float*)d_in[9];
  const float* g00 = (const float*)d_in[10]; const float* be00 = (const float*)d_in[11];
  const float* g10 = (const float*)d_in[12]; const float* be10 = (const float*)d_in[13];
  const float* wq1 = (const float*)d_in[14]; const float* bq1 = (const float*)d_in[15];
  const float* wk1 = (const float*)d_in[16]; const float* bk1 = (const float*)d_in[17];
  const float* wv1 = (const float*)d_in[18]; const float* bv1 = (const float*)d_in[19];
  const float* wo1 = (const float*)d_in[20]; const float* bo1 = (const float*)d_in[21];
  const float* g01 = (const float*)d_in[22]; const float* be01 = (const float*)d_in[23];
  const float* g11 = (const float*)d_in[24]; const float* be11 = (const float*)d_in[25];
  const float* wti = (const float*)d_in[26]; const float* bti = (const float*)d_in[27];
  const float* was = (const float*)d_in[28]; const float* bas = (const float*)d_in[29];
  const float* wto = (const float*)d_in[30]; const float* bto = (const float*)d_in[31];
  const float* gto = (const float*)d_in[32]; const float* btoln = (const float*)d_in[33];

  const size_t BIG = (size_t)BB * TT * FD;  // 2,097,152
  float* ws = (float*)d_ws;
  float* Qf = ws;                         // [0, 2M) fp32 Q / Ores
  ushortt* Kb = (ushortt*)(ws + BIG);     // [2M, 3M) bf16 K
  ushortt* Vt = (ushortt*)(ws + BIG + BIG / 2);  // [3M, 4M) bf16 V^T
  float* Ores = Qf;
  float* Xp2 = ws + BIG;                  // reuses Kb/Vt after attn#2
  float* S    = ws + 2 * BIG;             // [4M, 4.25M)
  float* aggF = ws + 2 * BIG + 262144;    // 256K floats
  float* part = ws + 2 * BIG + 524288;    // 32*32*128 = 128K floats

  float* out_main = (float*)d_out;
  float* out_agg  = (float*)d_out + BIG;

  int nrb = BB * TT / 8;  // 2048
  proj16_k<<<nrb, 128, 0, stream>>>(X, wq0, bq0, wk0, bk0, wv0, bv0, Qf, Kb, Vt);
  attn_k<<<BB * 16, 256, 0, stream>>>(Qf, Kb, Vt, mask, Ores);
  post_proj_k<<<nrb, 128, 0, stream>>>(Ores, mask, wo0, bo0, g00, be00, g10, be10,
                                       wq1, bq1, wk1, bk1, wv1, bv1, Qf, Kb, Vt);
  attn_k<<<BB * 16, 256, 0, stream>>>(Qf, Kb, Vt, mask, Ores);
  post_ti_k<<<nrb, 128, 0, stream>>>(Ores, mask, wo1, bo1, g01, be01, g11, be11,
                                     wti, bti, was, bas, Xp2, S);
  soft_pool_k<<<BB * NAGG, 128, 0, stream>>>(S, Xp2, mask, aggF, out_agg);
  aggmm_k<<<BB * 32, 128, 0, stream>>>(aggF, wto, part);
  final_k<<<nrb, 128, 0, stream>>>(X, Xp2, part, wto, bto, gto, btoln, mask, out_main);
}

// Round 8
// 233.587 us; speedup vs baseline: 11.4876x; 1.1128x over previous
//
#include <hip/hip_runtime.h>
#include <hip/hip_bf16.h>

#define BB 32
#define TT 512
#define IND 16
#define FD 128
#define NAGG 32

typedef unsigned short ushortt;
typedef __attribute__((ext_vector_type(8))) short bf16x8;
typedef __attribute__((ext_vector_type(4))) short s16x4;
typedef __attribute__((ext_vector_type(4))) float f32x4;

__device__ __forceinline__ short f2b(float x) {
  union { __hip_bfloat16 h; short s; } u;
  u.h = __float2bfloat16(x);
  return u.s;
}

#define MFMA_16x16x32(A, B, C) __builtin_amdgcn_mfma_f32_16x16x32_bf16(A, B, C, 0, 0, 0)

// ---- proj16: 8 rows/block; writes Q fp32, K bf16 row-major, V^T bf16 ----
__global__ void proj16_k(const float* __restrict__ X,
                         const float* __restrict__ wq, const float* __restrict__ bq,
                         const float* __restrict__ wk, const float* __restrict__ bk,
                         const float* __restrict__ wv, const float* __restrict__ bv,
                         float* __restrict__ Q, ushortt* __restrict__ Kb,
                         ushortt* __restrict__ Vt) {
  int base = blockIdx.x * 8;
  int b = base >> 9;
  int tloc = base & 511;
  int f = threadIdx.x;
  __shared__ float xs[8][IND];
  {
    int rr = f >> 4, ii = f & 15;
    xs[rr][ii] = X[(size_t)(base + rr) * IND + ii];
  }
  __syncthreads();
  float qa[8], ka[8], va[8];
  float bqf = bq[f], bkf = bk[f], bvf = bv[f];
#pragma unroll
  for (int rr = 0; rr < 8; rr++) { qa[rr] = bqf; ka[rr] = bkf; va[rr] = bvf; }
#pragma unroll
  for (int i = 0; i < IND; i++) {
    float wqv = wq[i * FD + f], wkv = wk[i * FD + f], wvv = wv[i * FD + f];
#pragma unroll
    for (int rr = 0; rr < 8; rr++) {
      float x = xs[rr][i];
      qa[rr] += x * wqv; ka[rr] += x * wkv; va[rr] += x * wvv;
    }
  }
  short vp[8];
#pragma unroll
  for (int rr = 0; rr < 8; rr++) {
    size_t o = (size_t)(base + rr) * FD + f;
    Q[o] = qa[rr];
    Kb[o] = (ushortt)f2b(ka[rr]);
    vp[rr] = f2b(va[rr]);
  }
  *(bf16x8*)&Vt[((size_t)(b * FD) + f) * 512 + tloc] = *(bf16x8*)vp;
}

// ---- MFMA bf16 flash attention v3: double-buffered, 1 barrier/tile ----
__global__ __launch_bounds__(256, 2) void attn_k(const float* __restrict__ Q,
                                                 const ushortt* __restrict__ Kb,
                                                 const ushortt* __restrict__ Vt,
                                                 const float* __restrict__ mask,
                                                 float* __restrict__ Ores) {
  int b = blockIdx.x >> 4;
  int qt = blockIdx.x & 15;
  int tid = threadIdx.x;
  int w = tid >> 6;
  int lane = tid & 63;
  int l15 = lane & 15, g = lane >> 4;

  __shared__ __align__(16) short q_s[32 * 136];
  __shared__ __align__(16) short k_s[2][32 * 136];
  __shared__ __align__(16) short vt_s[2][128 * 40];
  __shared__ __align__(16) short p_s[4][32 * 40];
  __shared__ float msk_s[512];

  const float scale = 0.17677669529663688f;

  msk_s[tid] = mask[b * TT + tid];
  msk_s[256 + tid] = mask[b * TT + 256 + tid];

  int sr = tid >> 3, sc8 = tid & 7;
  size_t qbase = ((size_t)(b * TT + qt * 32 + sr)) * FD + sc8 * 16;
  {
    const float4* src = (const float4*)(Q + qbase);
#pragma unroll
    for (int jj = 0; jj < 4; jj++) {
      float4 v4 = src[jj];
      *(s16x4*)&q_s[sr * 136 + sc8 * 16 + jj * 4] =
          (s16x4){f2b(v4.x), f2b(v4.y), f2b(v4.z), f2b(v4.w)};
    }
  }

  bf16x8 kr[2], vr[2];
  const ushortt* KbB = Kb + (size_t)b * TT * FD;
  const ushortt* VtB = Vt + (size_t)b * FD * 512;

#define LOAD_TILE(kt)                                                              \
  {                                                                                \
    const ushortt* kbp = KbB + (size_t)(kt) * 32 * FD;                             \
    _Pragma("unroll") for (int is = 0; is < 2; is++) {                             \
      int idx = tid + is * 256;                                                    \
      kr[is] = *(const bf16x8*)(kbp + (idx >> 4) * FD + (idx & 15) * 8);           \
      vr[is] = *(const bf16x8*)(VtB + (size_t)(idx >> 2) * 512 + (kt) * 32 +       \
                                (idx & 3) * 8);                                    \
    }                                                                              \
  }
#define WRITE_TILE(buf)                                                            \
  {                                                                                \
    _Pragma("unroll") for (int is = 0; is < 2; is++) {                             \
      int idx = tid + is * 256;                                                    \
      *(bf16x8*)&k_s[buf][(idx >> 4) * 136 + (idx & 15) * 8] = kr[is];             \
      *(bf16x8*)&vt_s[buf][(idx >> 2) * 40 + (idx & 3) * 8] = vr[is];              \
    }                                                                              \
  }

  LOAD_TILE(0);
  WRITE_TILE(0);

  f32x4 o00 = {0.f, 0.f, 0.f, 0.f}, o01 = o00, o10 = o00, o11 = o00;
  float m_st[2][4], l_st[2][4], sc_st[2][4];
#pragma unroll
  for (int mt = 0; mt < 2; mt++)
#pragma unroll
    for (int r = 0; r < 4; r++) { m_st[mt][r] = -1e30f; l_st[mt][r] = 0.f; }

  bf16x8 aq0, aq1;
  int cur = 0;

  for (int kt = 0; kt < 16; kt++) {
    __syncthreads();
    if (kt == 0) {
      aq0 = *(const bf16x8*)&q_s[l15 * 136 + w * 32 + g * 8];
      aq1 = *(const bf16x8*)&q_s[(16 + l15) * 136 + w * 32 + g * 8];
    }
    if (kt < 15) LOAD_TILE(kt + 1);

    bf16x8 bk0 = *(const bf16x8*)&k_s[cur][l15 * 136 + w * 32 + g * 8];
    bf16x8 bk1 = *(const bf16x8*)&k_s[cur][(16 + l15) * 136 + w * 32 + g * 8];
    f32x4 zero = {0.f, 0.f, 0.f, 0.f};
    f32x4 s00 = MFMA_16x16x32(aq0, bk0, zero);
    f32x4 s01 = MFMA_16x16x32(aq0, bk1, zero);
    f32x4 s10 = MFMA_16x16x32(aq1, bk0, zero);
    f32x4 s11 = MFMA_16x16x32(aq1, bk1, zero);
    float mk0 = msk_s[kt * 32 + l15], mk1 = msk_s[kt * 32 + 16 + l15];
#pragma unroll
    for (int mt = 0; mt < 2; mt++) {
#pragma unroll
      for (int r = 0; r < 4; r++) {
        float v0 = mt ? s10[r] : s00[r];
        float v1 = mt ? s11[r] : s01[r];
        float x0 = mk0 > 0.f ? v0 * scale : -1e9f;
        float x1 = mk1 > 0.f ? v1 * scale : -1e9f;
        float rm = fmaxf(x0, x1);
        rm = fmaxf(rm, __shfl_xor(rm, 1));
        rm = fmaxf(rm, __shfl_xor(rm, 2));
        rm = fmaxf(rm, __shfl_xor(rm, 4));
        rm = fmaxf(rm, __shfl_xor(rm, 8));
        float mo = m_st[mt][r];
        float mn = fmaxf(mo, rm);
        float p0 = __expf(x0 - mn);
        float p1 = __expf(x1 - mn);
        float rs = p0 + p1;
        rs += __shfl_xor(rs, 1);
        rs += __shfl_xor(rs, 2);
        rs += __shfl_xor(rs, 4);
        rs += __shfl_xor(rs, 8);
        float scv = __expf(mo - mn);
        m_st[mt][r] = mn;
        l_st[mt][r] = l_st[mt][r] * scv + rs;
        sc_st[mt][r] = scv;
        int qrow = 16 * mt + 4 * g + r;
        p_s[w][qrow * 40 + l15] = f2b(p0);
        p_s[w][qrow * 40 + 16 + l15] = f2b(p1);
      }
    }
    bf16x8 ap0 = *(const bf16x8*)&p_s[w][l15 * 40 + g * 8];
    bf16x8 ap1 = *(const bf16x8*)&p_s[w][(16 + l15) * 40 + g * 8];
    bf16x8 bv0 = *(const bf16x8*)&vt_s[cur][(w * 32 + l15) * 40 + g * 8];
    bf16x8 bv1 = *(const bf16x8*)&vt_s[cur][(w * 32 + 16 + l15) * 40 + g * 8];
#pragma unroll
    for (int r = 0; r < 4; r++) {
      o00[r] *= sc_st[0][r]; o01[r] *= sc_st[0][r];
      o10[r] *= sc_st[1][r]; o11[r] *= sc_st[1][r];
    }
    o00 = MFMA_16x16x32(ap0, bv0, o00);
    o01 = MFMA_16x16x32(ap0, bv1, o01);
    o10 = MFMA_16x16x32(ap1, bv0, o10);
    o11 = MFMA_16x16x32(ap1, bv1, o11);

    if (kt < 15) WRITE_TILE(cur ^ 1);
    cur ^= 1;
  }
  size_t rowbase = (size_t)(b * TT + qt * 32);
#pragma unroll
  for (int mt = 0; mt < 2; mt++) {
#pragma unroll
    for (int r = 0; r < 4; r++) {
      float inv = 1.f / l_st[mt][r];
      int qrow = 16 * mt + 4 * g + r;
      size_t base = (rowbase + qrow) * FD + w * 32 + l15;
      float ov0 = mt ? o10[r] : o00[r];
      float ov1 = mt ? o11[r] : o01[r];
      Ores[base] = Q[base] + ov0 * inv;
      Ores[base + 16] = Q[base + 16] + ov1 * inv;
    }
  }
#undef LOAD_TILE
#undef WRITE_TILE
}

// wave-per-row LN helper
__device__ __forceinline__ void ln_rows(const float (*A)[128], float (*Bf)[128],
                                        int lane, int w,
                                        float ga, float gb, float ba, float bb,
                                        const float* mk) {
  for (int j = 0; j < 4; j++) {
    int rr = w * 4 + j;
    float a = A[rr][lane], b2 = A[rr][lane + 64];
    float s = a + b2, ss = a * a + b2 * b2;
#pragma unroll
    for (int o = 32; o > 0; o >>= 1) { s += __shfl_xor(s, o); ss += __shfl_xor(ss, o); }
    float mean = s * (1.f / 128.f);
    float var = ss * (1.f / 128.f) - mean * mean;
    float rs = rsqrtf(var + 1e-5f);
    float m = mk ? mk[rr] : 1.f;
    Bf[rr][lane] = ((a - mean) * rs * ga + ba) * m;
    Bf[rr][lane + 64] = ((b2 - mean) * rs * gb + bb) * m;
  }
}

// ---- post(layer1) + proj128(layer2) ----
__global__ void post_proj_k(const float* __restrict__ Ores, const float* __restrict__ mask,
                            const float* __restrict__ wo, const float* __restrict__ bo,
                            const float* __restrict__ g0, const float* __restrict__ be0,
                            const float* __restrict__ g1, const float* __restrict__ be1,
                            const float* __restrict__ wq, const float* __restrict__ bq,
                            const float* __restrict__ wk, const float* __restrict__ bk,
                            const float* __restrict__ wv, const float* __restrict__ bv,
                            float* __restrict__ Q, ushortt* __restrict__ Kb,
                            ushortt* __restrict__ Vt) {
  int base = blockIdx.x * 8;
  int b = base >> 9;
  int tloc = base & 511;
  int tid = threadIdx.x;
  int lane = tid & 63, w = tid >> 6;
  __shared__ float A[8][128];
  __shared__ float Bf[8][128];
  __shared__ float mk[8];
#pragma unroll
  for (int rr = 0; rr < 8; rr++) A[rr][tid] = Ores[(size_t)(base + rr) * FD + tid];
  if (tid < 8) mk[tid] = mask[base + tid];
  __syncthreads();
  ln_rows(A, Bf, lane, w, g0[lane], g0[lane + 64], be0[lane], be0[lane + 64], nullptr);
  __syncthreads();
  float acc[8];
  float bof = bo[tid];
#pragma unroll
  for (int rr = 0; rr < 8; rr++) acc[rr] = bof;
  for (int i = 0; i < 128; i++) {
    float wv_ = wo[i * 128 + tid];
#pragma unroll
    for (int rr = 0; rr < 8; rr++) acc[rr] += Bf[rr][i] * wv_;
  }
  __syncthreads();
#pragma unroll
  for (int rr = 0; rr < 8; rr++) A[rr][tid] = Bf[rr][tid] + fmaxf(acc[rr], 0.f);
  __syncthreads();
  ln_rows(A, Bf, lane, w, g1[lane], g1[lane + 64], be1[lane], be1[lane + 64], mk);
  __syncthreads();
  float qa[8], ka[8], va[8];
  float bqf = bq[tid], bkf = bk[tid], bvf = bv[tid];
#pragma unroll
  for (int rr = 0; rr < 8; rr++) { qa[rr] = bqf; ka[rr] = bkf; va[rr] = bvf; }
  for (int i = 0; i < 128; i++) {
    float wqv = wq[i * 128 + tid], wkv = wk[i * 128 + tid], wvv = wv[i * 128 + tid];
#pragma unroll
    for (int rr = 0; rr < 8; rr++) {
      float xv = Bf[rr][i];
      qa[rr] += xv * wqv; ka[rr] += xv * wkv; va[rr] += xv * wvv;
    }
  }
  short vp[8];
#pragma unroll
  for (int rr = 0; rr < 8; rr++) {
    size_t o = (size_t)(base + rr) * FD + tid;
    Q[o] = qa[rr];
    Kb[o] = (ushortt)f2b(ka[rr]);
    vp[rr] = f2b(va[rr]);
  }
  *(bf16x8*)&Vt[((size_t)(b * FD) + tid) * 512 + tloc] = *(bf16x8*)vp;
}

// ---- post(layer2) + ti + as-score ----
__global__ void post_ti_k(const float* __restrict__ Ores, const float* __restrict__ mask,
                          const float* __restrict__ wo, const float* __restrict__ bo,
                          const float* __restrict__ g0, const float* __restrict__ be0,
                          const float* __restrict__ g1, const float* __restrict__ be1,
                          const float* __restrict__ wti, const float* __restrict__ bti,
                          const float* __restrict__ was, const float* __restrict__ bas,
                          float* __restrict__ Xp2, float* __restrict__ S) {
  int base = blockIdx.x * 8;
  int tid = threadIdx.x;
  int lane = tid & 63, w = tid >> 6;
  __shared__ float A[8][128];
  __shared__ float Bf[8][128];
  __shared__ float mk[8];
#pragma unroll
  for (int rr = 0; rr < 8; rr++) A[rr][tid] = Ores[(size_t)(base + rr) * FD + tid];
  if (tid < 8) mk[tid] = mask[base + tid];
  __syncthreads();
  ln_rows(A, Bf, lane, w, g0[lane], g0[lane + 64], be0[lane], be0[lane + 64], nullptr);
  __syncthreads();
  float acc[8];
  float bof = bo[tid];
#pragma unroll
  for (int rr = 0; rr < 8; rr++) acc[rr] = bof;
  for (int i = 0; i < 128; i++) {
    float wv_ = wo[i * 128 + tid];
#pragma unroll
    for (int rr = 0; rr < 8; rr++) acc[rr] += Bf[rr][i] * wv_;
  }
  __syncthreads();
#pragma unroll
  for (int rr = 0; rr < 8; rr++) A[rr][tid] = Bf[rr][tid] + fmaxf(acc[rr], 0.f);
  __syncthreads();
  ln_rows(A, Bf, lane, w, g1[lane], g1[lane + 64], be1[lane], be1[lane + 64], mk);
  __syncthreads();
  float btif = bti[tid];
#pragma unroll
  for (int rr = 0; rr < 8; rr++) acc[rr] = btif;
  for (int i = 0; i < 128; i++) {
    float wv_ = wti[i * 128 + tid];
#pragma unroll
    for (int rr = 0; rr < 8; rr++) acc[rr] += Bf[rr][i] * wv_;
  }
#pragma unroll
  for (int rr = 0; rr < 8; rr++) {
    float x2 = acc[rr] * mk[rr];
    A[rr][tid] = x2;
    Xp2[(size_t)(base + rr) * FD + tid] = x2;
  }
  __syncthreads();
  int a = tid & 31, rg = tid >> 5;
  float s0 = bas[a], s1 = s0;
  for (int i = 0; i < 128; i++) {
    float wv_ = was[i * NAGG + a];
    s0 += A[2 * rg][i] * wv_;
    s1 += A[2 * rg + 1][i] * wv_;
  }
  S[(size_t)(base + 2 * rg) * NAGG + a] = s0;
  S[(size_t)(base + 2 * rg + 1) * NAGG + a] = s1;
}

// ---- soft_t: att[b][a][t] = softmax over T (unmasked max, masked sum) ----
__global__ void soft_t(const float* __restrict__ S, const float* __restrict__ mask,
                       float* __restrict__ att) {
  int b = blockIdx.x >> 5, a = blockIdx.x & 31;
  int tid = threadIdx.x;  // 128
  __shared__ float red[2];
  float sv[4], mv[4];
#pragma unroll
  for (int j = 0; j < 4; j++) {
    int t = tid + j * 128;
    sv[j] = S[(size_t)(b * TT + t) * NAGG + a];
    mv[j] = mask[b * TT + t];
  }
  float mx = fmaxf(fmaxf(sv[0], sv[1]), fmaxf(sv[2], sv[3]));
#pragma unroll
  for (int o = 32; o > 0; o >>= 1) mx = fmaxf(mx, __shfl_xor(mx, o));
  if ((tid & 63) == 0) red[tid >> 6] = mx;
  __syncthreads();
  mx = fmaxf(red[0], red[1]);
  __syncthreads();
  float e[4];
  float sm = 0.f;
#pragma unroll
  for (int j = 0; j < 4; j++) {
    e[j] = __expf(sv[j] - mx) * mv[j];
    sm += e[j];
  }
#pragma unroll
  for (int o = 32; o > 0; o >>= 1) sm += __shfl_xor(sm, o);
  if ((tid & 63) == 0) red[tid >> 6] = sm;
  __syncthreads();
  float inv = 1.f / (red[0] + red[1] + 1e-16f);
  float* dst = att + ((size_t)(b * NAGG + a)) * TT;
#pragma unroll
  for (int j = 0; j < 4; j++) dst[tid + j * 128] = e[j] * inv;
}

// ---- pool_part: partial masked max/min/sum over a 128-t chunk ----
// grid = BB*NAGG*4; blockIdx = b*128 + a*4 + tc
__global__ void pool_part_k(const float* __restrict__ Xp2, const float* __restrict__ att,
                            const float* __restrict__ mask,
                            float* __restrict__ pmax, float* __restrict__ pmin,
                            float* __restrict__ psum) {
  int bid = blockIdx.x;
  int b = bid >> 7;
  int a = (bid >> 2) & 31;
  int tc = bid & 3;
  int f = threadIdx.x;  // 128
  __shared__ float att_s[128];
  __shared__ float ms[128];
  att_s[f] = att[((size_t)(b * NAGG + a)) * TT + tc * 128 + f];
  ms[f] = mask[b * TT + tc * 128 + f];
  __syncthreads();
  const float* xp = Xp2 + ((size_t)(b * TT + tc * 128)) * FD + f;
  float mn = 1e30f, mx = -1e30f, sm = 0.f;
#pragma unroll 4
  for (int t = 0; t < 128; t++) {
    float e = xp[(size_t)t * FD] * att_s[t];
    mn = fminf(mn, e);
    bool keep = ms[t] > 0.f;
    mx = keep ? fmaxf(mx, e) : mx;
    sm = keep ? sm + e : sm;
  }
  size_t idx = (size_t)bid * 128 + f;
  pmax[idx] = mx;
  pmin[idx] = mn;
  psum[idx] = sm;
}

// ---- combine: fold 4 partials + nt; write aggF / agg output ----
__global__ void combine_k(const float* __restrict__ pmax, const float* __restrict__ pmin,
                          const float* __restrict__ psum, const float* __restrict__ mask,
                          float* __restrict__ aggF, float* __restrict__ agg_out) {
  int b = blockIdx.x >> 5, a = blockIdx.x & 31;
  int f = threadIdx.x;  // 128
  __shared__ float red[2];
  float ntp = 0.f;
#pragma unroll
  for (int j = 0; j < 4; j++) ntp += (mask[b * TT + f + j * 128] > 0.f) ? 1.f : 0.f;
#pragma unroll
  for (int o = 32; o > 0; o >>= 1) ntp += __shfl_xor(ntp, o);
  if ((f & 63) == 0) red[f >> 6] = ntp;
  __syncthreads();
  float nt = red[0] + red[1];
  float mx = -1e30f, mn = 1e30f, sm = 0.f;
#pragma unroll
  for (int tc = 0; tc < 4; tc++) {
    size_t idx = ((size_t)(b * 128 + a * 4 + tc)) * 128 + f;
    mx = fmaxf(mx, pmax[idx]);
    mn = fminf(mn, pmin[idx]);
    sm += psum[idx];
  }
  bool anyUn = nt < 511.5f;
  float mp = anyUn ? fmaxf(mx, mn - 1.f) : mx;
  float mean = sm / (nt == 0.f ? 1.f : nt);
  size_t bs = (size_t)b * 8192 + (size_t)a * 256;
  aggF[bs + f] = mp;
  aggF[bs + 128 + f] = mean;
  agg_out[bs + f] = mp;
  agg_out[bs + 128 + f] = mean;
}

// ---- agg @ wto[144:,:]: 32 K-chunks of 256 ----
__global__ void aggmm_k(const float* __restrict__ aggF, const float* __restrict__ wto,
                        float* __restrict__ part) {
  int b = blockIdx.x >> 5, cc = blockIdx.x & 31;
  int f = threadIdx.x;  // 128
  __shared__ float ag[256];
  ag[f] = aggF[(size_t)b * 8192 + cc * 256 + f];
  ag[128 + f] = aggF[(size_t)b * 8192 + cc * 256 + 128 + f];
  __syncthreads();
  const float* w = wto + ((size_t)(IND + FD) + cc * 256) * FD;
  float a0 = 0.f, a1 = 0.f, a2 = 0.f, a3 = 0.f;
#pragma unroll 4
  for (int j = 0; j < 256; j += 4) {
    a0 += ag[j] * w[(size_t)j * FD + f];
    a1 += ag[j + 1] * w[(size_t)(j + 1) * FD + f];
    a2 += ag[j + 2] * w[(size_t)(j + 2) * FD + f];
    a3 += ag[j + 3] * w[(size_t)(j + 3) * FD + f];
  }
  part[(size_t)(b * 32 + cc) * FD + f] = (a0 + a1) + (a2 + a3);
}

// ---- final: relu(LN(X@wto_x + Xp2@wto_p + sum(part) + bto)) * m ----
__global__ void final_k(const float* __restrict__ X, const float* __restrict__ Xp2,
                        const float* __restrict__ part,
                        const float* __restrict__ wto, const float* __restrict__ bto,
                        const float* __restrict__ gto, const float* __restrict__ btoln,
                        const float* __restrict__ mask, float* __restrict__ out) {
  int base = blockIdx.x * 8;
  int b = base >> 9;
  int tid = threadIdx.x;
  int lane = tid & 63, w = tid >> 6;
  __shared__ float A[8][128];
  __shared__ float Bf[8][128];
  __shared__ float xss[8][16];
  __shared__ float mk[8];
#pragma unroll
  for (int rr = 0; rr < 8; rr++) Bf[rr][tid] = Xp2[(size_t)(base + rr) * FD + tid];
  {
    int rr = tid >> 4, ii = tid & 15;
    xss[rr][ii] = X[(size_t)(base + rr) * IND + ii];
  }
  if (tid < 8) mk[tid] = mask[base + tid];
  __syncthreads();
  float psum = 0.f;
#pragma unroll 8
  for (int cc = 0; cc < 32; cc++) psum += part[(size_t)(b * 32 + cc) * FD + tid];
  float acc[8];
  float btof = bto[tid];
#pragma unroll
  for (int rr = 0; rr < 8; rr++) acc[rr] = btof + psum;
#pragma unroll
  for (int i = 0; i < IND; i++) {
    float wv_ = wto[i * FD + tid];
#pragma unroll
    for (int rr = 0; rr < 8; rr++) acc[rr] += xss[rr][i] * wv_;
  }
  for (int i = 0; i < 128; i++) {
    float wv_ = wto[(IND + i) * FD + tid];
#pragma unroll
    for (int rr = 0; rr < 8; rr++) acc[rr] += Bf[rr][i] * wv_;
  }
  __syncthreads();
#pragma unroll
  for (int rr = 0; rr < 8; rr++) A[rr][tid] = acc[rr];
  __syncthreads();
  float ga = gto[lane], gb = gto[lane + 64], ba = btoln[lane], bb = btoln[lane + 64];
  for (int j = 0; j < 4; j++) {
    int rr = w * 4 + j;
    float av = A[rr][lane], bv2 = A[rr][lane + 64];
    float s = av + bv2, ss = av * av + bv2 * bv2;
#pragma unroll
    for (int o = 32; o > 0; o >>= 1) { s += __shfl_xor(s, o); ss += __shfl_xor(ss, o); }
    float mean = s * (1.f / 128.f);
    float var = ss * (1.f / 128.f) - mean * mean;
    float rs = rsqrtf(var + 1e-5f);
    float m = mk[rr];
    out[(size_t)(base + rr) * FD + lane] = fmaxf((av - mean) * rs * ga + ba, 0.f) * m;
    out[(size_t)(base + rr) * FD + lane + 64] = fmaxf((bv2 - mean) * rs * gb + bb, 0.f) * m;
  }
}

extern "C" void kernel_launch(void* const* d_in, const int* in_sizes, int n_in,
                              void* d_out, int out_size, void* d_ws, size_t ws_size,
                              hipStream_t stream) {
  const float* X    = (const float*)d_in[0];
  const float* mask = (const float*)d_in[1];
  const float* wq0 = (const float*)d_in[2];  const float* bq0 = (const float*)d_in[3];
  const float* wk0 = (const float*)d_in[4];  const float* bk0 = (const float*)d_in[5];
  const float* wv0 = (const float*)d_in[6];  const float* bv0 = (const float*)d_in[7];
  const float* wo0 = (const float*)d_in[8];  const float* bo0 = (const float*)d_in[9];
  const float* g00 = (const float*)d_in[10]; const float* be00 = (const float*)d_in[11];
  const float* g10 = (const float*)d_in[12]; const float* be10 = (const float*)d_in[13];
  const float* wq1 = (const float*)d_in[14]; const float* bq1 = (const float*)d_in[15];
  const float* wk1 = (const float*)d_in[16]; const float* bk1 = (const float*)d_in[17];
  const float* wv1 = (const float*)d_in[18]; const float* bv1 = (const float*)d_in[19];
  const float* wo1 = (const float*)d_in[20]; const float* bo1 = (const float*)d_in[21];
  const float* g01 = (const float*)d_in[22]; const float* be01 = (const float*)d_in[23];
  const float* g11 = (const float*)d_in[24]; const float* be11 = (const float*)d_in[25];
  const float* wti = (const float*)d_in[26]; const float* bti = (const float*)d_in[27];
  const float* was = (const float*)d_in[28]; const float* bas = (const float*)d_in[29];
  const float* wto = (const float*)d_in[30]; const float* bto = (const float*)d_in[31];
  const float* gto = (const float*)d_in[32]; const float* btoln = (const float*)d_in[33];

  const size_t BIG = (size_t)BB * TT * FD;  // 2,097,152 floats
  float* ws = (float*)d_ws;
  float* Qf = ws;                                 // [0, BIG) fp32 Q / Ores
  ushortt* Kb = (ushortt*)(ws + BIG);             // bf16 K
  ushortt* Vt = (ushortt*)(ws + BIG + BIG / 2);   // bf16 V^T
  float* Ores = Qf;
  float* Xp2 = ws + BIG;                          // reuses Kb/Vt after attn#2
  float* S    = ws + 2 * BIG;                     // 524288 floats (full, no overlap)
  float* att  = ws + 2 * BIG + 524288;            // 524288 floats
  float* aggF = ws + 2 * BIG + 1048576;           // 262144 floats
  float* part = ws + 2 * BIG + 1310720;           // 131072 floats
  // partials reuse dead Qf/Ores region (Ores consumed by post_ti_k):
  float* pmax = ws;                               // 524288 floats
  float* pmin = ws + 524288;
  float* psum = ws + 1048576;                     // ends at 1572864 < BIG

  float* out_main = (float*)d_out;
  float* out_agg  = (float*)d_out + BIG;

  int nrb = BB * TT / 8;  // 2048
  proj16_k<<<nrb, 128, 0, stream>>>(X, wq0, bq0, wk0, bk0, wv0, bv0, Qf, Kb, Vt);
  attn_k<<<BB * 16, 256, 0, stream>>>(Qf, Kb, Vt, mask, Ores);
  post_proj_k<<<nrb, 128, 0, stream>>>(Ores, mask, wo0, bo0, g00, be00, g10, be10,
                                       wq1, bq1, wk1, bk1, wv1, bv1, Qf, Kb, Vt);
  attn_k<<<BB * 16, 256, 0, stream>>>(Qf, Kb, Vt, mask, Ores);
  post_ti_k<<<nrb, 128, 0, stream>>>(Ores, mask, wo1, bo1, g01, be01, g11, be11,
                                     wti, bti, was, bas, Xp2, S);
  soft_t<<<BB * NAGG, 128, 0, stream>>>(S, mask, att);
  pool_part_k<<<BB * NAGG * 4, 128, 0, stream>>>(Xp2, att, mask, pmax, pmin, psum);
  combine_k<<<BB * NAGG, 128, 0, stream>>>(pmax, pmin, psum, mask, aggF, out_agg);
  aggmm_k<<<BB * 32, 128, 0, stream>>>(aggF, wto, part);
  final_k<<<nrb, 128, 0, stream>>>(X, Xp2, part, wto, bto, gto, btoln, mask, out_main);
}

// Round 9
// 182.664 us; speedup vs baseline: 14.6900x; 1.2788x over previous
//
#include <hip/hip_runtime.h>
#include <hip/hip_bf16.h>

#define BB 32
#define TT 512
#define IND 16
#define FD 128
#define NAGG 32

typedef unsigned short ushortt;
typedef __attribute__((ext_vector_type(8))) short bf16x8;
typedef __attribute__((ext_vector_type(4))) short s16x4;
typedef __attribute__((ext_vector_type(4))) float f32x4;

__device__ __forceinline__ short f2b(float x) {
  union { __hip_bfloat16 h; short s; } u;
  u.h = __float2bfloat16(x);
  return u.s;
}

#define MFMA_16x16x32(A, B, C) __builtin_amdgcn_mfma_f32_16x16x32_bf16(A, B, C, 0, 0, 0)

// K=128 GEMM over 32-row LDS tile Xb, cols c0/c1 per wave, frags per m89 mapping.
#define GEMM128(WT, c00, c01, c10, c11)                                        \
  {                                                                            \
    _Pragma("unroll") for (int ks = 0; ks < 4; ks++) {                         \
      bf16x8 a0 = *(const bf16x8*)&Xb[l15][ks * 32 + g * 8];                   \
      bf16x8 a1 = *(const bf16x8*)&Xb[16 + l15][ks * 32 + g * 8];              \
      bf16x8 b0 = *(const bf16x8*)((WT) + (size_t)c0 * 128 + ks * 32 + g * 8); \
      bf16x8 b1 = *(const bf16x8*)((WT) + (size_t)c1 * 128 + ks * 32 + g * 8); \
      c00 = MFMA_16x16x32(a0, b0, c00);                                        \
      c01 = MFMA_16x16x32(a0, b1, c01);                                        \
      c10 = MFMA_16x16x32(a1, b0, c10);                                        \
      c11 = MFMA_16x16x32(a1, b1, c11);                                        \
    }                                                                          \
  }

// ---- prep: transpose weights to bf16 W^T. grid 8*4, 256 thr ----
__global__ void prep_w_k(const float* __restrict__ wo0, const float* __restrict__ wq1,
                         const float* __restrict__ wk1, const float* __restrict__ wv1,
                         const float* __restrict__ wo1, const float* __restrict__ wti,
                         const float* __restrict__ wto, const float* __restrict__ was,
                         ushortt* __restrict__ Wt) {
  int m = blockIdx.x >> 2;
  int slab = blockIdx.x & 3;
  int tid = threadIdx.x;
  if (m == 7) {  // wast[32][128] from was[128][32]
    __shared__ float t[32][33];
    int iloc = tid >> 3, c4 = (tid & 7) * 4;
    *(float4*)&t[iloc][c4] = *(const float4*)(was + (size_t)(slab * 32 + iloc) * 32 + c4);
    __syncthreads();
    int a = tid & 31, ch = tid >> 5;
    short p[4];
#pragma unroll
    for (int k = 0; k < 4; k++) p[k] = f2b(t[ch * 4 + k][a]);
    *(s16x4*)(Wt + (size_t)7 * 16384 + (size_t)a * 128 + slab * 32 + ch * 4) = *(s16x4*)p;
  } else {
    const float* src = m == 0 ? wo0 : m == 1 ? wq1 : m == 2 ? wk1
                     : m == 3 ? wv1 : m == 4 ? wo1 : m == 5 ? wti : wto + IND * FD;
    __shared__ float t[32][132];
    int r = tid >> 3, c16 = (tid & 7) * 16;
    const float4* s4 = (const float4*)(src + (size_t)(slab * 32 + r) * 128 + c16);
#pragma unroll
    for (int jj = 0; jj < 4; jj++) *(float4*)&t[r][c16 + jj * 4] = s4[jj];
    __syncthreads();
    int f = tid >> 1, ih = (tid & 1) * 16;
    short p[16];
#pragma unroll
    for (int k = 0; k < 16; k++) p[k] = f2b(t[ih + k][f]);
    ushortt* dst = Wt + (size_t)m * 16384 + (size_t)f * 128 + slab * 32 + ih;
    *(bf16x8*)dst = *(bf16x8*)&p[0];
    *(bf16x8*)(dst + 8) = *(bf16x8*)&p[8];
  }
}

// ---- proj16: 8 rows/block; writes Q fp32, K bf16 row-major, V^T bf16 ----
__global__ void proj16_k(const float* __restrict__ X,
                         const float* __restrict__ wq, const float* __restrict__ bq,
                         const float* __restrict__ wk, const float* __restrict__ bk,
                         const float* __restrict__ wv, const float* __restrict__ bv,
                         float* __restrict__ Q, ushortt* __restrict__ Kb,
                         ushortt* __restrict__ Vt) {
  int base = blockIdx.x * 8;
  int b = base >> 9;
  int tloc = base & 511;
  int f = threadIdx.x;
  __shared__ float xs[8][IND];
  {
    int rr = f >> 4, ii = f & 15;
    xs[rr][ii] = X[(size_t)(base + rr) * IND + ii];
  }
  __syncthreads();
  float qa[8], ka[8], va[8];
  float bqf = bq[f], bkf = bk[f], bvf = bv[f];
#pragma unroll
  for (int rr = 0; rr < 8; rr++) { qa[rr] = bqf; ka[rr] = bkf; va[rr] = bvf; }
#pragma unroll
  for (int i = 0; i < IND; i++) {
    float wqv = wq[i * FD + f], wkv = wk[i * FD + f], wvv = wv[i * FD + f];
#pragma unroll
    for (int rr = 0; rr < 8; rr++) {
      float x = xs[rr][i];
      qa[rr] += x * wqv; ka[rr] += x * wkv; va[rr] += x * wvv;
    }
  }
  short vp[8];
#pragma unroll
  for (int rr = 0; rr < 8; rr++) {
    size_t o = (size_t)(base + rr) * FD + f;
    Q[o] = qa[rr];
    Kb[o] = (ushortt)f2b(ka[rr]);
    vp[rr] = f2b(va[rr]);
  }
  *(bf16x8*)&Vt[((size_t)(b * FD) + f) * 512 + tloc] = *(bf16x8*)vp;
}

// ---- MFMA bf16 flash attention (unchanged from r7) ----
__global__ __launch_bounds__(256, 2) void attn_k(const float* __restrict__ Q,
                                                 const ushortt* __restrict__ Kb,
                                                 const ushortt* __restrict__ Vt,
                                                 const float* __restrict__ mask,
                                                 float* __restrict__ Ores) {
  int b = blockIdx.x >> 4;
  int qt = blockIdx.x & 15;
  int tid = threadIdx.x;
  int w = tid >> 6;
  int lane = tid & 63;
  int l15 = lane & 15, g = lane >> 4;

  __shared__ __align__(16) short q_s[32 * 136];
  __shared__ __align__(16) short k_s[2][32 * 136];
  __shared__ __align__(16) short vt_s[2][128 * 40];
  __shared__ __align__(16) short p_s[4][32 * 40];
  __shared__ float msk_s[512];

  const float scale = 0.17677669529663688f;

  msk_s[tid] = mask[b * TT + tid];
  msk_s[256 + tid] = mask[b * TT + 256 + tid];

  int sr = tid >> 3, sc8 = tid & 7;
  size_t qbase = ((size_t)(b * TT + qt * 32 + sr)) * FD + sc8 * 16;
  {
    const float4* src = (const float4*)(Q + qbase);
#pragma unroll
    for (int jj = 0; jj < 4; jj++) {
      float4 v4 = src[jj];
      *(s16x4*)&q_s[sr * 136 + sc8 * 16 + jj * 4] =
          (s16x4){f2b(v4.x), f2b(v4.y), f2b(v4.z), f2b(v4.w)};
    }
  }

  bf16x8 kr[2], vr[2];
  const ushortt* KbB = Kb + (size_t)b * TT * FD;
  const ushortt* VtB = Vt + (size_t)b * FD * 512;

#define LOAD_TILE(kt)                                                              \
  {                                                                                \
    const ushortt* kbp = KbB + (size_t)(kt) * 32 * FD;                             \
    _Pragma("unroll") for (int is = 0; is < 2; is++) {                             \
      int idx = tid + is * 256;                                                    \
      kr[is] = *(const bf16x8*)(kbp + (idx >> 4) * FD + (idx & 15) * 8);           \
      vr[is] = *(const bf16x8*)(VtB + (size_t)(idx >> 2) * 512 + (kt) * 32 +       \
                                (idx & 3) * 8);                                    \
    }                                                                              \
  }
#define WRITE_TILE(buf)                                                            \
  {                                                                                \
    _Pragma("unroll") for (int is = 0; is < 2; is++) {                             \
      int idx = tid + is * 256;                                                    \
      *(bf16x8*)&k_s[buf][(idx >> 4) * 136 + (idx & 15) * 8] = kr[is];             \
      *(bf16x8*)&vt_s[buf][(idx >> 2) * 40 + (idx & 3) * 8] = vr[is];              \
    }                                                                              \
  }

  LOAD_TILE(0);
  WRITE_TILE(0);

  f32x4 o00 = {0.f, 0.f, 0.f, 0.f}, o01 = o00, o10 = o00, o11 = o00;
  float m_st[2][4], l_st[2][4], sc_st[2][4];
#pragma unroll
  for (int mt = 0; mt < 2; mt++)
#pragma unroll
    for (int r = 0; r < 4; r++) { m_st[mt][r] = -1e30f; l_st[mt][r] = 0.f; }

  bf16x8 aq0, aq1;
  int cur = 0;

  for (int kt = 0; kt < 16; kt++) {
    __syncthreads();
    if (kt == 0) {
      aq0 = *(const bf16x8*)&q_s[l15 * 136 + w * 32 + g * 8];
      aq1 = *(const bf16x8*)&q_s[(16 + l15) * 136 + w * 32 + g * 8];
    }
    if (kt < 15) LOAD_TILE(kt + 1);

    bf16x8 bk0 = *(const bf16x8*)&k_s[cur][l15 * 136 + w * 32 + g * 8];
    bf16x8 bk1 = *(const bf16x8*)&k_s[cur][(16 + l15) * 136 + w * 32 + g * 8];
    f32x4 zero = {0.f, 0.f, 0.f, 0.f};
    f32x4 s00 = MFMA_16x16x32(aq0, bk0, zero);
    f32x4 s01 = MFMA_16x16x32(aq0, bk1, zero);
    f32x4 s10 = MFMA_16x16x32(aq1, bk0, zero);
    f32x4 s11 = MFMA_16x16x32(aq1, bk1, zero);
    float mk0 = msk_s[kt * 32 + l15], mk1 = msk_s[kt * 32 + 16 + l15];
#pragma unroll
    for (int mt = 0; mt < 2; mt++) {
#pragma unroll
      for (int r = 0; r < 4; r++) {
        float v0 = mt ? s10[r] : s00[r];
        float v1 = mt ? s11[r] : s01[r];
        float x0 = mk0 > 0.f ? v0 * scale : -1e9f;
        float x1 = mk1 > 0.f ? v1 * scale : -1e9f;
        float rm = fmaxf(x0, x1);
        rm = fmaxf(rm, __shfl_xor(rm, 1));
        rm = fmaxf(rm, __shfl_xor(rm, 2));
        rm = fmaxf(rm, __shfl_xor(rm, 4));
        rm = fmaxf(rm, __shfl_xor(rm, 8));
        float mo = m_st[mt][r];
        float mn = fmaxf(mo, rm);
        float p0 = __expf(x0 - mn);
        float p1 = __expf(x1 - mn);
        float rs = p0 + p1;
        rs += __shfl_xor(rs, 1);
        rs += __shfl_xor(rs, 2);
        rs += __shfl_xor(rs, 4);
        rs += __shfl_xor(rs, 8);
        float scv = __expf(mo - mn);
        m_st[mt][r] = mn;
        l_st[mt][r] = l_st[mt][r] * scv + rs;
        sc_st[mt][r] = scv;
        int qrow = 16 * mt + 4 * g + r;
        p_s[w][qrow * 40 + l15] = f2b(p0);
        p_s[w][qrow * 40 + 16 + l15] = f2b(p1);
      }
    }
    bf16x8 ap0 = *(const bf16x8*)&p_s[w][l15 * 40 + g * 8];
    bf16x8 ap1 = *(const bf16x8*)&p_s[w][(16 + l15) * 40 + g * 8];
    bf16x8 bv0 = *(const bf16x8*)&vt_s[cur][(w * 32 + l15) * 40 + g * 8];
    bf16x8 bv1 = *(const bf16x8*)&vt_s[cur][(w * 32 + 16 + l15) * 40 + g * 8];
#pragma unroll
    for (int r = 0; r < 4; r++) {
      o00[r] *= sc_st[0][r]; o01[r] *= sc_st[0][r];
      o10[r] *= sc_st[1][r]; o11[r] *= sc_st[1][r];
    }
    o00 = MFMA_16x16x32(ap0, bv0, o00);
    o01 = MFMA_16x16x32(ap0, bv1, o01);
    o10 = MFMA_16x16x32(ap1, bv0, o10);
    o11 = MFMA_16x16x32(ap1, bv1, o11);

    if (kt < 15) WRITE_TILE(cur ^ 1);
    cur ^= 1;
  }
  size_t rowbase = (size_t)(b * TT + qt * 32);
#pragma unroll
  for (int mt = 0; mt < 2; mt++) {
#pragma unroll
    for (int r = 0; r < 4; r++) {
      float inv = 1.f / l_st[mt][r];
      int qrow = 16 * mt + 4 * g + r;
      size_t base = (rowbase + qrow) * FD + w * 32 + l15;
      float ov0 = mt ? o10[r] : o00[r];
      float ov1 = mt ? o11[r] : o01[r];
      Ores[base] = Q[base] + ov0 * inv;
      Ores[base + 16] = Q[base + 16] + ov1 * inv;
    }
  }
#undef LOAD_TILE
#undef WRITE_TILE
}

// LN over 32-row fp32 tile; writes fp32 back + bf16 copy. wave w owns rows w*8..w*8+7.
__device__ __forceinline__ void ln32(float (*A)[132], short (*Xb)[136], int lane, int w,
                                     const float* __restrict__ gg,
                                     const float* __restrict__ bb,
                                     const float* mk, bool applyMask) {
  float ga = gg[lane], gb = gg[lane + 64], ba = bb[lane], b2 = bb[lane + 64];
  for (int j = 0; j < 8; j++) {
    int rr = w * 8 + j;
    float a = A[rr][lane], c = A[rr][lane + 64];
    float s = a + c, ss = a * a + c * c;
#pragma unroll
    for (int o = 32; o > 0; o >>= 1) { s += __shfl_xor(s, o); ss += __shfl_xor(ss, o); }
    float mean = s * (1.f / 128.f);
    float var = ss * (1.f / 128.f) - mean * mean;
    float rs = rsqrtf(var + 1e-5f);
    float m = applyMask ? mk[rr] : 1.f;
    float y0 = ((a - mean) * rs * ga + ba) * m;
    float y1 = ((c - mean) * rs * gb + b2) * m;
    A[rr][lane] = y0; A[rr][lane + 64] = y1;
    Xb[rr][lane] = f2b(y0); Xb[rr][lane + 64] = f2b(y1);
  }
}

// ---- post(layer1) + proj128(layer2), MFMA version: 32 rows/block, 4 waves ----
__global__ __launch_bounds__(256) void post_proj_k(
    const float* __restrict__ Ores, const float* __restrict__ mask,
    const ushortt* __restrict__ wot, const float* __restrict__ bo,
    const float* __restrict__ g0, const float* __restrict__ be0,
    const float* __restrict__ g1, const float* __restrict__ be1,
    const ushortt* __restrict__ wqt, const float* __restrict__ bq,
    const ushortt* __restrict__ wkt, const float* __restrict__ bk,
    const ushortt* __restrict__ wvt, const float* __restrict__ bv,
    float* __restrict__ Q, ushortt* __restrict__ Kb, ushortt* __restrict__ Vt) {
  int base = blockIdx.x * 32;
  int b = base >> 9;
  int tloc = base & 511;
  int tid = threadIdx.x;
  int w = tid >> 6, lane = tid & 63;
  int l15 = lane & 15, g = lane >> 4;

  __shared__ float A32[32][132];
  __shared__ __align__(16) short Xb[32][136];
  __shared__ float mk[32];

  {
    int r = tid >> 3, c = (tid & 7) * 16;
    const float4* src = (const float4*)(Ores + (size_t)(base + r) * FD + c);
#pragma unroll
    for (int jj = 0; jj < 4; jj++) *(float4*)&A32[r][c + jj * 4] = src[jj];
  }
  if (tid < 32) mk[tid] = mask[base + tid];
  __syncthreads();
  ln32(A32, Xb, lane, w, g0, be0, mk, false);
  __syncthreads();

  int c0 = w * 32 + l15, c1 = c0 + 16;
  // FFN
  f32x4 f00 = {0.f, 0.f, 0.f, 0.f}, f01 = f00, f10 = f00, f11 = f00;
  GEMM128(wot, f00, f01, f10, f11);
  float bo0 = bo[c0], bo1 = bo[c1];
#pragma unroll
  for (int r = 0; r < 4; r++) {
    int r0 = g * 4 + r, r1 = 16 + r0;
    A32[r0][c0] += fmaxf(f00[r] + bo0, 0.f);
    A32[r0][c1] += fmaxf(f01[r] + bo1, 0.f);
    A32[r1][c0] += fmaxf(f10[r] + bo0, 0.f);
    A32[r1][c1] += fmaxf(f11[r] + bo1, 0.f);
  }
  __syncthreads();
  ln32(A32, Xb, lane, w, g1, be1, mk, true);
  __syncthreads();

  // Q projection
  {
    f32x4 q00 = {0.f, 0.f, 0.f, 0.f}, q01 = q00, q10 = q00, q11 = q00;
    GEMM128(wqt, q00, q01, q10, q11);
    float bq0 = bq[c0], bq1 = bq[c1];
#pragma unroll
    for (int r = 0; r < 4; r++) {
      int r0 = g * 4 + r, r1 = 16 + r0;
      Q[(size_t)(base + r0) * FD + c0] = q00[r] + bq0;
      Q[(size_t)(base + r0) * FD + c1] = q01[r] + bq1;
      Q[(size_t)(base + r1) * FD + c0] = q10[r] + bq0;
      Q[(size_t)(base + r1) * FD + c1] = q11[r] + bq1;
    }
  }
  // K projection
  {
    f32x4 k00 = {0.f, 0.f, 0.f, 0.f}, k01 = k00, k10 = k00, k11 = k00;
    GEMM128(wkt, k00, k01, k10, k11);
    float bk0 = bk[c0], bk1 = bk[c1];
#pragma unroll
    for (int r = 0; r < 4; r++) {
      int r0 = g * 4 + r, r1 = 16 + r0;
      Kb[(size_t)(base + r0) * FD + c0] = (ushortt)f2b(k00[r] + bk0);
      Kb[(size_t)(base + r0) * FD + c1] = (ushortt)f2b(k01[r] + bk1);
      Kb[(size_t)(base + r1) * FD + c0] = (ushortt)f2b(k10[r] + bk0);
      Kb[(size_t)(base + r1) * FD + c1] = (ushortt)f2b(k11[r] + bk1);
    }
  }
  // V projection -> transposed store (4 consecutive t per lane)
  {
    f32x4 v00 = {0.f, 0.f, 0.f, 0.f}, v01 = v00, v10 = v00, v11 = v00;
    GEMM128(wvt, v00, v01, v10, v11);
    float bv0 = bv[c0], bv1 = bv[c1];
    short p[4];
#pragma unroll
    for (int k = 0; k < 4; k++) p[k] = f2b(v00[k] + bv0);
    *(s16x4*)&Vt[((size_t)b * FD + c0) * 512 + tloc + g * 4] = *(s16x4*)p;
#pragma unroll
    for (int k = 0; k < 4; k++) p[k] = f2b(v01[k] + bv1);
    *(s16x4*)&Vt[((size_t)b * FD + c1) * 512 + tloc + g * 4] = *(s16x4*)p;
#pragma unroll
    for (int k = 0; k < 4; k++) p[k] = f2b(v10[k] + bv0);
    *(s16x4*)&Vt[((size_t)b * FD + c0) * 512 + tloc + 16 + g * 4] = *(s16x4*)p;
#pragma unroll
    for (int k = 0; k < 4; k++) p[k] = f2b(v11[k] + bv1);
    *(s16x4*)&Vt[((size_t)b * FD + c1) * 512 + tloc + 16 + g * 4] = *(s16x4*)p;
  }
}

// ---- post(layer2) + ti + as-score, MFMA version ----
__global__ __launch_bounds__(256) void post_ti_k(
    const float* __restrict__ Ores, const float* __restrict__ mask,
    const ushortt* __restrict__ wot, const float* __restrict__ bo,
    const float* __restrict__ g0, const float* __restrict__ be0,
    const float* __restrict__ g1, const float* __restrict__ be1,
    const ushortt* __restrict__ wtit, const float* __restrict__ bti,
    const ushortt* __restrict__ wast, const float* __restrict__ bas,
    float* __restrict__ Xp2, float* __restrict__ S) {
  int base = blockIdx.x * 32;
  int tid = threadIdx.x;
  int w = tid >> 6, lane = tid & 63;
  int l15 = lane & 15, g = lane >> 4;

  __shared__ float A32[32][132];
  __shared__ __align__(16) short Xb[32][136];
  __shared__ float mk[32];

  {
    int r = tid >> 3, c = (tid & 7) * 16;
    const float4* src = (const float4*)(Ores + (size_t)(base + r) * FD + c);
#pragma unroll
    for (int jj = 0; jj < 4; jj++) *(float4*)&A32[r][c + jj * 4] = src[jj];
  }
  if (tid < 32) mk[tid] = mask[base + tid];
  __syncthreads();
  ln32(A32, Xb, lane, w, g0, be0, mk, false);
  __syncthreads();

  int c0 = w * 32 + l15, c1 = c0 + 16;
  f32x4 f00 = {0.f, 0.f, 0.f, 0.f}, f01 = f00, f10 = f00, f11 = f00;
  GEMM128(wot, f00, f01, f10, f11);
  float bo0 = bo[c0], bo1 = bo[c1];
#pragma unroll
  for (int r = 0; r < 4; r++) {
    int r0 = g * 4 + r, r1 = 16 + r0;
    A32[r0][c0] += fmaxf(f00[r] + bo0, 0.f);
    A32[r0][c1] += fmaxf(f01[r] + bo1, 0.f);
    A32[r1][c0] += fmaxf(f10[r] + bo0, 0.f);
    A32[r1][c1] += fmaxf(f11[r] + bo1, 0.f);
  }
  __syncthreads();
  ln32(A32, Xb, lane, w, g1, be1, mk, true);
  __syncthreads();

  // ti
  f32x4 t00 = {0.f, 0.f, 0.f, 0.f}, t01 = t00, t10 = t00, t11 = t00;
  GEMM128(wtit, t00, t01, t10, t11);
  float bti0 = bti[c0], bti1 = bti[c1];
#pragma unroll
  for (int r = 0; r < 4; r++) {
    int r0 = g * 4 + r, r1 = 16 + r0;
    float v00 = (t00[r] + bti0) * mk[r0];
    float v01 = (t01[r] + bti1) * mk[r0];
    float v10 = (t10[r] + bti0) * mk[r1];
    float v11 = (t11[r] + bti1) * mk[r1];
    Xp2[(size_t)(base + r0) * FD + c0] = v00;
    Xp2[(size_t)(base + r0) * FD + c1] = v01;
    Xp2[(size_t)(base + r1) * FD + c0] = v10;
    Xp2[(size_t)(base + r1) * FD + c1] = v11;
    Xb[r0][c0] = f2b(v00); Xb[r0][c1] = f2b(v01);
    Xb[r1][c0] = f2b(v10); Xb[r1][c1] = f2b(v11);
  }
  __syncthreads();
  // S = Xp2 @ was + bas (waves 0,1: 16 agg cols each)
  if (w < 2) {
    int a0 = w * 16 + l15;
    f32x4 s0 = {0.f, 0.f, 0.f, 0.f}, s1 = s0;
#pragma unroll
    for (int ks = 0; ks < 4; ks++) {
      bf16x8 aa0 = *(const bf16x8*)&Xb[l15][ks * 32 + g * 8];
      bf16x8 aa1 = *(const bf16x8*)&Xb[16 + l15][ks * 32 + g * 8];
      bf16x8 bb0 = *(const bf16x8*)(wast + (size_t)a0 * 128 + ks * 32 + g * 8);
      s0 = MFMA_16x16x32(aa0, bb0, s0);
      s1 = MFMA_16x16x32(aa1, bb0, s1);
    }
    float bas0 = bas[a0];
#pragma unroll
    for (int r = 0; r < 4; r++) {
      int r0 = g * 4 + r;
      S[(size_t)(base + r0) * NAGG + a0] = s0[r] + bas0;
      S[(size_t)(base + 16 + r0) * NAGG + a0] = s1[r] + bas0;
    }
  }
}

// ---- soft_t ----
__global__ void soft_t(const float* __restrict__ S, const float* __restrict__ mask,
                       float* __restrict__ att) {
  int b = blockIdx.x >> 5, a = blockIdx.x & 31;
  int tid = threadIdx.x;  // 128
  __shared__ float red[2];
  float sv[4], mv[4];
#pragma unroll
  for (int j = 0; j < 4; j++) {
    int t = tid + j * 128;
    sv[j] = S[(size_t)(b * TT + t) * NAGG + a];
    mv[j] = mask[b * TT + t];
  }
  float mx = fmaxf(fmaxf(sv[0], sv[1]), fmaxf(sv[2], sv[3]));
#pragma unroll
  for (int o = 32; o > 0; o >>= 1) mx = fmaxf(mx, __shfl_xor(mx, o));
  if ((tid & 63) == 0) red[tid >> 6] = mx;
  __syncthreads();
  mx = fmaxf(red[0], red[1]);
  __syncthreads();
  float e[4];
  float sm = 0.f;
#pragma unroll
  for (int j = 0; j < 4; j++) {
    e[j] = __expf(sv[j] - mx) * mv[j];
    sm += e[j];
  }
#pragma unroll
  for (int o = 32; o > 0; o >>= 1) sm += __shfl_xor(sm, o);
  if ((tid & 63) == 0) red[tid >> 6] = sm;
  __syncthreads();
  float inv = 1.f / (red[0] + red[1] + 1e-16f);
  float* dst = att + ((size_t)(b * NAGG + a)) * TT;
#pragma unroll
  for (int j = 0; j < 4; j++) dst[tid + j * 128] = e[j] * inv;
}

// ---- pool_part ----
__global__ void pool_part_k(const float* __restrict__ Xp2, const float* __restrict__ att,
                            const float* __restrict__ mask,
                            float* __restrict__ pmax, float* __restrict__ pmin,
                            float* __restrict__ psum) {
  int bid = blockIdx.x;
  int b = bid >> 7;
  int a = (bid >> 2) & 31;
  int tc = bid & 3;
  int f = threadIdx.x;
  __shared__ float att_s[128];
  __shared__ float ms[128];
  att_s[f] = att[((size_t)(b * NAGG + a)) * TT + tc * 128 + f];
  ms[f] = mask[b * TT + tc * 128 + f];
  __syncthreads();
  const float* xp = Xp2 + ((size_t)(b * TT + tc * 128)) * FD + f;
  float mn = 1e30f, mx = -1e30f, sm = 0.f;
#pragma unroll 4
  for (int t = 0; t < 128; t++) {
    float e = xp[(size_t)t * FD] * att_s[t];
    mn = fminf(mn, e);
    bool keep = ms[t] > 0.f;
    mx = keep ? fmaxf(mx, e) : mx;
    sm = keep ? sm + e : sm;
  }
  size_t idx = (size_t)bid * 128 + f;
  pmax[idx] = mx;
  pmin[idx] = mn;
  psum[idx] = sm;
}

// ---- combine ----
__global__ void combine_k(const float* __restrict__ pmax, const float* __restrict__ pmin,
                          const float* __restrict__ psum, const float* __restrict__ mask,
                          float* __restrict__ aggF, float* __restrict__ agg_out) {
  int b = blockIdx.x >> 5, a = blockIdx.x & 31;
  int f = threadIdx.x;
  __shared__ float red[2];
  float ntp = 0.f;
#pragma unroll
  for (int j = 0; j < 4; j++) ntp += (mask[b * TT + f + j * 128] > 0.f) ? 1.f : 0.f;
#pragma unroll
  for (int o = 32; o > 0; o >>= 1) ntp += __shfl_xor(ntp, o);
  if ((f & 63) == 0) red[f >> 6] = ntp;
  __syncthreads();
  float nt = red[0] + red[1];
  float mx = -1e30f, mn = 1e30f, sm = 0.f;
#pragma unroll
  for (int tc = 0; tc < 4; tc++) {
    size_t idx = ((size_t)(b * 128 + a * 4 + tc)) * 128 + f;
    mx = fmaxf(mx, pmax[idx]);
    mn = fminf(mn, pmin[idx]);
    sm += psum[idx];
  }
  bool anyUn = nt < 511.5f;
  float mp = anyUn ? fmaxf(mx, mn - 1.f) : mx;
  float mean = sm / (nt == 0.f ? 1.f : nt);
  size_t bs = (size_t)b * 8192 + (size_t)a * 256;
  aggF[bs + f] = mp;
  aggF[bs + 128 + f] = mean;
  agg_out[bs + f] = mp;
  agg_out[bs + 128 + f] = mean;
}

// ---- aggmm ----
__global__ void aggmm_k(const float* __restrict__ aggF, const float* __restrict__ wto,
                        float* __restrict__ part) {
  int b = blockIdx.x >> 5, cc = blockIdx.x & 31;
  int f = threadIdx.x;
  __shared__ float ag[256];
  ag[f] = aggF[(size_t)b * 8192 + cc * 256 + f];
  ag[128 + f] = aggF[(size_t)b * 8192 + cc * 256 + 128 + f];
  __syncthreads();
  const float* w = wto + ((size_t)(IND + FD) + cc * 256) * FD;
  float a0 = 0.f, a1 = 0.f, a2 = 0.f, a3 = 0.f;
#pragma unroll 4
  for (int j = 0; j < 256; j += 4) {
    a0 += ag[j] * w[(size_t)j * FD + f];
    a1 += ag[j + 1] * w[(size_t)(j + 1) * FD + f];
    a2 += ag[j + 2] * w[(size_t)(j + 2) * FD + f];
    a3 += ag[j + 3] * w[(size_t)(j + 3) * FD + f];
  }
  part[(size_t)(b * 32 + cc) * FD + f] = (a0 + a1) + (a2 + a3);
}

// ---- final, MFMA version ----
__global__ __launch_bounds__(256) void final_k(
    const float* __restrict__ X, const float* __restrict__ Xp2,
    const float* __restrict__ part, const ushortt* __restrict__ wtot,
    const float* __restrict__ wto, const float* __restrict__ bto,
    const float* __restrict__ gto, const float* __restrict__ btoln,
    const float* __restrict__ mask, float* __restrict__ out) {
  int base = blockIdx.x * 32;
  int b = base >> 9;
  int tid = threadIdx.x;
  int w = tid >> 6, lane = tid & 63;
  int l15 = lane & 15, g = lane >> 4;
  __shared__ float A32[32][132];
  __shared__ __align__(16) short Xb[32][136];
  __shared__ float xss[32][17];
  __shared__ float psum_s[128];
  __shared__ float mk[32];
  {
    int r = tid >> 3, c = (tid & 7) * 16;
    const float4* src = (const float4*)(Xp2 + (size_t)(base + r) * FD + c);
#pragma unroll
    for (int jj = 0; jj < 4; jj++) {
      float4 v = src[jj];
      *(s16x4*)&Xb[r][c + jj * 4] = (s16x4){f2b(v.x), f2b(v.y), f2b(v.z), f2b(v.w)};
    }
  }
  {
    int r = tid >> 3, ii = (tid & 7) * 2;
    xss[r][ii] = X[(size_t)(base + r) * IND + ii];
    xss[r][ii + 1] = X[(size_t)(base + r) * IND + ii + 1];
  }
  if (tid < 32) mk[tid] = mask[base + tid];
  if (tid < 128) {
    float ps = 0.f;
#pragma unroll 8
    for (int cc = 0; cc < 32; cc++) ps += part[(size_t)(b * 32 + cc) * FD + tid];
    psum_s[tid] = ps;
  }
  __syncthreads();
  int c0 = w * 32 + l15, c1 = c0 + 16;
  f32x4 q00 = {0.f, 0.f, 0.f, 0.f}, q01 = q00, q10 = q00, q11 = q00;
  GEMM128(wtot, q00, q01, q10, q11);
  float wx0[16], wx1[16];
#pragma unroll
  for (int i = 0; i < 16; i++) { wx0[i] = wto[i * FD + c0]; wx1[i] = wto[i * FD + c1]; }
  float add0 = bto[c0] + psum_s[c0], add1 = bto[c1] + psum_s[c1];
#pragma unroll
  for (int r = 0; r < 4; r++) {
    int r0 = g * 4 + r, r1 = 16 + r0;
    float x00 = q00[r] + add0, x01 = q01[r] + add1;
    float x10 = q10[r] + add0, x11 = q11[r] + add1;
#pragma unroll
    for (int i = 0; i < 16; i++) {
      x00 += xss[r0][i] * wx0[i];
      x01 += xss[r0][i] * wx1[i];
      x10 += xss[r1][i] * wx0[i];
      x11 += xss[r1][i] * wx1[i];
    }
    A32[r0][c0] = x00; A32[r0][c1] = x01;
    A32[r1][c0] = x10; A32[r1][c1] = x11;
  }
  __syncthreads();
  float ga = gto[lane], gb = gto[lane + 64], ba = btoln[lane], bb2 = btoln[lane + 64];
  for (int j = 0; j < 8; j++) {
    int rr = w * 8 + j;
    float a = A32[rr][lane], c = A32[rr][lane + 64];
    float s = a + c, ss = a * a + c * c;
#pragma unroll
    for (int o = 32; o > 0; o >>= 1) { s += __shfl_xor(s, o); ss += __shfl_xor(ss, o); }
    float mean = s * (1.f / 128.f);
    float var = ss * (1.f / 128.f) - mean * mean;
    float rs = rsqrtf(var + 1e-5f);
    float m = mk[rr];
    out[(size_t)(base + rr) * FD + lane] = fmaxf((a - mean) * rs * ga + ba, 0.f) * m;
    out[(size_t)(base + rr) * FD + lane + 64] = fmaxf((c - mean) * rs * gb + bb2, 0.f) * m;
  }
}

extern "C" void kernel_launch(void* const* d_in, const int* in_sizes, int n_in,
                              void* d_out, int out_size, void* d_ws, size_t ws_size,
                              hipStream_t stream) {
  const float* X    = (const float*)d_in[0];
  const float* mask = (const float*)d_in[1];
  const float* wq0 = (const float*)d_in[2];  const float* bq0 = (const float*)d_in[3];
  const float* wk0 = (const float*)d_in[4];  const float* bk0 = (const float*)d_in[5];
  const float* wv0 = (const float*)d_in[6];  const float* bv0 = (const float*)d_in[7];
  const float* wo0 = (const float*)d_in[8];  const float* bo0 = (const float*)d_in[9];
  const float* g00 = (const float*)d_in[10]; const float* be00 = (const float*)d_in[11];
  const float* g10 = (const float*)d_in[12]; const float* be10 = (const float*)d_in[13];
  const float* wq1 = (const float*)d_in[14]; const float* bq1 = (const float*)d_in[15];
  const float* wk1 = (const float*)d_in[16]; const float* bk1 = (const float*)d_in[17];
  const float* wv1 = (const float*)d_in[18]; const float* bv1 = (const float*)d_in[19];
  const float* wo1 = (const float*)d_in[20]; const float* bo1 = (const float*)d_in[21];
  const float* g01 = (const float*)d_in[22]; const float* be01 = (const float*)d_in[23];
  const float* g11 = (const float*)d_in[24]; const float* be11 = (const float*)d_in[25];
  const float* wti = (const float*)d_in[26]; const float* bti = (const float*)d_in[27];
  const float* was = (const float*)d_in[28]; const float* bas = (const float*)d_in[29];
  const float* wto = (const float*)d_in[30]; const float* bto = (const float*)d_in[31];
  const float* gto = (const float*)d_in[32]; const float* btoln = (const float*)d_in[33];

  const size_t BIG = (size_t)BB * TT * FD;  // 2,097,152 floats
  float* ws = (float*)d_ws;
  float* Qf = ws;
  ushortt* Kb = (ushortt*)(ws + BIG);
  ushortt* Vt = (ushortt*)(ws + BIG + BIG / 2);
  float* Ores = Qf;
  float* Xp2 = ws + BIG;
  float* S    = ws + 2 * BIG;
  float* att  = ws + 2 * BIG + 524288;
  float* aggF = ws + 2 * BIG + 1048576;
  float* part = ws + 2 * BIG + 1310720;
  ushortt* Wt = (ushortt*)(ws + 2 * BIG + 1441792);  // 8 x 16384 bf16
  float* pmax = ws;
  float* pmin = ws + 524288;
  float* psum = ws + 1048576;

  ushortt* wo0t = Wt;
  ushortt* wq1t = Wt + 16384;
  ushortt* wk1t = Wt + 2 * 16384;
  ushortt* wv1t = Wt + 3 * 16384;
  ushortt* wo1t = Wt + 4 * 16384;
  ushortt* wtit = Wt + 5 * 16384;
  ushortt* wtot = Wt + 6 * 16384;
  ushortt* wast = Wt + 7 * 16384;

  float* out_main = (float*)d_out;
  float* out_agg  = (float*)d_out + BIG;

  int nrb = BB * TT / 8;    // 2048
  int nrb32 = BB * TT / 32; // 512
  prep_w_k<<<32, 256, 0, stream>>>(wo0, wq1, wk1, wv1, wo1, wti, wto, was, Wt);
  proj16_k<<<nrb, 128, 0, stream>>>(X, wq0, bq0, wk0, bk0, wv0, bv0, Qf, Kb, Vt);
  attn_k<<<BB * 16, 256, 0, stream>>>(Qf, Kb, Vt, mask, Ores);
  post_proj_k<<<nrb32, 256, 0, stream>>>(Ores, mask, wo0t, bo0, g00, be00, g10, be10,
                                         wq1t, bq1, wk1t, bk1, wv1t, bv1, Qf, Kb, Vt);
  attn_k<<<BB * 16, 256, 0, stream>>>(Qf, Kb, Vt, mask, Ores);
  post_ti_k<<<nrb32, 256, 0, stream>>>(Ores, mask, wo1t, bo1, g01, be01, g11, be11,
                                       wtit, bti, wast, bas, Xp2, S);
  soft_t<<<BB * NAGG, 128, 0, stream>>>(S, mask, att);
  pool_part_k<<<BB * NAGG * 4, 128, 0, stream>>>(Xp2, att, mask, pmax, pmin, psum);
  combine_k<<<BB * NAGG, 128, 0, stream>>>(pmax, pmin, psum, mask, aggF, out_agg);
  aggmm_k<<<BB * 32, 128, 0, stream>>>(aggF, wto, part);
  final_k<<<nrb32, 256, 0, stream>>>(X, Xp2, part, wtot, wto, bto, gto, btoln, mask, out_main);
}

// Round 10
// 144.777 us; speedup vs baseline: 18.5344x; 1.2617x over previous
//
#include <hip/hip_runtime.h>
#include <hip/hip_bf16.h>

#define BB 32
#define TT 512
#define IND 16
#define FD 128
#define NAGG 32

typedef unsigned short ushortt;
typedef unsigned int uintt;
typedef __attribute__((ext_vector_type(8))) short bf16x8;
typedef __attribute__((ext_vector_type(4))) short s16x4;
typedef __attribute__((ext_vector_type(4))) float f32x4;

__device__ __forceinline__ short f2b(float x) {
  union { __hip_bfloat16 h; short s; } u;
  u.h = __float2bfloat16(x);
  return u.s;
}

#define MFMA_16x16x32(A, B, C) __builtin_amdgcn_mfma_f32_16x16x32_bf16(A, B, C, 0, 0, 0)

// K=128 GEMM over 32-row LDS tile Xb, cols c0/c1 per wave, frags per m89 mapping.
#define GEMM128(WT, c00, c01, c10, c11)                                        \
  {                                                                            \
    _Pragma("unroll") for (int ks = 0; ks < 4; ks++) {                         \
      bf16x8 a0 = *(const bf16x8*)&Xb[l15][ks * 32 + g * 8];                   \
      bf16x8 a1 = *(const bf16x8*)&Xb[16 + l15][ks * 32 + g * 8];              \
      bf16x8 b0 = *(const bf16x8*)((WT) + (size_t)c0 * 128 + ks * 32 + g * 8); \
      bf16x8 b1 = *(const bf16x8*)((WT) + (size_t)c1 * 128 + ks * 32 + g * 8); \
      c00 = MFMA_16x16x32(a0, b0, c00);                                        \
      c01 = MFMA_16x16x32(a0, b1, c01);                                        \
      c10 = MFMA_16x16x32(a1, b0, c10);                                        \
      c11 = MFMA_16x16x32(a1, b1, c11);                                        \
    }                                                                          \
  }

// ---- prep: transpose weights to bf16 W^T. grid 8*4, 256 thr ----
__global__ void prep_w_k(const float* __restrict__ wo0, const float* __restrict__ wq1,
                         const float* __restrict__ wk1, const float* __restrict__ wv1,
                         const float* __restrict__ wo1, const float* __restrict__ wti,
                         const float* __restrict__ wto, const float* __restrict__ was,
                         ushortt* __restrict__ Wt) {
  int m = blockIdx.x >> 2;
  int slab = blockIdx.x & 3;
  int tid = threadIdx.x;
  if (m == 7) {  // wast[32][128] from was[128][32]
    __shared__ float t[32][33];
    int iloc = tid >> 3, c4 = (tid & 7) * 4;
    *(float4*)&t[iloc][c4] = *(const float4*)(was + (size_t)(slab * 32 + iloc) * 32 + c4);
    __syncthreads();
    int a = tid & 31, ch = tid >> 5;
    short p[4];
#pragma unroll
    for (int k = 0; k < 4; k++) p[k] = f2b(t[ch * 4 + k][a]);
    *(s16x4*)(Wt + (size_t)7 * 16384 + (size_t)a * 128 + slab * 32 + ch * 4) = *(s16x4*)p;
  } else {
    const float* src = m == 0 ? wo0 : m == 1 ? wq1 : m == 2 ? wk1
                     : m == 3 ? wv1 : m == 4 ? wo1 : m == 5 ? wti : wto + IND * FD;
    __shared__ float t[32][132];
    int r = tid >> 3, c16 = (tid & 7) * 16;
    const float4* s4 = (const float4*)(src + (size_t)(slab * 32 + r) * 128 + c16);
#pragma unroll
    for (int jj = 0; jj < 4; jj++) *(float4*)&t[r][c16 + jj * 4] = s4[jj];
    __syncthreads();
    int f = tid >> 1, ih = (tid & 1) * 16;
    short p[16];
#pragma unroll
    for (int k = 0; k < 16; k++) p[k] = f2b(t[ih + k][f]);
    ushortt* dst = Wt + (size_t)m * 16384 + (size_t)f * 128 + slab * 32 + ih;
    *(bf16x8*)dst = *(bf16x8*)&p[0];
    *(bf16x8*)(dst + 8) = *(bf16x8*)&p[8];
  }
}

// ---- proj16: 8 rows/block; writes Q fp32, K bf16 row-major, V^T bf16 ----
__global__ void proj16_k(const float* __restrict__ X,
                         const float* __restrict__ wq, const float* __restrict__ bq,
                         const float* __restrict__ wk, const float* __restrict__ bk,
                         const float* __restrict__ wv, const float* __restrict__ bv,
                         float* __restrict__ Q, ushortt* __restrict__ Kb,
                         ushortt* __restrict__ Vt) {
  int base = blockIdx.x * 8;
  int b = base >> 9;
  int tloc = base & 511;
  int f = threadIdx.x;
  __shared__ float xs[8][IND];
  {
    int rr = f >> 4, ii = f & 15;
    xs[rr][ii] = X[(size_t)(base + rr) * IND + ii];
  }
  __syncthreads();
  float qa[8], ka[8], va[8];
  float bqf = bq[f], bkf = bk[f], bvf = bv[f];
#pragma unroll
  for (int rr = 0; rr < 8; rr++) { qa[rr] = bqf; ka[rr] = bkf; va[rr] = bvf; }
#pragma unroll
  for (int i = 0; i < IND; i++) {
    float wqv = wq[i * FD + f], wkv = wk[i * FD + f], wvv = wv[i * FD + f];
#pragma unroll
    for (int rr = 0; rr < 8; rr++) {
      float x = xs[rr][i];
      qa[rr] += x * wqv; ka[rr] += x * wkv; va[rr] += x * wvv;
    }
  }
  short vp[8];
#pragma unroll
  for (int rr = 0; rr < 8; rr++) {
    size_t o = (size_t)(base + rr) * FD + f;
    Q[o] = qa[rr];
    Kb[o] = (ushortt)f2b(ka[rr]);
    vp[rr] = f2b(va[rr]);
  }
  *(bf16x8*)&Vt[((size_t)(b * FD) + f) * 512 + tloc] = *(bf16x8*)vp;
}

// ---- MFMA bf16 flash attention v4: swapped QK^T + in-register softmax + defer-max ----
// grid BB*16, 256 thr = 4 waves (wave w = head). S^T layout: col=q=l15, row=k=16mt+4g+r.
__global__ __launch_bounds__(256, 2) void attn_k(const float* __restrict__ Q,
                                                 const ushortt* __restrict__ Kb,
                                                 const ushortt* __restrict__ Vt,
                                                 const float* __restrict__ mask,
                                                 float* __restrict__ Ores) {
  int b = blockIdx.x >> 4;
  int qt = blockIdx.x & 15;
  int tid = threadIdx.x;
  int w = tid >> 6;
  int lane = tid & 63;
  int l15 = lane & 15, g = lane >> 4;

  __shared__ __align__(16) short q_s[32 * 136];
  __shared__ __align__(16) short k_s[2][32 * 136];
  __shared__ __align__(16) short vt_s[2][128 * 40];
  __shared__ __align__(16) short p_s[4][32 * 40];
  __shared__ __align__(16) float msk_s[512];
  __shared__ __align__(16) float xch[4][32];  // scv / l exchange, wave-local

  const float scale = 0.17677669529663688f;  // 1/sqrt(32), pre-applied to Q

  msk_s[tid] = mask[b * TT + tid];
  msk_s[256 + tid] = mask[b * TT + 256 + tid];

  int sr = tid >> 3, sc8 = tid & 7;
  size_t qbase = ((size_t)(b * TT + qt * 32 + sr)) * FD + sc8 * 16;
  {  // stage Q pre-scaled -> bf16 LDS
    const float4* src = (const float4*)(Q + qbase);
#pragma unroll
    for (int jj = 0; jj < 4; jj++) {
      float4 v4 = src[jj];
      *(s16x4*)&q_s[sr * 136 + sc8 * 16 + jj * 4] =
          (s16x4){f2b(v4.x * scale), f2b(v4.y * scale), f2b(v4.z * scale),
                  f2b(v4.w * scale)};
    }
  }

  bf16x8 kr[2], vr[2];
  const ushortt* KbB = Kb + (size_t)b * TT * FD;
  const ushortt* VtB = Vt + (size_t)b * FD * 512;

#define LOAD_TILE(kt)                                                              \
  {                                                                                \
    const ushortt* kbp = KbB + (size_t)(kt) * 32 * FD;                             \
    _Pragma("unroll") for (int is = 0; is < 2; is++) {                             \
      int idx = tid + is * 256;                                                    \
      kr[is] = *(const bf16x8*)(kbp + (idx >> 4) * FD + (idx & 15) * 8);           \
      vr[is] = *(const bf16x8*)(VtB + (size_t)(idx >> 2) * 512 + (kt) * 32 +       \
                                (idx & 3) * 8);                                    \
    }                                                                              \
  }
#define WRITE_TILE(buf)                                                            \
  {                                                                                \
    _Pragma("unroll") for (int is = 0; is < 2; is++) {                             \
      int idx = tid + is * 256;                                                    \
      *(bf16x8*)&k_s[buf][(idx >> 4) * 136 + (idx & 15) * 8] = kr[is];             \
      *(bf16x8*)&vt_s[buf][(idx >> 2) * 40 + (idx & 3) * 8] = vr[is];              \
    }                                                                              \
  }

  LOAD_TILE(0);
  WRITE_TILE(0);

  f32x4 o00 = {0.f, 0.f, 0.f, 0.f}, o01 = o00, o10 = o00, o11 = o00;
  float m0 = -1e30f, m1 = -1e30f, l0 = 0.f, l1 = 0.f;

  bf16x8 aq0, aq1;
  int cur = 0;

  for (int kt = 0; kt < 16; kt++) {
    __syncthreads();
    if (kt == 0) {
      aq0 = *(const bf16x8*)&q_s[l15 * 136 + w * 32 + g * 8];
      aq1 = *(const bf16x8*)&q_s[(16 + l15) * 136 + w * 32 + g * 8];
    }
    if (kt < 15) LOAD_TILE(kt + 1);

    // swapped QK^T: st = K·Q^T, rows k, cols q
    bf16x8 bk0 = *(const bf16x8*)&k_s[cur][l15 * 136 + w * 32 + g * 8];
    bf16x8 bk1 = *(const bf16x8*)&k_s[cur][(16 + l15) * 136 + w * 32 + g * 8];
    f32x4 zero = {0.f, 0.f, 0.f, 0.f};
    f32x4 st00 = MFMA_16x16x32(bk0, aq0, zero);  // k 0-15, q 0-15
    f32x4 st01 = MFMA_16x16x32(bk0, aq1, zero);  // k 0-15, q 16-31
    f32x4 st10 = MFMA_16x16x32(bk1, aq0, zero);  // k 16-31, q 0-15
    f32x4 st11 = MFMA_16x16x32(bk1, aq1, zero);  // k 16-31, q 16-31

    float4 mk0 = *(const float4*)&msk_s[kt * 32 + 4 * g];
    float4 mk1 = *(const float4*)&msk_s[kt * 32 + 16 + 4 * g];
    float x0[8], x1[8];
#pragma unroll
    for (int r = 0; r < 4; r++) {
      x0[r] = mk0[r] > 0.f ? st00[r] : -1e9f;
      x0[4 + r] = mk1[r] > 0.f ? st10[r] : -1e9f;
      x1[r] = mk0[r] > 0.f ? st01[r] : -1e9f;
      x1[4 + r] = mk1[r] > 0.f ? st11[r] : -1e9f;
    }
    // per-q max: 8 in-lane + 2 cross-lane (4 lanes per q-column)
    float lm0 = x0[0], lm1 = x1[0];
#pragma unroll
    for (int i = 1; i < 8; i++) { lm0 = fmaxf(lm0, x0[i]); lm1 = fmaxf(lm1, x1[i]); }
    lm0 = fmaxf(lm0, __shfl_xor(lm0, 16));
    lm0 = fmaxf(lm0, __shfl_xor(lm0, 32));
    lm1 = fmaxf(lm1, __shfl_xor(lm1, 16));
    lm1 = fmaxf(lm1, __shfl_xor(lm1, 32));
    // defer-max: rescale only when max grows past threshold
    bool need = (lm0 > m0 + 8.f) || (lm1 > m1 + 8.f);
    if (__any(need)) {
      float mn0 = fmaxf(m0, lm0), mn1 = fmaxf(m1, lm1);
      float scv0 = __expf(m0 - mn0), scv1 = __expf(m1 - mn1);
      m0 = mn0; m1 = mn1;
      l0 *= scv0; l1 *= scv1;
      if (lane < 16) { xch[w][l15] = scv0; xch[w][16 + l15] = scv1; }
      float4 sa = *(const float4*)&xch[w][4 * g];
      float4 sb = *(const float4*)&xch[w][16 + 4 * g];
#pragma unroll
      for (int r = 0; r < 4; r++) {
        o00[r] *= sa[r]; o01[r] *= sa[r];
        o10[r] *= sb[r]; o11[r] *= sb[r];
      }
    }
    float p0[8], p1[8];
    float rs0 = 0.f, rs1 = 0.f;
#pragma unroll
    for (int i = 0; i < 8; i++) {
      p0[i] = __expf(x0[i] - m0); rs0 += p0[i];
      p1[i] = __expf(x1[i] - m1); rs1 += p1[i];
    }
    rs0 += __shfl_xor(rs0, 16); rs0 += __shfl_xor(rs0, 32);
    rs1 += __shfl_xor(rs1, 16); rs1 += __shfl_xor(rs1, 32);
    l0 += rs0; l1 += rs1;
    // pack P -> [q][k] b64 stores (k = 16mt+4g+r contiguous per mt)
    {
      uintt a0 = ((uintt)(ushortt)f2b(p0[1]) << 16) | (ushortt)f2b(p0[0]);
      uintt a1 = ((uintt)(ushortt)f2b(p0[3]) << 16) | (ushortt)f2b(p0[2]);
      uintt a2 = ((uintt)(ushortt)f2b(p0[5]) << 16) | (ushortt)f2b(p0[4]);
      uintt a3 = ((uintt)(ushortt)f2b(p0[7]) << 16) | (ushortt)f2b(p0[6]);
      uintt b0 = ((uintt)(ushortt)f2b(p1[1]) << 16) | (ushortt)f2b(p1[0]);
      uintt b1 = ((uintt)(ushortt)f2b(p1[3]) << 16) | (ushortt)f2b(p1[2]);
      uintt b2 = ((uintt)(ushortt)f2b(p1[5]) << 16) | (ushortt)f2b(p1[4]);
      uintt b3 = ((uintt)(ushortt)f2b(p1[7]) << 16) | (ushortt)f2b(p1[6]);
      *(uint2*)&p_s[w][l15 * 40 + 4 * g] = make_uint2(a0, a1);
      *(uint2*)&p_s[w][l15 * 40 + 16 + 4 * g] = make_uint2(a2, a3);
      *(uint2*)&p_s[w][(16 + l15) * 40 + 4 * g] = make_uint2(b0, b1);
      *(uint2*)&p_s[w][(16 + l15) * 40 + 16 + 4 * g] = make_uint2(b2, b3);
    }
    // AV (unchanged fragment reads; wave-local P ordering via lgkmcnt)
    bf16x8 ap0 = *(const bf16x8*)&p_s[w][l15 * 40 + g * 8];
    bf16x8 ap1 = *(const bf16x8*)&p_s[w][(16 + l15) * 40 + g * 8];
    bf16x8 bv0 = *(const bf16x8*)&vt_s[cur][(w * 32 + l15) * 40 + g * 8];
    bf16x8 bv1 = *(const bf16x8*)&vt_s[cur][(w * 32 + 16 + l15) * 40 + g * 8];
    o00 = MFMA_16x16x32(ap0, bv0, o00);
    o01 = MFMA_16x16x32(ap0, bv1, o01);
    o10 = MFMA_16x16x32(ap1, bv0, o10);
    o11 = MFMA_16x16x32(ap1, bv1, o11);

    if (kt < 15) WRITE_TILE(cur ^ 1);
    cur ^= 1;
  }
  // epilogue: exchange l per q-row, Ores = Q + O/l
  if (lane < 16) { xch[w][l15] = l0; xch[w][16 + l15] = l1; }
  float4 la = *(const float4*)&xch[w][4 * g];
  float4 lb = *(const float4*)&xch[w][16 + 4 * g];
  size_t rowbase = (size_t)(b * TT + qt * 32);
#pragma unroll
  for (int r = 0; r < 4; r++) {
    int q0r = 4 * g + r;
    size_t base0 = (rowbase + q0r) * FD + w * 32 + l15;
    Ores[base0] = Q[base0] + o00[r] / la[r];
    Ores[base0 + 16] = Q[base0 + 16] + o01[r] / la[r];
    int q1r = 16 + 4 * g + r;
    size_t base1 = (rowbase + q1r) * FD + w * 32 + l15;
    Ores[base1] = Q[base1] + o10[r] / lb[r];
    Ores[base1 + 16] = Q[base1 + 16] + o11[r] / lb[r];
  }
#undef LOAD_TILE
#undef WRITE_TILE
}

// LN over 32-row fp32 tile; writes fp32 back + bf16 copy. wave w owns rows w*8..w*8+7.
__device__ __forceinline__ void ln32(float (*A)[132], short (*Xb)[136], int lane, int w,
                                     const float* __restrict__ gg,
                                     const float* __restrict__ bb,
                                     const float* mk, bool applyMask) {
  float ga = gg[lane], gb = gg[lane + 64], ba = bb[lane], b2 = bb[lane + 64];
  for (int j = 0; j < 8; j++) {
    int rr = w * 8 + j;
    float a = A[rr][lane], c = A[rr][lane + 64];
    float s = a + c, ss = a * a + c * c;
#pragma unroll
    for (int o = 32; o > 0; o >>= 1) { s += __shfl_xor(s, o); ss += __shfl_xor(ss, o); }
    float mean = s * (1.f / 128.f);
    float var = ss * (1.f / 128.f) - mean * mean;
    float rs = rsqrtf(var + 1e-5f);
    float m = applyMask ? mk[rr] : 1.f;
    float y0 = ((a - mean) * rs * ga + ba) * m;
    float y1 = ((c - mean) * rs * gb + b2) * m;
    A[rr][lane] = y0; A[rr][lane + 64] = y1;
    Xb[rr][lane] = f2b(y0); Xb[rr][lane + 64] = f2b(y1);
  }
}

// ---- post(layer1) + proj128(layer2), MFMA version: 32 rows/block, 4 waves ----
__global__ __launch_bounds__(256) void post_proj_k(
    const float* __restrict__ Ores, const float* __restrict__ mask,
    const ushortt* __restrict__ wot, const float* __restrict__ bo,
    const float* __restrict__ g0, const float* __restrict__ be0,
    const float* __restrict__ g1, const float* __restrict__ be1,
    const ushortt* __restrict__ wqt, const float* __restrict__ bq,
    const ushortt* __restrict__ wkt, const float* __restrict__ bk,
    const ushortt* __restrict__ wvt, const float* __restrict__ bv,
    float* __restrict__ Q, ushortt* __restrict__ Kb, ushortt* __restrict__ Vt) {
  int base = blockIdx.x * 32;
  int b = base >> 9;
  int tloc = base & 511;
  int tid = threadIdx.x;
  int w = tid >> 6, lane = tid & 63;
  int l15 = lane & 15, g = lane >> 4;

  __shared__ float A32[32][132];
  __shared__ __align__(16) short Xb[32][136];
  __shared__ float mk[32];

  {
    int r = tid >> 3, c = (tid & 7) * 16;
    const float4* src = (const float4*)(Ores + (size_t)(base + r) * FD + c);
#pragma unroll
    for (int jj = 0; jj < 4; jj++) *(float4*)&A32[r][c + jj * 4] = src[jj];
  }
  if (tid < 32) mk[tid] = mask[base + tid];
  __syncthreads();
  ln32(A32, Xb, lane, w, g0, be0, mk, false);
  __syncthreads();

  int c0 = w * 32 + l15, c1 = c0 + 16;
  // FFN
  f32x4 f00 = {0.f, 0.f, 0.f, 0.f}, f01 = f00, f10 = f00, f11 = f00;
  GEMM128(wot, f00, f01, f10, f11);
  float bo0 = bo[c0], bo1 = bo[c1];
#pragma unroll
  for (int r = 0; r < 4; r++) {
    int r0 = g * 4 + r, r1 = 16 + r0;
    A32[r0][c0] += fmaxf(f00[r] + bo0, 0.f);
    A32[r0][c1] += fmaxf(f01[r] + bo1, 0.f);
    A32[r1][c0] += fmaxf(f10[r] + bo0, 0.f);
    A32[r1][c1] += fmaxf(f11[r] + bo1, 0.f);
  }
  __syncthreads();
  ln32(A32, Xb, lane, w, g1, be1, mk, true);
  __syncthreads();

  // Q projection
  {
    f32x4 q00 = {0.f, 0.f, 0.f, 0.f}, q01 = q00, q10 = q00, q11 = q00;
    GEMM128(wqt, q00, q01, q10, q11);
    float bq0 = bq[c0], bq1 = bq[c1];
#pragma unroll
    for (int r = 0; r < 4; r++) {
      int r0 = g * 4 + r, r1 = 16 + r0;
      Q[(size_t)(base + r0) * FD + c0] = q00[r] + bq0;
      Q[(size_t)(base + r0) * FD + c1] = q01[r] + bq1;
      Q[(size_t)(base + r1) * FD + c0] = q10[r] + bq0;
      Q[(size_t)(base + r1) * FD + c1] = q11[r] + bq1;
    }
  }
  // K projection
  {
    f32x4 k00 = {0.f, 0.f, 0.f, 0.f}, k01 = k00, k10 = k00, k11 = k00;
    GEMM128(wkt, k00, k01, k10, k11);
    float bk0 = bk[c0], bk1 = bk[c1];
#pragma unroll
    for (int r = 0; r < 4; r++) {
      int r0 = g * 4 + r, r1 = 16 + r0;
      Kb[(size_t)(base + r0) * FD + c0] = (ushortt)f2b(k00[r] + bk0);
      Kb[(size_t)(base + r0) * FD + c1] = (ushortt)f2b(k01[r] + bk1);
      Kb[(size_t)(base + r1) * FD + c0] = (ushortt)f2b(k10[r] + bk0);
      Kb[(size_t)(base + r1) * FD + c1] = (ushortt)f2b(k11[r] + bk1);
    }
  }
  // V projection -> transposed store (4 consecutive t per lane)
  {
    f32x4 v00 = {0.f, 0.f, 0.f, 0.f}, v01 = v00, v10 = v00, v11 = v00;
    GEMM128(wvt, v00, v01, v10, v11);
    float bv0 = bv[c0], bv1 = bv[c1];
    short p[4];
#pragma unroll
    for (int k = 0; k < 4; k++) p[k] = f2b(v00[k] + bv0);
    *(s16x4*)&Vt[((size_t)b * FD + c0) * 512 + tloc + g * 4] = *(s16x4*)p;
#pragma unroll
    for (int k = 0; k < 4; k++) p[k] = f2b(v01[k] + bv1);
    *(s16x4*)&Vt[((size_t)b * FD + c1) * 512 + tloc + g * 4] = *(s16x4*)p;
#pragma unroll
    for (int k = 0; k < 4; k++) p[k] = f2b(v10[k] + bv0);
    *(s16x4*)&Vt[((size_t)b * FD + c0) * 512 + tloc + 16 + g * 4] = *(s16x4*)p;
#pragma unroll
    for (int k = 0; k < 4; k++) p[k] = f2b(v11[k] + bv1);
    *(s16x4*)&Vt[((size_t)b * FD + c1) * 512 + tloc + 16 + g * 4] = *(s16x4*)p;
  }
}

// ---- post(layer2) + ti + as-score, MFMA version ----
__global__ __launch_bounds__(256) void post_ti_k(
    const float* __restrict__ Ores, const float* __restrict__ mask,
    const ushortt* __restrict__ wot, const float* __restrict__ bo,
    const float* __restrict__ g0, const float* __restrict__ be0,
    const float* __restrict__ g1, const float* __restrict__ be1,
    const ushortt* __restrict__ wtit, const float* __restrict__ bti,
    const ushortt* __restrict__ wast, const float* __restrict__ bas,
    float* __restrict__ Xp2, float* __restrict__ S) {
  int base = blockIdx.x * 32;
  int tid = threadIdx.x;
  int w = tid >> 6, lane = tid & 63;
  int l15 = lane & 15, g = lane >> 4;

  __shared__ float A32[32][132];
  __shared__ __align__(16) short Xb[32][136];
  __shared__ float mk[32];

  {
    int r = tid >> 3, c = (tid & 7) * 16;
    const float4* src = (const float4*)(Ores + (size_t)(base + r) * FD + c);
#pragma unroll
    for (int jj = 0; jj < 4; jj++) *(float4*)&A32[r][c + jj * 4] = src[jj];
  }
  if (tid < 32) mk[tid] = mask[base + tid];
  __syncthreads();
  ln32(A32, Xb, lane, w, g0, be0, mk, false);
  __syncthreads();

  int c0 = w * 32 + l15, c1 = c0 + 16;
  f32x4 f00 = {0.f, 0.f, 0.f, 0.f}, f01 = f00, f10 = f00, f11 = f00;
  GEMM128(wot, f00, f01, f10, f11);
  float bo0 = bo[c0], bo1 = bo[c1];
#pragma unroll
  for (int r = 0; r < 4; r++) {
    int r0 = g * 4 + r, r1 = 16 + r0;
    A32[r0][c0] += fmaxf(f00[r] + bo0, 0.f);
    A32[r0][c1] += fmaxf(f01[r] + bo1, 0.f);
    A32[r1][c0] += fmaxf(f10[r] + bo0, 0.f);
    A32[r1][c1] += fmaxf(f11[r] + bo1, 0.f);
  }
  __syncthreads();
  ln32(A32, Xb, lane, w, g1, be1, mk, true);
  __syncthreads();

  // ti
  f32x4 t00 = {0.f, 0.f, 0.f, 0.f}, t01 = t00, t10 = t00, t11 = t00;
  GEMM128(wtit, t00, t01, t10, t11);
  float bti0 = bti[c0], bti1 = bti[c1];
#pragma unroll
  for (int r = 0; r < 4; r++) {
    int r0 = g * 4 + r, r1 = 16 + r0;
    float v00 = (t00[r] + bti0) * mk[r0];
    float v01 = (t01[r] + bti1) * mk[r0];
    float v10 = (t10[r] + bti0) * mk[r1];
    float v11 = (t11[r] + bti1) * mk[r1];
    Xp2[(size_t)(base + r0) * FD + c0] = v00;
    Xp2[(size_t)(base + r0) * FD + c1] = v01;
    Xp2[(size_t)(base + r1) * FD + c0] = v10;
    Xp2[(size_t)(base + r1) * FD + c1] = v11;
    Xb[r0][c0] = f2b(v00); Xb[r0][c1] = f2b(v01);
    Xb[r1][c0] = f2b(v10); Xb[r1][c1] = f2b(v11);
  }
  __syncthreads();
  // S = Xp2 @ was + bas (waves 0,1: 16 agg cols each)
  if (w < 2) {
    int a0 = w * 16 + l15;
    f32x4 s0 = {0.f, 0.f, 0.f, 0.f}, s1 = s0;
#pragma unroll
    for (int ks = 0; ks < 4; ks++) {
      bf16x8 aa0 = *(const bf16x8*)&Xb[l15][ks * 32 + g * 8];
      bf16x8 aa1 = *(const bf16x8*)&Xb[16 + l15][ks * 32 + g * 8];
      bf16x8 bb0 = *(const bf16x8*)(wast + (size_t)a0 * 128 + ks * 32 + g * 8);
      s0 = MFMA_16x16x32(aa0, bb0, s0);
      s1 = MFMA_16x16x32(aa1, bb0, s1);
    }
    float bas0 = bas[a0];
#pragma unroll
    for (int r = 0; r < 4; r++) {
      int r0 = g * 4 + r;
      S[(size_t)(base + r0) * NAGG + a0] = s0[r] + bas0;
      S[(size_t)(base + 16 + r0) * NAGG + a0] = s1[r] + bas0;
    }
  }
}

// ---- soft_t ----
__global__ void soft_t(const float* __restrict__ S, const float* __restrict__ mask,
                       float* __restrict__ att) {
  int b = blockIdx.x >> 5, a = blockIdx.x & 31;
  int tid = threadIdx.x;  // 128
  __shared__ float red[2];
  float sv[4], mv[4];
#pragma unroll
  for (int j = 0; j < 4; j++) {
    int t = tid + j * 128;
    sv[j] = S[(size_t)(b * TT + t) * NAGG + a];
    mv[j] = mask[b * TT + t];
  }
  float mx = fmaxf(fmaxf(sv[0], sv[1]), fmaxf(sv[2], sv[3]));
#pragma unroll
  for (int o = 32; o > 0; o >>= 1) mx = fmaxf(mx, __shfl_xor(mx, o));
  if ((tid & 63) == 0) red[tid >> 6] = mx;
  __syncthreads();
  mx = fmaxf(red[0], red[1]);
  __syncthreads();
  float e[4];
  float sm = 0.f;
#pragma unroll
  for (int j = 0; j < 4; j++) {
    e[j] = __expf(sv[j] - mx) * mv[j];
    sm += e[j];
  }
#pragma unroll
  for (int o = 32; o > 0; o >>= 1) sm += __shfl_xor(sm, o);
  if ((tid & 63) == 0) red[tid >> 6] = sm;
  __syncthreads();
  float inv = 1.f / (red[0] + red[1] + 1e-16f);
  float* dst = att + ((size_t)(b * NAGG + a)) * TT;
#pragma unroll
  for (int j = 0; j < 4; j++) dst[tid + j * 128] = e[j] * inv;
}

// ---- pool_part ----
__global__ void pool_part_k(const float* __restrict__ Xp2, const float* __restrict__ att,
                            const float* __restrict__ mask,
                            float* __restrict__ pmax, float* __restrict__ pmin,
                            float* __restrict__ psum) {
  int bid = blockIdx.x;
  int b = bid >> 7;
  int a = (bid >> 2) & 31;
  int tc = bid & 3;
  int f = threadIdx.x;
  __shared__ float att_s[128];
  __shared__ float ms[128];
  att_s[f] = att[((size_t)(b * NAGG + a)) * TT + tc * 128 + f];
  ms[f] = mask[b * TT + tc * 128 + f];
  __syncthreads();
  const float* xp = Xp2 + ((size_t)(b * TT + tc * 128)) * FD + f;
  float mn = 1e30f, mx = -1e30f, sm = 0.f;
#pragma unroll 4
  for (int t = 0; t < 128; t++) {
    float e = xp[(size_t)t * FD] * att_s[t];
    mn = fminf(mn, e);
    bool keep = ms[t] > 0.f;
    mx = keep ? fmaxf(mx, e) : mx;
    sm = keep ? sm + e : sm;
  }
  size_t idx = (size_t)bid * 128 + f;
  pmax[idx] = mx;
  pmin[idx] = mn;
  psum[idx] = sm;
}

// ---- combine ----
__global__ void combine_k(const float* __restrict__ pmax, const float* __restrict__ pmin,
                          const float* __restrict__ psum, const float* __restrict__ mask,
                          float* __restrict__ aggF, float* __restrict__ agg_out) {
  int b = blockIdx.x >> 5, a = blockIdx.x & 31;
  int f = threadIdx.x;
  __shared__ float red[2];
  float ntp = 0.f;
#pragma unroll
  for (int j = 0; j < 4; j++) ntp += (mask[b * TT + f + j * 128] > 0.f) ? 1.f : 0.f;
#pragma unroll
  for (int o = 32; o > 0; o >>= 1) ntp += __shfl_xor(ntp, o);
  if ((f & 63) == 0) red[f >> 6] = ntp;
  __syncthreads();
  float nt = red[0] + red[1];
  float mx = -1e30f, mn = 1e30f, sm = 0.f;
#pragma unroll
  for (int tc = 0; tc < 4; tc++) {
    size_t idx = ((size_t)(b * 128 + a * 4 + tc)) * 128 + f;
    mx = fmaxf(mx, pmax[idx]);
    mn = fminf(mn, pmin[idx]);
    sm += psum[idx];
  }
  bool anyUn = nt < 511.5f;
  float mp = anyUn ? fmaxf(mx, mn - 1.f) : mx;
  float mean = sm / (nt == 0.f ? 1.f : nt);
  size_t bs = (size_t)b * 8192 + (size_t)a * 256;
  aggF[bs + f] = mp;
  aggF[bs + 128 + f] = mean;
  agg_out[bs + f] = mp;
  agg_out[bs + 128 + f] = mean;
}

// ---- aggmm ----
__global__ void aggmm_k(const float* __restrict__ aggF, const float* __restrict__ wto,
                        float* __restrict__ part) {
  int b = blockIdx.x >> 5, cc = blockIdx.x & 31;
  int f = threadIdx.x;
  __shared__ float ag[256];
  ag[f] = aggF[(size_t)b * 8192 + cc * 256 + f];
  ag[128 + f] = aggF[(size_t)b * 8192 + cc * 256 + 128 + f];
  __syncthreads();
  const float* w = wto + ((size_t)(IND + FD) + cc * 256) * FD;
  float a0 = 0.f, a1 = 0.f, a2 = 0.f, a3 = 0.f;
#pragma unroll 4
  for (int j = 0; j < 256; j += 4) {
    a0 += ag[j] * w[(size_t)j * FD + f];
    a1 += ag[j + 1] * w[(size_t)(j + 1) * FD + f];
    a2 += ag[j + 2] * w[(size_t)(j + 2) * FD + f];
    a3 += ag[j + 3] * w[(size_t)(j + 3) * FD + f];
  }
  part[(size_t)(b * 32 + cc) * FD + f] = (a0 + a1) + (a2 + a3);
}

// ---- final, MFMA version ----
__global__ __launch_bounds__(256) void final_k(
    const float* __restrict__ X, const float* __restrict__ Xp2,
    const float* __restrict__ part, const ushortt* __restrict__ wtot,
    const float* __restrict__ wto, const float* __restrict__ bto,
    const float* __restrict__ gto, const float* __restrict__ btoln,
    const float* __restrict__ mask, float* __restrict__ out) {
  int base = blockIdx.x * 32;
  int b = base >> 9;
  int tid = threadIdx.x;
  int w = tid >> 6, lane = tid & 63;
  int l15 = lane & 15, g = lane >> 4;
  __shared__ float A32[32][132];
  __shared__ __align__(16) short Xb[32][136];
  __shared__ float xss[32][17];
  __shared__ float psum_s[128];
  __shared__ float mk[32];
  {
    int r = tid >> 3, c = (tid & 7) * 16;
    const float4* src = (const float4*)(Xp2 + (size_t)(base + r) * FD + c);
#pragma unroll
    for (int jj = 0; jj < 4; jj++) {
      float4 v = src[jj];
      *(s16x4*)&Xb[r][c + jj * 4] = (s16x4){f2b(v.x), f2b(v.y), f2b(v.z), f2b(v.w)};
    }
  }
  {
    int r = tid >> 3, ii = (tid & 7) * 2;
    xss[r][ii] = X[(size_t)(base + r) * IND + ii];
    xss[r][ii + 1] = X[(size_t)(base + r) * IND + ii + 1];
  }
  if (tid < 32) mk[tid] = mask[base + tid];
  if (tid < 128) {
    float ps = 0.f;
#pragma unroll 8
    for (int cc = 0; cc < 32; cc++) ps += part[(size_t)(b * 32 + cc) * FD + tid];
    psum_s[tid] = ps;
  }
  __syncthreads();
  int c0 = w * 32 + l15, c1 = c0 + 16;
  f32x4 q00 = {0.f, 0.f, 0.f, 0.f}, q01 = q00, q10 = q00, q11 = q00;
  GEMM128(wtot, q00, q01, q10, q11);
  float wx0[16], wx1[16];
#pragma unroll
  for (int i = 0; i < 16; i++) { wx0[i] = wto[i * FD + c0]; wx1[i] = wto[i * FD + c1]; }
  float add0 = bto[c0] + psum_s[c0], add1 = bto[c1] + psum_s[c1];
#pragma unroll
  for (int r = 0; r < 4; r++) {
    int r0 = g * 4 + r, r1 = 16 + r0;
    float x00 = q00[r] + add0, x01 = q01[r] + add1;
    float x10 = q10[r] + add0, x11 = q11[r] + add1;
#pragma unroll
    for (int i = 0; i < 16; i++) {
      x00 += xss[r0][i] * wx0[i];
      x01 += xss[r0][i] * wx1[i];
      x10 += xss[r1][i] * wx0[i];
      x11 += xss[r1][i] * wx1[i];
    }
    A32[r0][c0] = x00; A32[r0][c1] = x01;
    A32[r1][c0] = x10; A32[r1][c1] = x11;
  }
  __syncthreads();
  float ga = gto[lane], gb = gto[lane + 64], ba = btoln[lane], bb2 = btoln[lane + 64];
  for (int j = 0; j < 8; j++) {
    int rr = w * 8 + j;
    float a = A32[rr][lane], c = A32[rr][lane + 64];
    float s = a + c, ss = a * a + c * c;
#pragma unroll
    for (int o = 32; o > 0; o >>= 1) { s += __shfl_xor(s, o); ss += __shfl_xor(ss, o); }
    float mean = s * (1.f / 128.f);
    float var = ss * (1.f / 128.f) - mean * mean;
    float rs = rsqrtf(var + 1e-5f);
    float m = mk[rr];
    out[(size_t)(base + rr) * FD + lane] = fmaxf((a - mean) * rs * ga + ba, 0.f) * m;
    out[(size_t)(base + rr) * FD + lane + 64] = fmaxf((c - mean) * rs * gb + bb2, 0.f) * m;
  }
}

extern "C" void kernel_launch(void* const* d_in, const int* in_sizes, int n_in,
                              void* d_out, int out_size, void* d_ws, size_t ws_size,
                              hipStream_t stream) {
  const float* X    = (const float*)d_in[0];
  const float* mask = (const float*)d_in[1];
  const float* wq0 = (const float*)d_in[2];  const float* bq0 = (const float*)d_in[3];
  const float* wk0 = (const float*)d_in[4];  const float* bk0 = (const float*)d_in[5];
  const float* wv0 = (const float*)d_in[6];  const float* bv0 = (const float*)d_in[7];
  const float* wo0 = (const float*)d_in[8];  const float* bo0 = (const float*)d_in[9];
  const float* g00 = (const float*)d_in[10]; const float* be00 = (const float*)d_in[11];
  const float* g10 = (const float*)d_in[12]; const float* be10 = (const float*)d_in[13];
  const float* wq1 = (const float*)d_in[14]; const float* bq1 = (const float*)d_in[15];
  const float* wk1 = (const float*)d_in[16]; const float* bk1 = (const float*)d_in[17];
  const float* wv1 = (const float*)d_in[18]; const float* bv1 = (const float*)d_in[19];
  const float* wo1 = (const float*)d_in[20]; const float* bo1 = (const float*)d_in[21];
  const float* g01 = (const float*)d_in[22]; const float* be01 = (const float*)d_in[23];
  const float* g11 = (const float*)d_in[24]; const float* be11 = (const float*)d_in[25];
  const float* wti = (const float*)d_in[26]; const float* bti = (const float*)d_in[27];
  const float* was = (const float*)d_in[28]; const float* bas = (const float*)d_in[29];
  const float* wto = (const float*)d_in[30]; const float* bto = (const float*)d_in[31];
  const float* gto = (const float*)d_in[32]; const float* btoln = (const float*)d_in[33];

  const size_t BIG = (size_t)BB * TT * FD;  // 2,097,152 floats
  float* ws = (float*)d_ws;
  float* Qf = ws;
  ushortt* Kb = (ushortt*)(ws + BIG);
  ushortt* Vt = (ushortt*)(ws + BIG + BIG / 2);
  float* Ores = Qf;
  float* Xp2 = ws + BIG;
  float* S    = ws + 2 * BIG;
  float* att  = ws + 2 * BIG + 524288;
  float* aggF = ws + 2 * BIG + 1048576;
  float* part = ws + 2 * BIG + 1310720;
  ushortt* Wt = (ushortt*)(ws + 2 * BIG + 1441792);  // 8 x 16384 bf16
  float* pmax = ws;
  float* pmin = ws + 524288;
  float* psum = ws + 1048576;

  ushortt* wo0t = Wt;
  ushortt* wq1t = Wt + 16384;
  ushortt* wk1t = Wt + 2 * 16384;
  ushortt* wv1t = Wt + 3 * 16384;
  ushortt* wo1t = Wt + 4 * 16384;
  ushortt* wtit = Wt + 5 * 16384;
  ushortt* wtot = Wt + 6 * 16384;
  ushortt* wast = Wt + 7 * 16384;

  float* out_main = (float*)d_out;
  float* out_agg  = (float*)d_out + BIG;

  int nrb = BB * TT / 8;    // 2048
  int nrb32 = BB * TT / 32; // 512
  prep_w_k<<<32, 256, 0, stream>>>(wo0, wq1, wk1, wv1, wo1, wti, wto, was, Wt);
  proj16_k<<<nrb, 128, 0, stream>>>(X, wq0, bq0, wk0, bk0, wv0, bv0, Qf, Kb, Vt);
  attn_k<<<BB * 16, 256, 0, stream>>>(Qf, Kb, Vt, mask, Ores);
  post_proj_k<<<nrb32, 256, 0, stream>>>(Ores, mask, wo0t, bo0, g00, be00, g10, be10,
                                         wq1t, bq1, wk1t, bk1, wv1t, bv1, Qf, Kb, Vt);
  attn_k<<<BB * 16, 256, 0, stream>>>(Qf, Kb, Vt, mask, Ores);
  post_ti_k<<<nrb32, 256, 0, stream>>>(Ores, mask, wo1t, bo1, g01, be01, g11, be11,
                                       wtit, bti, wast, bas, Xp2, S);
  soft_t<<<BB * NAGG, 128, 0, stream>>>(S, mask, att);
  pool_part_k<<<BB * NAGG * 4, 128, 0, stream>>>(Xp2, att, mask, pmax, pmin, psum);
  combine_k<<<BB * NAGG, 128, 0, stream>>>(pmax, pmin, psum, mask, aggF, out_agg);
  aggmm_k<<<BB * 32, 128, 0, stream>>>(aggF, wto, part);
  final_k<<<nrb32, 256, 0, stream>>>(X, Xp2, part, wtot, wto, bto, gto, btoln, mask, out_main);
}